// Round 2
// baseline (675.093 us; speedup 1.0000x reference)
//
#include <hip/hip_runtime.h>
#include <cstdint>

typedef unsigned short u16;
typedef unsigned int u32;
typedef unsigned long long u64;
typedef __attribute__((ext_vector_type(4))) float f32x4;
typedef __attribute__((ext_vector_type(8))) __bf16 bf16x8;
typedef __attribute__((ext_vector_type(8))) u16 u16x8;

#define DEV __device__ __forceinline__

DEV u16 f2bf(float f) {
  u32 u = __builtin_bit_cast(u32, f);
  u += 0x7fffu + ((u >> 16) & 1u);
  return (u16)(u >> 16);
}
DEV float bflo2f(u32 packed) { return __builtin_bit_cast(float, packed << 16); }
DEV float bfhi2f(u32 packed) { return __builtin_bit_cast(float, packed & 0xffff0000u); }

// async global->LDS, 16B per lane. lds pointer must be the WAVE-UNIFORM base;
// HW adds lane*16. Global pointer is per-lane.
DEV void g2l16(void* lds_wave_base, const void* gsrc) {
  __builtin_amdgcn_global_load_lds(
      (const __attribute__((address_space(1))) u32*)gsrc,
      (__attribute__((address_space(3))) u32*)lds_wave_base, 16, 0, 0);
}

// ---------------- depthwise conv 3x3 (first 192 ch) + passthrough ----------
__global__ __launch_bounds__(256) void conv_k(const float* __restrict__ x,
                                              const float* __restrict__ cw,
                                              const float* __restrict__ cb,
                                              float* __restrict__ xc) {
  int id = blockIdx.x * 256 + threadIdx.x;       // 32*384*1024 total
  int p = id & 1023;
  int bc = id >> 10;
  int c = bc % 384;
  float v;
  if (c < 192) {
    int hh = p >> 5, ww = p & 31;
    float a = cb[c];
    const float* xp = x + ((size_t)bc << 10);
    const float* wp = cw + c * 9;
#pragma unroll
    for (int dy = 0; dy < 3; ++dy) {
      int y = hh + dy - 1;
      if ((unsigned)y < 32u) {
#pragma unroll
        for (int dx = 0; dx < 3; ++dx) {
          int xw = ww + dx - 1;
          if ((unsigned)xw < 32u) a += xp[y * 32 + xw] * wp[dy * 3 + dx];
        }
      }
    }
    v = a;
  } else {
    v = x[id];
  }
  xc[id] = v;
}

// ---------------- f32 -> bf16 convert ----------------
__global__ __launch_bounds__(256) void cvt_k(const float* __restrict__ in,
                                             u16* __restrict__ out, int n) {
  int id = blockIdx.x * 256 + threadIdx.x;
  if (id < n) out[id] = f2bf(in[id]);
}

// ---------------- channel-LN (NCHW) + transpose to [token][C] bf16 ---------
__global__ __launch_bounds__(256) void ln_t_k(const float* __restrict__ X,
                                              const float* __restrict__ w,
                                              const float* __restrict__ bsh,
                                              u16* __restrict__ Y) {
  __shared__ float tile[384][33];
  __shared__ float ps[8][32], ps2[8][32];
  __shared__ float mean_s[32], rstd_s[32];
  const int b = blockIdx.y;
  const int p0 = blockIdx.x * 32;
  const int t = threadIdx.x;
  const int pl = t & 31, cg = t >> 5;
  const float* xb = X + (((size_t)b * 384) << 10) + p0 + pl;
  float s = 0.f, s2 = 0.f;
  for (int c = cg; c < 384; c += 8) {
    float v = xb[(size_t)c << 10];
    tile[c][pl] = v;
    s += v;
    s2 += v * v;
  }
  ps[cg][pl] = s;
  ps2[cg][pl] = s2;
  __syncthreads();
  if (t < 32) {
    float a = 0.f, a2 = 0.f;
#pragma unroll
    for (int g = 0; g < 8; ++g) { a += ps[g][t]; a2 += ps2[g][t]; }
    float mu = a * (1.f / 384.f);
    float var = a2 * (1.f / 384.f) - mu * mu;
    mean_s[t] = mu;
    rstd_s[t] = rsqrtf(var + 1e-6f);
  }
  __syncthreads();
  const int cl = t & 63, pg = t >> 6;
  for (int p = pg; p < 32; p += 4) {
    float mu = mean_s[p], rs = rstd_s[p];
    size_t orow = (((size_t)b << 10) + p0 + p) * 384;
#pragma unroll
    for (int cc = 0; cc < 6; ++cc) {
      int c = cc * 64 + cl;
      float v = (tile[c][p] - mu) * rs * w[c] + bsh[c];
      Y[orow + c] = f2bf(v);
    }
  }
}

// ---------------- L2-normalize rows of Qn (×temp) and Kn, in place ---------
// Layout: [bh][1024][96]. Wave handles 4 rows (16 lanes × 6 elems each).
__global__ __launch_bounds__(256) void normqk_k(u16* __restrict__ Qn,
                                                u16* __restrict__ Kn,
                                                const float* __restrict__ temp) {
  const int t = threadIdx.x;
  const int w = t >> 6, l = t & 63;
  const int rg = l >> 4, li = l & 15;
  const int row = blockIdx.x * 16 + w * 4 + rg;   // bh*1024 + n
  const float tmp = temp[(row >> 10) & 3];
#pragma unroll
  for (int arr = 0; arr < 2; ++arr) {
    u16* p = (arr ? Kn : Qn) + (size_t)row * 96 + li * 6;
    u32 a = *(const u32*)p;
    u32 b2 = *(const u32*)(p + 2);
    u32 c = *(const u32*)(p + 4);
    float v[6] = {bflo2f(a), bfhi2f(a), bflo2f(b2), bfhi2f(b2), bflo2f(c), bfhi2f(c)};
    float ss = 0.f;
#pragma unroll
    for (int i = 0; i < 6; ++i) ss += v[i] * v[i];
#pragma unroll
    for (int mk = 1; mk < 16; mk <<= 1) ss += __shfl_xor(ss, mk, 64);
    float sc = 1.0f / fmaxf(sqrtf(ss), 1e-12f);
    if (arr == 0) sc *= tmp;     // fold temp into q̂: (q̂·temp)·k̂ = temp·(q̂·k̂)
    u32 o0 = (u32)f2bf(v[0] * sc) | ((u32)f2bf(v[1] * sc) << 16);
    u32 o1 = (u32)f2bf(v[2] * sc) | ((u32)f2bf(v[3] * sc) << 16);
    u32 o2 = (u32)f2bf(v[4] * sc) | ((u32)f2bf(v[5] * sc) << 16);
    *(u32*)p = o0;
    *(u32*)(p + 2) = o1;
    *(u32*)(p + 4) = o2;
  }
}

// ---------------- flash attention, barrier-free ----------------------------
// Grid (qtile=16, h=4, b=32), 4 independent waves/block, wave owns 16 q-rows.
// K,V read directly from L2 (per-bh K/V = 192KB each, reused by 16 blocks).
// Only per-wave P tile in LDS. Online softmax with defer-max (THR=8).
__global__ __launch_bounds__(256) void attn_k(const u16* __restrict__ Qn,
                                              const u16* __restrict__ Kn,
                                              const u16* __restrict__ Vt,
                                              u16* __restrict__ O) {
  __shared__ u16 Pt[4][16 * 72];
  const int t = threadIdx.x;
  const int w = t >> 6, l = t & 63;
  const int l15 = l & 15, kg = l >> 4;
  const int qt = blockIdx.x, h = blockIdx.y, b = blockIdx.z;
  const int bh = b * 4 + h;
  const int q0 = qt * 64;
  const u16* Qb = Qn + (size_t)bh * 98304;
  const u16* Kb = Kn + (size_t)bh * 98304;
  const u16* Vb = Vt + (size_t)bh * 98304;

  bf16x8 qf[3];
  {
    const u16* qp = Qb + (size_t)(q0 + w * 16 + l15) * 96 + kg * 8;
#pragma unroll
    for (int kk = 0; kk < 3; ++kk) qf[kk] = *(const bf16x8*)(qp + kk * 32);
  }
  float m_r[4], l_r[4];
#pragma unroll
  for (int j = 0; j < 4; ++j) { m_r[j] = -3.0e38f; l_r[j] = 0.f; }
  f32x4 oa[6];
#pragma unroll
  for (int d = 0; d < 6; ++d) oa[d] = {0.f, 0.f, 0.f, 0.f};

  for (int kv0 = 0; kv0 < 1024; kv0 += 64) {
    f32x4 s[4];
#pragma unroll
    for (int n = 0; n < 4; ++n) s[n] = {0.f, 0.f, 0.f, 0.f};
#pragma unroll
    for (int n = 0; n < 4; ++n) {
      const u16* kp = Kb + (size_t)(kv0 + n * 16 + l15) * 96 + kg * 8;
#pragma unroll
      for (int kk = 0; kk < 3; ++kk) {
        bf16x8 kf = *(const bf16x8*)(kp + kk * 32);
        s[n] = __builtin_amdgcn_mfma_f32_16x16x32_bf16(qf[kk], kf, s[n], 0, 0, 0);
      }
    }
    // per-row tile max (rows kg*4+j, spread over 16 lanes)
    float pmax[4];
#pragma unroll
    for (int j = 0; j < 4; ++j) {
      float mx = fmaxf(fmaxf(s[0][j], s[1][j]), fmaxf(s[2][j], s[3][j]));
#pragma unroll
      for (int mk = 1; mk < 16; mk <<= 1) mx = fmaxf(mx, __shfl_xor(mx, mk, 64));
      pmax[j] = mx;
    }
    bool need = (pmax[0] > m_r[0] + 8.f) || (pmax[1] > m_r[1] + 8.f) ||
                (pmax[2] > m_r[2] + 8.f) || (pmax[3] > m_r[3] + 8.f);
    if (__any(need)) {
#pragma unroll
      for (int j = 0; j < 4; ++j) {
        float nm = fmaxf(m_r[j], pmax[j]);
        float corr = __expf(m_r[j] - nm);
        m_r[j] = nm;
        l_r[j] *= corr;
#pragma unroll
        for (int d = 0; d < 6; ++d) oa[d][j] *= corr;
      }
    }
#pragma unroll
    for (int j = 0; j < 4; ++j) {
      float sum = 0.f;
#pragma unroll
      for (int n = 0; n < 4; ++n) {
        float pv = __expf(s[n][j] - m_r[j]);
        s[n][j] = pv;
        sum += pv;
      }
#pragma unroll
      for (int mk = 1; mk < 16; mk <<= 1) sum += __shfl_xor(sum, mk, 64);
      l_r[j] += sum;
    }
    // P -> per-wave LDS (stride 72: 16B-aligned rows, ~2-way banks)
#pragma unroll
    for (int n = 0; n < 4; ++n)
#pragma unroll
      for (int j = 0; j < 4; ++j)
        Pt[w][(kg * 4 + j) * 72 + n * 16 + l15] = f2bf(s[n][j]);
    // O += P @ V  (V^T rows contiguous in kv from pre-transposed Vt)
#pragma unroll
    for (int kk = 0; kk < 2; ++kk) {
      bf16x8 pf = *(const bf16x8*)(&Pt[w][l15 * 72 + kk * 32 + kg * 8]);
#pragma unroll
      for (int d = 0; d < 6; ++d) {
        bf16x8 vf = *(const bf16x8*)(Vb + (size_t)(d * 16 + l15) * 1024 + kv0 + kk * 32 + kg * 8);
        oa[d] = __builtin_amdgcn_mfma_f32_16x16x32_bf16(pf, vf, oa[d], 0, 0, 0);
      }
    }
  }
  float inv[4];
#pragma unroll
  for (int j = 0; j < 4; ++j) inv[j] = 1.0f / l_r[j];
#pragma unroll
  for (int d = 0; d < 6; ++d) {
#pragma unroll
    for (int j = 0; j < 4; ++j) {
      int tok = q0 + w * 16 + kg * 4 + j;
      O[((size_t)b * 1024 + tok) * 384 + h * 96 + d * 16 + l15] = f2bf(oa[d][j] * inv[j]);
    }
  }
}

// ---------------- 128x128x32 bf16 GEMM, m97 2-barrier structure ------------
// A [Mdim][K] row-major bf16, B [Ndim][K] row-major bf16, D = A @ B^T.
// EPI 1: gelu(D+bias) -> bf16 row-major [M][N]
// EPI 2: rows=channels, cols=tokens; out/res NCHW f32:
//        out[b,c,p] = res[b,c,p] + gamma[c]*(D+bias[c])
// EPI 3: QKV split epilogue: cols [0,384)=q,[384,768)=k,[768,1152)=v.
//        q,k -> [bh][n][96] row-major; v -> transposed [bh][96][n].
template <int EPI>
__global__ __launch_bounds__(256) void gemm_k(const u16* __restrict__ A,
                                              const u16* __restrict__ B, int M,
                                              int N, int K,
                                              const float* __restrict__ bias,
                                              const float* gamma,
                                              const float* res, void* outp) {
  __shared__ u16 At[128 * 32];
  __shared__ u16 Bt[128 * 32];
  const int t = threadIdx.x;
  const int w = t >> 6, l = t & 63;
  const int l15 = l & 15, kg = l >> 4;
  const int m0 = blockIdx.y * 128, n0 = blockIdx.x * 128;
  const int wr = w >> 1, wc = w & 1;

  const int off1 = w * 1024 + l * 16;
  const int off2 = 4096 + w * 1024 + l * 16;
  const int r1 = off1 >> 6, c1 = off1 & 63;
  const int r2 = off2 >> 6, c2 = off2 & 63;
  const size_t ldab = (size_t)K * 2;
  const char* pa1 = (const char*)A + (size_t)(m0 + r1) * ldab + c1;
  const char* pa2 = (const char*)A + (size_t)(m0 + r2) * ldab + c2;
  const char* pb1 = (const char*)B + (size_t)(n0 + r1) * ldab + c1;
  const char* pb2 = (const char*)B + (size_t)(n0 + r2) * ldab + c2;
  char* At1 = (char*)At + w * 1024;
  char* At2 = (char*)At + 4096 + w * 1024;
  char* Bt1 = (char*)Bt + w * 1024;
  char* Bt2 = (char*)Bt + 4096 + w * 1024;

  f32x4 acc[4][4];
#pragma unroll
  for (int m = 0; m < 4; ++m)
#pragma unroll
    for (int n = 0; n < 4; ++n) acc[m][n] = {0.f, 0.f, 0.f, 0.f};

  const int nkt = K >> 5;
  for (int kt = 0; kt < nkt; ++kt) {
    g2l16(At1, pa1);
    g2l16(At2, pa2);
    g2l16(Bt1, pb1);
    g2l16(Bt2, pb2);
    pa1 += 64; pa2 += 64; pb1 += 64; pb2 += 64;
    __syncthreads();
    bf16x8 af[4], bfr[4];
#pragma unroll
    for (int m = 0; m < 4; ++m)
      af[m] = *(const bf16x8*)(At + (wr * 64 + m * 16 + l15) * 32 + kg * 8);
#pragma unroll
    for (int n = 0; n < 4; ++n)
      bfr[n] = *(const bf16x8*)(Bt + (wc * 64 + n * 16 + l15) * 32 + kg * 8);
#pragma unroll
    for (int m = 0; m < 4; ++m)
#pragma unroll
      for (int n = 0; n < 4; ++n)
        acc[m][n] = __builtin_amdgcn_mfma_f32_16x16x32_bf16(af[m], bfr[n], acc[m][n], 0, 0, 0);
    __syncthreads();
  }

  if (EPI == 1) {
    u16* out = (u16*)outp;
#pragma unroll
    for (int m = 0; m < 4; ++m) {
#pragma unroll
      for (int n = 0; n < 4; ++n) {
        int gcol = n0 + wc * 64 + n * 16 + l15;
        float bs = bias[gcol];
#pragma unroll
        for (int j = 0; j < 4; ++j) {
          int grow = m0 + wr * 64 + m * 16 + kg * 4 + j;
          float v = acc[m][n][j] + bs;
          v = 0.5f * v * (1.0f + erff(v * 0.70710678118f));
          out[(size_t)grow * N + gcol] = f2bf(v);
        }
      }
    }
  } else if (EPI == 2) {
    float* out = (float*)outp;
#pragma unroll
    for (int m = 0; m < 4; ++m) {
#pragma unroll
      for (int n = 0; n < 4; ++n) {
        int tok = n0 + wc * 64 + n * 16 + l15;
        int bb = tok >> 10, p = tok & 1023;
#pragma unroll
        for (int j = 0; j < 4; ++j) {
          int c = m0 + wr * 64 + m * 16 + kg * 4 + j;
          size_t addr = (((size_t)(bb * 384 + c)) << 10) + p;
          out[addr] = res[addr] + gamma[c] * (acc[m][n][j] + bias[c]);
        }
      }
    }
  } else {  // EPI == 3
    u16* Qp = (u16*)outp;
    u16* Kp = Qp + 12582912;       // 128*1024*96
    u16* Vp = Kp + 12582912;
    const int sec = n0 / 384;      // uniform: 128-col tile within one section
#pragma unroll
    for (int m = 0; m < 4; ++m) {
      const int tokbase = m0 + wr * 64 + m * 16 + kg * 4;
      const int bb = tokbase >> 10, nb = tokbase & 1023;
#pragma unroll
      for (int n = 0; n < 4; ++n) {
        int gcol = n0 + wc * 64 + n * 16 + l15;
        int within = gcol - sec * 384;
        int hh = within / 96;
        int dd = within - hh * 96;
        float bs = bias[gcol];
        int bh = bb * 4 + hh;
        if (sec < 2) {
          u16* ptr = (sec ? Kp : Qp) + ((size_t)bh * 1024 + nb) * 96 + dd;
#pragma unroll
          for (int j = 0; j < 4; ++j) ptr[(size_t)j * 96] = f2bf(acc[m][n][j] + bs);
        } else {
          u64 pk = 0;
#pragma unroll
          for (int j = 0; j < 4; ++j)
            pk |= (u64)f2bf(acc[m][n][j] + bs) << (16 * j);
          *(u64*)(Vp + ((size_t)bh * 96 + dd) * 1024 + nb) = pk;
        }
      }
    }
  }
}

// ---------------------------------------------------------------------------
extern "C" void kernel_launch(void* const* d_in, const int* in_sizes, int n_in,
                              void* d_out, int out_size, void* d_ws,
                              size_t ws_size, hipStream_t stream) {
  const float* x      = (const float*)d_in[0];
  const float* conv_w = (const float*)d_in[1];
  const float* conv_b = (const float*)d_in[2];
  const float* nxca_w = (const float*)d_in[3];
  const float* nxca_b = (const float*)d_in[4];
  const float* temp   = (const float*)d_in[5];
  const float* qkv_w  = (const float*)d_in[6];
  const float* qkv_b  = (const float*)d_in[7];
  const float* proj_w = (const float*)d_in[8];
  const float* proj_b = (const float*)d_in[9];
  const float* norm_w = (const float*)d_in[10];
  const float* norm_b = (const float*)d_in[11];
  const float* fc1_w  = (const float*)d_in[12];
  const float* fc1_b  = (const float*)d_in[13];
  const float* fc2_w  = (const float*)d_in[14];
  const float* fc2_b  = (const float*)d_in[15];
  const float* g_xca  = (const float*)d_in[16];
  const float* g_mlp  = (const float*)d_in[17];
  (void)in_sizes; (void)n_in; (void)out_size; (void)ws_size;

  char* ws = (char*)d_ws;
  float* xc  = (float*)(ws);                    // 50,331,648 B (f32 NCHW, shortcut)
  u16* Y     = (u16*)(ws + 50331648);           // 25,165,824 B
  u16* Qn    = (u16*)(ws + 75497472);           // 25,165,824 B  [bh][1024][96]
  u16* Kn    = (u16*)(ws + 100663296);          // 25,165,824 B
  u16* Vt    = (u16*)(ws + 125829120);          // 25,165,824 B  [bh][96][1024]
  u16* Obuf  = (u16*)(ws + 150994944);          // 25,165,824 B
  u16* H1    = Qn;                              // overlays Qn..Obuf: 100,663,296 B
  u16* wq    = (u16*)(ws + 176160768);
  u16* wp    = (u16*)(ws + 177045504);
  u16* w1    = (u16*)(ws + 177340416);
  u16* w2    = (u16*)(ws + 178520064);          // end: 179,699,712 B
  (void)Kn; (void)Vt;

  cvt_k<<<1728, 256, 0, stream>>>(qkv_w, wq, 442368);
  cvt_k<<<576, 256, 0, stream>>>(proj_w, wp, 147456);
  cvt_k<<<2304, 256, 0, stream>>>(fc1_w, w1, 589824);
  cvt_k<<<2304, 256, 0, stream>>>(fc2_w, w2, 589824);

  conv_k<<<49152, 256, 0, stream>>>(x, conv_w, conv_b, xc);
  ln_t_k<<<dim3(32, 32), 256, 0, stream>>>(xc, nxca_w, nxca_b, Y);
  gemm_k<3><<<dim3(9, 256), 256, 0, stream>>>(Y, wq, 32768, 1152, 384, qkv_b,
                                              nullptr, nullptr, Qn);
  normqk_k<<<8192, 256, 0, stream>>>(Qn, Kn, temp);
  attn_k<<<dim3(16, 4, 32), 256, 0, stream>>>(Qn, Kn, Vt, Obuf);
  gemm_k<2><<<dim3(256, 3), 256, 0, stream>>>(wp, Obuf, 384, 32768, 384,
                                              proj_b, g_xca, xc, xc);
  ln_t_k<<<dim3(32, 32), 256, 0, stream>>>(xc, norm_w, norm_b, Y);
  gemm_k<1><<<dim3(12, 256), 256, 0, stream>>>(Y, w1, 32768, 1536, 384, fc1_b,
                                               nullptr, nullptr, H1);
  gemm_k<2><<<dim3(256, 3), 256, 0, stream>>>(w2, H1, 384, 32768, 1536, fc2_b,
                                              g_mlp, xc, (float*)d_out);
}

// Round 3
// 572.797 us; speedup vs baseline: 1.1786x; 1.1786x over previous
//
#include <hip/hip_runtime.h>
#include <cstdint>

typedef unsigned short u16;
typedef unsigned int u32;
typedef unsigned long long u64;
typedef __attribute__((ext_vector_type(4))) float f32x4;
typedef __attribute__((ext_vector_type(8))) __bf16 bf16x8;
typedef __attribute__((ext_vector_type(8))) u16 u16x8;

#define DEV __device__ __forceinline__

DEV u16 f2bf(float f) {
  u32 u = __builtin_bit_cast(u32, f);
  u += 0x7fffu + ((u >> 16) & 1u);
  return (u16)(u >> 16);
}
DEV float bflo2f(u32 packed) { return __builtin_bit_cast(float, packed << 16); }
DEV float bfhi2f(u32 packed) { return __builtin_bit_cast(float, packed & 0xffff0000u); }

// async global->LDS, 16B per lane. lds pointer must be the WAVE-UNIFORM base;
// HW adds lane*16. Global pointer is per-lane.
DEV void g2l16(void* lds_wave_base, const void* gsrc) {
  __builtin_amdgcn_global_load_lds(
      (const __attribute__((address_space(1))) u32*)gsrc,
      (__attribute__((address_space(3))) u32*)lds_wave_base, 16, 0, 0);
}

// ---------------- depthwise conv 3x3 (first 192 ch) + passthrough ----------
__global__ __launch_bounds__(256) void conv_k(const float* __restrict__ x,
                                              const float* __restrict__ cw,
                                              const float* __restrict__ cb,
                                              float* __restrict__ xc) {
  int id = blockIdx.x * 256 + threadIdx.x;       // 32*384*1024 total
  int p = id & 1023;
  int bc = id >> 10;
  int c = bc % 384;
  float v;
  if (c < 192) {
    int hh = p >> 5, ww = p & 31;
    float a = cb[c];
    const float* xp = x + ((size_t)bc << 10);
    const float* wp = cw + c * 9;
#pragma unroll
    for (int dy = 0; dy < 3; ++dy) {
      int y = hh + dy - 1;
      if ((unsigned)y < 32u) {
#pragma unroll
        for (int dx = 0; dx < 3; ++dx) {
          int xw = ww + dx - 1;
          if ((unsigned)xw < 32u) a += xp[y * 32 + xw] * wp[dy * 3 + dx];
        }
      }
    }
    v = a;
  } else {
    v = x[id];
  }
  xc[id] = v;
}

// ---------------- f32 -> bf16 convert ----------------
__global__ __launch_bounds__(256) void cvt_k(const float* __restrict__ in,
                                             u16* __restrict__ out, int n) {
  int id = blockIdx.x * 256 + threadIdx.x;
  if (id < n) out[id] = f2bf(in[id]);
}

// ---------------- channel-LN (NCHW) + transpose to [token][C] bf16 ---------
__global__ __launch_bounds__(256) void ln_t_k(const float* __restrict__ X,
                                              const float* __restrict__ w,
                                              const float* __restrict__ bsh,
                                              u16* __restrict__ Y) {
  __shared__ float tile[384][33];
  __shared__ float ps[8][32], ps2[8][32];
  __shared__ float mean_s[32], rstd_s[32];
  const int b = blockIdx.y;
  const int p0 = blockIdx.x * 32;
  const int t = threadIdx.x;
  const int pl = t & 31, cg = t >> 5;
  const float* xb = X + (((size_t)b * 384) << 10) + p0 + pl;
  float s = 0.f, s2 = 0.f;
  for (int c = cg; c < 384; c += 8) {
    float v = xb[(size_t)c << 10];
    tile[c][pl] = v;
    s += v;
    s2 += v * v;
  }
  ps[cg][pl] = s;
  ps2[cg][pl] = s2;
  __syncthreads();
  if (t < 32) {
    float a = 0.f, a2 = 0.f;
#pragma unroll
    for (int g = 0; g < 8; ++g) { a += ps[g][t]; a2 += ps2[g][t]; }
    float mu = a * (1.f / 384.f);
    float var = a2 * (1.f / 384.f) - mu * mu;
    mean_s[t] = mu;
    rstd_s[t] = rsqrtf(var + 1e-6f);
  }
  __syncthreads();
  const int cl = t & 63, pg = t >> 6;
  for (int p = pg; p < 32; p += 4) {
    float mu = mean_s[p], rs = rstd_s[p];
    size_t orow = (((size_t)b << 10) + p0 + p) * 384;
#pragma unroll
    for (int cc = 0; cc < 6; ++cc) {
      int c = cc * 64 + cl;
      float v = (tile[c][p] - mu) * rs * w[c] + bsh[c];
      Y[orow + c] = f2bf(v);
    }
  }
}

// ---------------- L2-normalize rows of Qn (×temp) and Kn, in place ---------
__global__ __launch_bounds__(256) void normqk_k(u16* __restrict__ Qn,
                                                u16* __restrict__ Kn,
                                                const float* __restrict__ temp) {
  const int t = threadIdx.x;
  const int w = t >> 6, l = t & 63;
  const int rg = l >> 4, li = l & 15;
  const int row = blockIdx.x * 16 + w * 4 + rg;   // bh*1024 + n
  const float tmp = temp[(row >> 10) & 3];
#pragma unroll
  for (int arr = 0; arr < 2; ++arr) {
    u16* p = (arr ? Kn : Qn) + (size_t)row * 96 + li * 6;
    u32 a = *(const u32*)p;
    u32 b2 = *(const u32*)(p + 2);
    u32 c = *(const u32*)(p + 4);
    float v[6] = {bflo2f(a), bfhi2f(a), bflo2f(b2), bfhi2f(b2), bflo2f(c), bfhi2f(c)};
    float ss = 0.f;
#pragma unroll
    for (int i = 0; i < 6; ++i) ss += v[i] * v[i];
#pragma unroll
    for (int mk = 1; mk < 16; mk <<= 1) ss += __shfl_xor(ss, mk, 64);
    float sc = 1.0f / fmaxf(sqrtf(ss), 1e-12f);
    if (arr == 0) sc *= tmp;     // fold temp into q̂: (q̂·temp)·k̂ = temp·(q̂·k̂)
    u32 o0 = (u32)f2bf(v[0] * sc) | ((u32)f2bf(v[1] * sc) << 16);
    u32 o1 = (u32)f2bf(v[2] * sc) | ((u32)f2bf(v[3] * sc) << 16);
    u32 o2 = (u32)f2bf(v[4] * sc) | ((u32)f2bf(v[5] * sc) << 16);
    *(u32*)p = o0;
    *(u32*)(p + 2) = o1;
    *(u32*)(p + 4) = o2;
  }
}

// ---------------- flash attention v3: XCD-local, barrier-free --------------
// 2048 blocks (1D, swizzled: all 16 q-blocks of a bh on one XCD), 2 waves.
// Wave owns 32 q-rows (2 MFMA frags). K,V read from L2. Softmax uses the
// CONSTANT shift T=|temp| (scores bounded by |t| since q,k unit + t folded):
// no running max, no rescale, lane-local l accumulation (reduced at end).
__global__ __launch_bounds__(128) void attn_k(const u16* __restrict__ Qn,
                                              const u16* __restrict__ Kn,
                                              const u16* __restrict__ Vt,
                                              u16* __restrict__ O,
                                              const float* __restrict__ temp) {
  __shared__ __bf16 Pt[2][32 * 72];
  const int t = threadIdx.x;
  const int w = t >> 6, l = t & 63;
  const int l15 = l & 15, kg = l >> 4;
  const int id = blockIdx.x;
  const int xcd = id & 7, jj = id >> 3;      // jj in [0,256)
  const int bh = xcd * 16 + (jj >> 4);       // 16 bh per XCD
  const int qb = jj & 15;
  const int b = bh >> 2, h = bh & 3;
  const int q0 = qb * 64 + w * 32;
  const u16* Qb = Qn + (size_t)bh * 98304;
  const u16* Kb = Kn + (size_t)bh * 98304;
  const u16* Vb = Vt + (size_t)bh * 98304;
  const float T = fabsf(temp[h]);

  bf16x8 qf[2][3];
#pragma unroll
  for (int f = 0; f < 2; ++f) {
    const u16* qp = Qb + (size_t)(q0 + f * 16 + l15) * 96 + kg * 8;
#pragma unroll
    for (int kk = 0; kk < 3; ++kk) qf[f][kk] = *(const bf16x8*)(qp + kk * 32);
  }
  f32x4 oa[2][6];
#pragma unroll
  for (int f = 0; f < 2; ++f)
#pragma unroll
    for (int d = 0; d < 6; ++d) oa[f][d] = {0.f, 0.f, 0.f, 0.f};
  float l_r[2][4] = {{0.f, 0.f, 0.f, 0.f}, {0.f, 0.f, 0.f, 0.f}};
  __bf16* Pw = &Pt[w][0];

  for (int kv0 = 0; kv0 < 1024; kv0 += 64) {
    f32x4 s0[4], s1[4];
#pragma unroll
    for (int n = 0; n < 4; ++n) { s0[n] = {0.f, 0.f, 0.f, 0.f}; s1[n] = {0.f, 0.f, 0.f, 0.f}; }
#pragma unroll
    for (int n = 0; n < 4; ++n) {
      const u16* kp = Kb + (size_t)(kv0 + n * 16 + l15) * 96 + kg * 8;
#pragma unroll
      for (int kk = 0; kk < 3; ++kk) {
        bf16x8 kf = *(const bf16x8*)(kp + kk * 32);
        s0[n] = __builtin_amdgcn_mfma_f32_16x16x32_bf16(qf[0][kk], kf, s0[n], 0, 0, 0);
        s1[n] = __builtin_amdgcn_mfma_f32_16x16x32_bf16(qf[1][kk], kf, s1[n], 0, 0, 0);
      }
    }
    // P = exp(s - T); lane-local partial row-sums (no shuffles here)
#pragma unroll
    for (int n = 0; n < 4; ++n) {
#pragma unroll
      for (int j = 0; j < 4; ++j) {
        float p0 = __expf(s0[n][j] - T);
        float p1 = __expf(s1[n][j] - T);
        l_r[0][j] += p0;
        l_r[1][j] += p1;
        Pw[(kg * 4 + j) * 72 + n * 16 + l15] = (__bf16)p0;
        Pw[(16 + kg * 4 + j) * 72 + n * 16 + l15] = (__bf16)p1;
      }
    }
    // O += P @ V  (same wave wrote Pt -> compiler inserts lgkmcnt wait)
#pragma unroll
    for (int kk = 0; kk < 2; ++kk) {
      bf16x8 pf0 = *(const bf16x8*)(Pw + (size_t)l15 * 72 + kk * 32 + kg * 8);
      bf16x8 pf1 = *(const bf16x8*)(Pw + (size_t)(16 + l15) * 72 + kk * 32 + kg * 8);
#pragma unroll
      for (int d = 0; d < 6; ++d) {
        bf16x8 vf = *(const bf16x8*)(Vb + (size_t)(d * 16 + l15) * 1024 + kv0 + kk * 32 + kg * 8);
        oa[0][d] = __builtin_amdgcn_mfma_f32_16x16x32_bf16(pf0, vf, oa[0][d], 0, 0, 0);
        oa[1][d] = __builtin_amdgcn_mfma_f32_16x16x32_bf16(pf1, vf, oa[1][d], 0, 0, 0);
      }
    }
  }
  float inv[2][4];
#pragma unroll
  for (int f = 0; f < 2; ++f)
#pragma unroll
    for (int j = 0; j < 4; ++j) {
      float sum = l_r[f][j];
#pragma unroll
      for (int mk = 1; mk < 16; mk <<= 1) sum += __shfl_xor(sum, mk, 64);
      inv[f][j] = 1.0f / sum;
    }
#pragma unroll
  for (int f = 0; f < 2; ++f)
#pragma unroll
    for (int d = 0; d < 6; ++d)
#pragma unroll
      for (int j = 0; j < 4; ++j) {
        int tok = q0 + f * 16 + kg * 4 + j;
        O[((size_t)b * 1024 + tok) * 384 + h * 96 + d * 16 + l15] =
            f2bf(oa[f][d][j] * inv[f][j]);
      }
}

// ---------------- 128x128x32 bf16 GEMM, m97 2-barrier structure ------------
// A [Mdim][K] rm bf16, B [Ndim][K] rm bf16, D = A @ B^T.
// SWZ: 1D grid, gy==256 assumed; same-by blocks pinned to one XCD.
// EPI 1: gelu(D+bias) -> bf16 rm [M][N]
// EPI 2: rows=channels, cols=tokens; out[b,c,p]=res[b,c,p]+gamma[c]*(D+bias)
// EPI 3: QKV split: q,k -> [bh][n][96]; v -> [bh][96][n] (transposed)
template <int EPI, bool SWZ>
__global__ __launch_bounds__(256) void gemm_k(const u16* __restrict__ A,
                                              const u16* __restrict__ B, int M,
                                              int N, int K,
                                              const float* __restrict__ bias,
                                              const float* gamma,
                                              const float* res, void* outp,
                                              int nbx) {
  __shared__ u16 At[128 * 32];
  __shared__ u16 Bt[128 * 32];
  const int t = threadIdx.x;
  const int w = t >> 6, l = t & 63;
  const int l15 = l & 15, kg = l >> 4;
  int bx, by;
  if (SWZ) {
    int id = blockIdx.x;
    int xcd = id & 7, jj = id >> 3;
    int q = jj / nbx;
    bx = jj - q * nbx;
    by = xcd * 32 + q;            // 256/8 = 32 y-tiles per XCD
  } else {
    bx = blockIdx.x; by = blockIdx.y;
  }
  const int m0 = by * 128, n0 = bx * 128;
  const int wr = w >> 1, wc = w & 1;

  const int off1 = w * 1024 + l * 16;
  const int off2 = 4096 + w * 1024 + l * 16;
  const int r1 = off1 >> 6, c1 = off1 & 63;
  const int r2 = off2 >> 6, c2 = off2 & 63;
  const size_t ldab = (size_t)K * 2;
  const char* pa1 = (const char*)A + (size_t)(m0 + r1) * ldab + c1;
  const char* pa2 = (const char*)A + (size_t)(m0 + r2) * ldab + c2;
  const char* pb1 = (const char*)B + (size_t)(n0 + r1) * ldab + c1;
  const char* pb2 = (const char*)B + (size_t)(n0 + r2) * ldab + c2;
  char* At1 = (char*)At + w * 1024;
  char* At2 = (char*)At + 4096 + w * 1024;
  char* Bt1 = (char*)Bt + w * 1024;
  char* Bt2 = (char*)Bt + 4096 + w * 1024;

  f32x4 acc[4][4];
#pragma unroll
  for (int m = 0; m < 4; ++m)
#pragma unroll
    for (int n = 0; n < 4; ++n) acc[m][n] = {0.f, 0.f, 0.f, 0.f};

  const int nkt = K >> 5;
  for (int kt = 0; kt < nkt; ++kt) {
    g2l16(At1, pa1);
    g2l16(At2, pa2);
    g2l16(Bt1, pb1);
    g2l16(Bt2, pb2);
    pa1 += 64; pa2 += 64; pb1 += 64; pb2 += 64;
    __syncthreads();
    bf16x8 af[4], bfr[4];
#pragma unroll
    for (int m = 0; m < 4; ++m)
      af[m] = *(const bf16x8*)(At + (wr * 64 + m * 16 + l15) * 32 + kg * 8);
#pragma unroll
    for (int n = 0; n < 4; ++n)
      bfr[n] = *(const bf16x8*)(Bt + (wc * 64 + n * 16 + l15) * 32 + kg * 8);
#pragma unroll
    for (int m = 0; m < 4; ++m)
#pragma unroll
      for (int n = 0; n < 4; ++n)
        acc[m][n] = __builtin_amdgcn_mfma_f32_16x16x32_bf16(af[m], bfr[n], acc[m][n], 0, 0, 0);
    __syncthreads();
  }

  if (EPI == 1) {
    u16* out = (u16*)outp;
#pragma unroll
    for (int m = 0; m < 4; ++m) {
#pragma unroll
      for (int n = 0; n < 4; ++n) {
        int gcol = n0 + wc * 64 + n * 16 + l15;
        float bs = bias[gcol];
#pragma unroll
        for (int j = 0; j < 4; ++j) {
          int grow = m0 + wr * 64 + m * 16 + kg * 4 + j;
          float v = acc[m][n][j] + bs;
          v = 0.5f * v * (1.0f + erff(v * 0.70710678118f));
          out[(size_t)grow * N + gcol] = f2bf(v);
        }
      }
    }
  } else if (EPI == 2) {
    float* out = (float*)outp;
#pragma unroll
    for (int m = 0; m < 4; ++m) {
#pragma unroll
      for (int n = 0; n < 4; ++n) {
        int tok = n0 + wc * 64 + n * 16 + l15;
        int bb = tok >> 10, p = tok & 1023;
#pragma unroll
        for (int j = 0; j < 4; ++j) {
          int c = m0 + wr * 64 + m * 16 + kg * 4 + j;
          size_t addr = (((size_t)(bb * 384 + c)) << 10) + p;
          out[addr] = res[addr] + gamma[c] * (acc[m][n][j] + bias[c]);
        }
      }
    }
  } else {  // EPI == 3
    u16* Qp = (u16*)outp;
    u16* Kp = Qp + 12582912;       // 128*1024*96
    u16* Vp = Kp + 12582912;
    const int sec = n0 / 384;      // uniform: 128-col tile within one section
#pragma unroll
    for (int m = 0; m < 4; ++m) {
      const int tokbase = m0 + wr * 64 + m * 16 + kg * 4;
      const int bb = tokbase >> 10, nb = tokbase & 1023;
#pragma unroll
      for (int n = 0; n < 4; ++n) {
        int gcol = n0 + wc * 64 + n * 16 + l15;
        int within = gcol - sec * 384;
        int hh = within / 96;
        int dd = within - hh * 96;
        float bs = bias[gcol];
        int bh = bb * 4 + hh;
        if (sec < 2) {
          u16* ptr = (sec ? Kp : Qp) + ((size_t)bh * 1024 + nb) * 96 + dd;
#pragma unroll
          for (int j = 0; j < 4; ++j) ptr[(size_t)j * 96] = f2bf(acc[m][n][j] + bs);
        } else {
          u64 pk = 0;
#pragma unroll
          for (int j = 0; j < 4; ++j)
            pk |= (u64)f2bf(acc[m][n][j] + bs) << (16 * j);
          *(u64*)(Vp + ((size_t)bh * 96 + dd) * 1024 + nb) = pk;
        }
      }
    }
  }
}

// ---------------------------------------------------------------------------
extern "C" void kernel_launch(void* const* d_in, const int* in_sizes, int n_in,
                              void* d_out, int out_size, void* d_ws,
                              size_t ws_size, hipStream_t stream) {
  const float* x      = (const float*)d_in[0];
  const float* conv_w = (const float*)d_in[1];
  const float* conv_b = (const float*)d_in[2];
  const float* nxca_w = (const float*)d_in[3];
  const float* nxca_b = (const float*)d_in[4];
  const float* temp   = (const float*)d_in[5];
  const float* qkv_w  = (const float*)d_in[6];
  const float* qkv_b  = (const float*)d_in[7];
  const float* proj_w = (const float*)d_in[8];
  const float* proj_b = (const float*)d_in[9];
  const float* norm_w = (const float*)d_in[10];
  const float* norm_b = (const float*)d_in[11];
  const float* fc1_w  = (const float*)d_in[12];
  const float* fc1_b  = (const float*)d_in[13];
  const float* fc2_w  = (const float*)d_in[14];
  const float* fc2_b  = (const float*)d_in[15];
  const float* g_xca  = (const float*)d_in[16];
  const float* g_mlp  = (const float*)d_in[17];
  (void)in_sizes; (void)n_in; (void)out_size; (void)ws_size;

  char* ws = (char*)d_ws;
  float* xc  = (float*)(ws);                    // 50,331,648 B (f32 NCHW, shortcut)
  u16* Y     = (u16*)(ws + 50331648);           // 25,165,824 B
  u16* Qn    = (u16*)(ws + 75497472);           // 25,165,824 B  [bh][1024][96]
  u16* Kn    = (u16*)(ws + 100663296);          // 25,165,824 B
  u16* Vt    = (u16*)(ws + 125829120);          // 25,165,824 B  [bh][96][1024]
  u16* Obuf  = (u16*)(ws + 150994944);          // 25,165,824 B
  u16* H1    = Qn;                              // overlays Qn..Obuf: 100,663,296 B
  u16* wq    = (u16*)(ws + 176160768);
  u16* wp    = (u16*)(ws + 177045504);
  u16* w1    = (u16*)(ws + 177340416);
  u16* w2    = (u16*)(ws + 178520064);          // end: 179,699,712 B
  (void)Kn; (void)Vt;

  cvt_k<<<1728, 256, 0, stream>>>(qkv_w, wq, 442368);
  cvt_k<<<576, 256, 0, stream>>>(proj_w, wp, 147456);
  cvt_k<<<2304, 256, 0, stream>>>(fc1_w, w1, 589824);
  cvt_k<<<2304, 256, 0, stream>>>(fc2_w, w2, 589824);

  conv_k<<<49152, 256, 0, stream>>>(x, conv_w, conv_b, xc);
  ln_t_k<<<dim3(32, 32), 256, 0, stream>>>(xc, nxca_w, nxca_b, Y);
  gemm_k<3, true><<<2304, 256, 0, stream>>>(Y, wq, 32768, 1152, 384, qkv_b,
                                            nullptr, nullptr, Qn, 9);
  normqk_k<<<8192, 256, 0, stream>>>(Qn, Kn, temp);
  attn_k<<<2048, 128, 0, stream>>>(Qn, Kn, Vt, Obuf, temp);
  gemm_k<2, false><<<dim3(256, 3), 256, 0, stream>>>(wp, Obuf, 384, 32768, 384,
                                                     proj_b, g_xca, xc, xc, 0);
  ln_t_k<<<dim3(32, 32), 256, 0, stream>>>(xc, norm_w, norm_b, Y);
  gemm_k<1, true><<<3072, 256, 0, stream>>>(Y, w1, 32768, 1536, 384, fc1_b,
                                            nullptr, nullptr, H1, 12);
  gemm_k<2, false><<<dim3(256, 3), 256, 0, stream>>>(w2, H1, 384, 32768, 1536,
                                                     fc2_b, g_mlp, xc,
                                                     (float*)d_out, 0);
}

// Round 4
// 486.070 us; speedup vs baseline: 1.3889x; 1.1784x over previous
//
#include <hip/hip_runtime.h>
#include <cstdint>

typedef unsigned short u16;
typedef unsigned int u32;
typedef unsigned long long u64;
typedef __attribute__((ext_vector_type(4))) float f32x4;
typedef __attribute__((ext_vector_type(8))) __bf16 bf16x8;
typedef __attribute__((ext_vector_type(8))) u16 u16x8;

#define DEV __device__ __forceinline__

DEV u16 f2bf(float f) {
  u32 u = __builtin_bit_cast(u32, f);
  u += 0x7fffu + ((u >> 16) & 1u);
  return (u16)(u >> 16);
}
DEV float bflo2f(u32 packed) { return __builtin_bit_cast(float, packed << 16); }
DEV float bfhi2f(u32 packed) { return __builtin_bit_cast(float, packed & 0xffff0000u); }

// async global->LDS, 16B per lane. lds pointer must be the WAVE-UNIFORM base;
// HW adds lane*16. Global pointer is per-lane.
DEV void g2l16(void* lds_wave_base, const void* gsrc) {
  __builtin_amdgcn_global_load_lds(
      (const __attribute__((address_space(1))) u32*)gsrc,
      (__attribute__((address_space(3))) u32*)lds_wave_base, 16, 0, 0);
}

// ---------------- depthwise conv 3x3 (first 192 ch) + passthrough ----------
__global__ __launch_bounds__(256) void conv_k(const float* __restrict__ x,
                                              const float* __restrict__ cw,
                                              const float* __restrict__ cb,
                                              float* __restrict__ xc) {
  int id = blockIdx.x * 256 + threadIdx.x;       // 32*384*1024 total
  int p = id & 1023;
  int bc = id >> 10;
  int c = bc % 384;
  float v;
  if (c < 192) {
    int hh = p >> 5, ww = p & 31;
    float a = cb[c];
    const float* xp = x + ((size_t)bc << 10);
    const float* wp = cw + c * 9;
#pragma unroll
    for (int dy = 0; dy < 3; ++dy) {
      int y = hh + dy - 1;
      if ((unsigned)y < 32u) {
#pragma unroll
        for (int dx = 0; dx < 3; ++dx) {
          int xw = ww + dx - 1;
          if ((unsigned)xw < 32u) a += xp[y * 32 + xw] * wp[dy * 3 + dx];
        }
      }
    }
    v = a;
  } else {
    v = x[id];
  }
  xc[id] = v;
}

// ---------------- f32 -> bf16 convert ----------------
__global__ __launch_bounds__(256) void cvt_k(const float* __restrict__ in,
                                             u16* __restrict__ out, int n) {
  int id = blockIdx.x * 256 + threadIdx.x;
  if (id < n) out[id] = f2bf(in[id]);
}

// ---------------- channel-LN (NCHW) + transpose to [token][C] bf16 ---------
__global__ __launch_bounds__(256) void ln_t_k(const float* __restrict__ X,
                                              const float* __restrict__ w,
                                              const float* __restrict__ bsh,
                                              u16* __restrict__ Y) {
  __shared__ float tile[384][33];
  __shared__ float ps[8][32], ps2[8][32];
  __shared__ float mean_s[32], rstd_s[32];
  const int b = blockIdx.y;
  const int p0 = blockIdx.x * 32;
  const int t = threadIdx.x;
  const int pl = t & 31, cg = t >> 5;
  const float* xb = X + (((size_t)b * 384) << 10) + p0 + pl;
  float s = 0.f, s2 = 0.f;
  for (int c = cg; c < 384; c += 8) {
    float v = xb[(size_t)c << 10];
    tile[c][pl] = v;
    s += v;
    s2 += v * v;
  }
  ps[cg][pl] = s;
  ps2[cg][pl] = s2;
  __syncthreads();
  if (t < 32) {
    float a = 0.f, a2 = 0.f;
#pragma unroll
    for (int g = 0; g < 8; ++g) { a += ps[g][t]; a2 += ps2[g][t]; }
    float mu = a * (1.f / 384.f);
    float var = a2 * (1.f / 384.f) - mu * mu;
    mean_s[t] = mu;
    rstd_s[t] = rsqrtf(var + 1e-6f);
  }
  __syncthreads();
  const int cl = t & 63, pg = t >> 6;
  for (int p = pg; p < 32; p += 4) {
    float mu = mean_s[p], rs = rstd_s[p];
    size_t orow = (((size_t)b << 10) + p0 + p) * 384;
#pragma unroll
    for (int cc = 0; cc < 6; ++cc) {
      int c = cc * 64 + cl;
      float v = (tile[c][p] - mu) * rs * w[c] + bsh[c];
      Y[orow + c] = f2bf(v);
    }
  }
}

// ---------------- L2-normalize rows of Qn (×temp, stride 96) and Kn (128) --
__global__ __launch_bounds__(256) void normqk_k(u16* __restrict__ Qn,
                                                u16* __restrict__ Kn,
                                                const float* __restrict__ temp) {
  const int t = threadIdx.x;
  const int w = t >> 6, l = t & 63;
  const int rg = l >> 4, li = l & 15;
  const int row = blockIdx.x * 16 + w * 4 + rg;   // bh*1024 + n
  const float tmp = temp[(row >> 10) & 3];
#pragma unroll
  for (int arr = 0; arr < 2; ++arr) {
    u16* p = arr ? (Kn + (size_t)row * 128 + li * 6)
                 : (Qn + (size_t)row * 96 + li * 6);
    u32 a = *(const u32*)p;
    u32 b2 = *(const u32*)(p + 2);
    u32 c = *(const u32*)(p + 4);
    float v[6] = {bflo2f(a), bfhi2f(a), bflo2f(b2), bfhi2f(b2), bflo2f(c), bfhi2f(c)};
    float ss = 0.f;
#pragma unroll
    for (int i = 0; i < 6; ++i) ss += v[i] * v[i];
#pragma unroll
    for (int mk = 1; mk < 16; mk <<= 1) ss += __shfl_xor(ss, mk, 64);
    float sc = 1.0f / fmaxf(sqrtf(ss), 1e-12f);
    if (arr == 0) sc *= tmp;     // fold temp into q̂
    u32 o0 = (u32)f2bf(v[0] * sc) | ((u32)f2bf(v[1] * sc) << 16);
    u32 o1 = (u32)f2bf(v[2] * sc) | ((u32)f2bf(v[3] * sc) << 16);
    u32 o2 = (u32)f2bf(v[4] * sc) | ((u32)f2bf(v[5] * sc) << 16);
    *(u32*)p = o0;
    *(u32*)(p + 2) = o1;
    *(u32*)(p + 4) = o2;
  }
}

// ---------------- flash attention v4: LDS dbuf pipeline --------------------
// 1024 blocks (XCD-pinned: 16 bh/XCD × 8 q-blocks), 4 waves × 32 q-rows.
// K (global rows padded to 128 u16) staged as contiguous 16KB tiles; V^T
// gathered; both XOR-swizzled in LDS via pre-swizzled SOURCE offsets
// (linear g2l16 dest) + swizzled read addrs. Counted vmcnt(7), 2 barriers.
__global__ __launch_bounds__(256) void attn_k(const u16* __restrict__ Qn,
                                              const u16* __restrict__ Kg,
                                              const u16* __restrict__ Vg,
                                              u16* __restrict__ O,
                                              const float* __restrict__ temp) {
  __shared__ u16 Kt[2][8192];    // [64 rows][128 u16] swizzled
  __shared__ u16 Vt[2][6144];    // [96 rows][64 u16] swizzled
  __shared__ u16 Pt[4][2304];    // per-wave P [32][72]
  const int t = threadIdx.x;
  const int w = t >> 6, l = t & 63;
  const int l15 = l & 15, kg = l >> 4;
  const int id = blockIdx.x;
  const int xcd = id & 7, jj = id >> 3;          // jj in [0,128)
  const int bh = xcd * 16 + (jj >> 3);
  const int qb = jj & 7;
  const int b = bh >> 2, h = bh & 3;
  const int q0 = qb * 128 + w * 32;
  const u16* Qb = Qn + (size_t)bh * 98304;       // stride 96
  const u16* Kbg = Kg + (size_t)bh * 131072;     // stride 128
  const u16* Vbg = Vg + (size_t)bh * 98304;      // [96][1024]
  const float T = fabsf(temp[h]);

  // per-lane staging source offsets (bytes within tile), inverse-swizzled
  u32 sK[4], sV[3];
#pragma unroll
  for (int j = 0; j < 4; ++j) {
    u32 s = w * 4096 + j * 1024 + l * 16;
    sK[j] = s ^ (((s >> 8) & 7) << 4);
  }
#pragma unroll
  for (int j = 0; j < 3; ++j) {
    u32 s = w * 3072 + j * 1024 + l * 16;
    u32 u = s ^ (((s >> 7) & 7) << 4);
    sV[j] = (u >> 7) * 2048 + (u & 127);
  }
  // read-side swizzled column byte offsets (col ^ ((row&7)<<4))
  u32 cs[3];
#pragma unroll
  for (int kk = 0; kk < 3; ++kk)
    cs[kk] = (u32)((kk * 64 + kg * 16) ^ ((l15 & 7) << 4));

  bf16x8 qf[2][3];
#pragma unroll
  for (int f = 0; f < 2; ++f) {
    const u16* qp = Qb + (size_t)(q0 + f * 16 + l15) * 96 + kg * 8;
#pragma unroll
    for (int kk = 0; kk < 3; ++kk) qf[f][kk] = *(const bf16x8*)(qp + kk * 32);
  }
  f32x4 oa[2][6];
#pragma unroll
  for (int f = 0; f < 2; ++f)
#pragma unroll
    for (int d = 0; d < 6; ++d) oa[f][d] = {0.f, 0.f, 0.f, 0.f};
  float l_r[2][4] = {{0.f, 0.f, 0.f, 0.f}, {0.f, 0.f, 0.f, 0.f}};
  __bf16* Pw = (__bf16*)&Pt[w][0];

#define STAGE(buf, kv0)                                                        \
  {                                                                            \
    const char* kb = (const char*)Kbg + (size_t)(kv0) * 256;                   \
    const char* vb = (const char*)Vbg + (size_t)(kv0) * 2;                     \
    char* kd = (char*)&Kt[buf][0] + w * 4096;                                  \
    char* vd = (char*)&Vt[buf][0] + w * 3072;                                  \
    g2l16(kd, kb + sK[0]);                                                     \
    g2l16(kd + 1024, kb + sK[1]);                                              \
    g2l16(kd + 2048, kb + sK[2]);                                              \
    g2l16(kd + 3072, kb + sK[3]);                                              \
    g2l16(vd, vb + sV[0]);                                                     \
    g2l16(vd + 1024, vb + sV[1]);                                              \
    g2l16(vd + 2048, vb + sV[2]);                                              \
  }

  STAGE(0, 0);
  for (int tt = 0; tt < 16; ++tt) {
    const int cur = tt & 1;
    if (tt < 15) {
      STAGE(cur ^ 1, (tt + 1) * 64);
      asm volatile("s_waitcnt vmcnt(7)" ::: "memory");
    } else {
      asm volatile("s_waitcnt vmcnt(0)" ::: "memory");
    }
    __builtin_amdgcn_s_barrier();
    const char* Kc = (const char*)&Kt[cur][0];
    const char* Vc = (const char*)&Vt[cur][0];
    // S = Qn @ Kn^T
    f32x4 s0[4], s1[4];
#pragma unroll
    for (int n = 0; n < 4; ++n) { s0[n] = {0.f, 0.f, 0.f, 0.f}; s1[n] = {0.f, 0.f, 0.f, 0.f}; }
#pragma unroll
    for (int n = 0; n < 4; ++n) {
      const char* krow = Kc + ((n * 16 + l15) << 8);
#pragma unroll
      for (int kk = 0; kk < 3; ++kk) {
        bf16x8 kf = *(const bf16x8*)(krow + cs[kk]);
        s0[n] = __builtin_amdgcn_mfma_f32_16x16x32_bf16(qf[0][kk], kf, s0[n], 0, 0, 0);
        s1[n] = __builtin_amdgcn_mfma_f32_16x16x32_bf16(qf[1][kk], kf, s1[n], 0, 0, 0);
      }
    }
    // P = exp(s - T); lane-local partial row-sums
#pragma unroll
    for (int n = 0; n < 4; ++n) {
#pragma unroll
      for (int j = 0; j < 4; ++j) {
        float p0 = __expf(s0[n][j] - T);
        float p1 = __expf(s1[n][j] - T);
        l_r[0][j] += p0;
        l_r[1][j] += p1;
        Pw[(kg * 4 + j) * 72 + n * 16 + l15] = (__bf16)p0;
        Pw[(16 + kg * 4 + j) * 72 + n * 16 + l15] = (__bf16)p1;
      }
    }
    // O += P @ V
#pragma unroll
    for (int kk = 0; kk < 2; ++kk) {
      bf16x8 pf0 = *(const bf16x8*)(Pw + (size_t)l15 * 72 + kk * 32 + kg * 8);
      bf16x8 pf1 = *(const bf16x8*)(Pw + (size_t)(16 + l15) * 72 + kk * 32 + kg * 8);
#pragma unroll
      for (int d = 0; d < 6; ++d) {
        bf16x8 vf = *(const bf16x8*)(Vc + ((d * 16 + l15) << 7) + cs[kk]);
        oa[0][d] = __builtin_amdgcn_mfma_f32_16x16x32_bf16(pf0, vf, oa[0][d], 0, 0, 0);
        oa[1][d] = __builtin_amdgcn_mfma_f32_16x16x32_bf16(pf1, vf, oa[1][d], 0, 0, 0);
      }
    }
    __builtin_amdgcn_s_barrier();
  }
#undef STAGE
  float inv[2][4];
#pragma unroll
  for (int f = 0; f < 2; ++f)
#pragma unroll
    for (int j = 0; j < 4; ++j) {
      float sum = l_r[f][j];
#pragma unroll
      for (int mk = 1; mk < 16; mk <<= 1) sum += __shfl_xor(sum, mk, 64);
      inv[f][j] = 1.0f / sum;
    }
#pragma unroll
  for (int f = 0; f < 2; ++f)
#pragma unroll
    for (int d = 0; d < 6; ++d)
#pragma unroll
      for (int j = 0; j < 4; ++j) {
        int tok = q0 + f * 16 + kg * 4 + j;
        O[((size_t)b * 1024 + tok) * 384 + h * 96 + d * 16 + l15] =
            f2bf(oa[f][d][j] * inv[f][j]);
      }
}

// ---------------- 128x128x32 bf16 GEMM, m97 2-barrier structure ------------
// A [Mdim][K] rm bf16, B [Ndim][K] rm bf16, D = A @ B^T.
// SWZ: 1D grid, gy==256 assumed; same-by blocks pinned to one XCD.
// EPI 1: gelu(D+bias) -> bf16 rm [M][N]
// EPI 2: rows=channels, cols=tokens; out[b,c,p]=res[b,c,p]+gamma[c]*(D+bias)
// EPI 3: QKV split: q -> [bh][n][96]; k -> [bh][n][128] (padded); v -> [bh][96][n]
template <int EPI, bool SWZ>
__global__ __launch_bounds__(256) void gemm_k(const u16* __restrict__ A,
                                              const u16* __restrict__ B, int M,
                                              int N, int K,
                                              const float* __restrict__ bias,
                                              const float* gamma,
                                              const float* res, void* outp,
                                              int nbx) {
  __shared__ u16 At[128 * 32];
  __shared__ u16 Bt[128 * 32];
  const int t = threadIdx.x;
  const int w = t >> 6, l = t & 63;
  const int l15 = l & 15, kg = l >> 4;
  int bx, by;
  if (SWZ) {
    int id = blockIdx.x;
    int xcd = id & 7, jj = id >> 3;
    int q = jj / nbx;
    bx = jj - q * nbx;
    by = xcd * 32 + q;            // 256/8 = 32 y-tiles per XCD
  } else {
    bx = blockIdx.x; by = blockIdx.y;
  }
  const int m0 = by * 128, n0 = bx * 128;
  const int wr = w >> 1, wc = w & 1;

  const int off1 = w * 1024 + l * 16;
  const int off2 = 4096 + w * 1024 + l * 16;
  const int r1 = off1 >> 6, c1 = off1 & 63;
  const int r2 = off2 >> 6, c2 = off2 & 63;
  const size_t ldab = (size_t)K * 2;
  const char* pa1 = (const char*)A + (size_t)(m0 + r1) * ldab + c1;
  const char* pa2 = (const char*)A + (size_t)(m0 + r2) * ldab + c2;
  const char* pb1 = (const char*)B + (size_t)(n0 + r1) * ldab + c1;
  const char* pb2 = (const char*)B + (size_t)(n0 + r2) * ldab + c2;
  char* At1 = (char*)At + w * 1024;
  char* At2 = (char*)At + 4096 + w * 1024;
  char* Bt1 = (char*)Bt + w * 1024;
  char* Bt2 = (char*)Bt + 4096 + w * 1024;

  f32x4 acc[4][4];
#pragma unroll
  for (int m = 0; m < 4; ++m)
#pragma unroll
    for (int n = 0; n < 4; ++n) acc[m][n] = {0.f, 0.f, 0.f, 0.f};

  const int nkt = K >> 5;
  for (int kt = 0; kt < nkt; ++kt) {
    g2l16(At1, pa1);
    g2l16(At2, pa2);
    g2l16(Bt1, pb1);
    g2l16(Bt2, pb2);
    pa1 += 64; pa2 += 64; pb1 += 64; pb2 += 64;
    __syncthreads();
    bf16x8 af[4], bfr[4];
#pragma unroll
    for (int m = 0; m < 4; ++m)
      af[m] = *(const bf16x8*)(At + (wr * 64 + m * 16 + l15) * 32 + kg * 8);
#pragma unroll
    for (int n = 0; n < 4; ++n)
      bfr[n] = *(const bf16x8*)(Bt + (wc * 64 + n * 16 + l15) * 32 + kg * 8);
#pragma unroll
    for (int m = 0; m < 4; ++m)
#pragma unroll
      for (int n = 0; n < 4; ++n)
        acc[m][n] = __builtin_amdgcn_mfma_f32_16x16x32_bf16(af[m], bfr[n], acc[m][n], 0, 0, 0);
    __syncthreads();
  }

  if (EPI == 1) {
    u16* out = (u16*)outp;
#pragma unroll
    for (int m = 0; m < 4; ++m) {
#pragma unroll
      for (int n = 0; n < 4; ++n) {
        int gcol = n0 + wc * 64 + n * 16 + l15;
        float bs = bias[gcol];
#pragma unroll
        for (int j = 0; j < 4; ++j) {
          int grow = m0 + wr * 64 + m * 16 + kg * 4 + j;
          float v = acc[m][n][j] + bs;
          v = 0.5f * v * (1.0f + erff(v * 0.70710678118f));
          out[(size_t)grow * N + gcol] = f2bf(v);
        }
      }
    }
  } else if (EPI == 2) {
    float* out = (float*)outp;
#pragma unroll
    for (int m = 0; m < 4; ++m) {
#pragma unroll
      for (int n = 0; n < 4; ++n) {
        int tok = n0 + wc * 64 + n * 16 + l15;
        int bb = tok >> 10, p = tok & 1023;
#pragma unroll
        for (int j = 0; j < 4; ++j) {
          int c = m0 + wr * 64 + m * 16 + kg * 4 + j;
          size_t addr = (((size_t)(bb * 384 + c)) << 10) + p;
          out[addr] = res[addr] + gamma[c] * (acc[m][n][j] + bias[c]);
        }
      }
    }
  } else {  // EPI == 3
    u16* Qp = (u16*)outp;
    u16* Kp = Qp + 12582912;       // Qn: 128bh*1024*96 u16
    u16* Vp = Kp + 16777216;       // Kn: 128bh*1024*128 u16
    const int sec = n0 / 384;      // uniform: 128-col tile within one section
#pragma unroll
    for (int m = 0; m < 4; ++m) {
      const int tokbase = m0 + wr * 64 + m * 16 + kg * 4;
      const int bb = tokbase >> 10, nb = tokbase & 1023;
#pragma unroll
      for (int n = 0; n < 4; ++n) {
        int gcol = n0 + wc * 64 + n * 16 + l15;
        int within = gcol - sec * 384;
        int hh = within / 96;
        int dd = within - hh * 96;
        float bs = bias[gcol];
        int bh = bb * 4 + hh;
        if (sec == 0) {
          u16* ptr = Qp + ((size_t)bh * 1024 + nb) * 96 + dd;
#pragma unroll
          for (int j = 0; j < 4; ++j) ptr[(size_t)j * 96] = f2bf(acc[m][n][j] + bs);
        } else if (sec == 1) {
          u16* ptr = Kp + (((size_t)bh * 1024 + nb) << 7) + dd;
#pragma unroll
          for (int j = 0; j < 4; ++j) ptr[(size_t)j << 7] = f2bf(acc[m][n][j] + bs);
        } else {
          u64 pk = 0;
#pragma unroll
          for (int j = 0; j < 4; ++j)
            pk |= (u64)f2bf(acc[m][n][j] + bs) << (16 * j);
          *(u64*)(Vp + ((size_t)bh * 96 + dd) * 1024 + nb) = pk;
        }
      }
    }
  }
}

// ---------------------------------------------------------------------------
extern "C" void kernel_launch(void* const* d_in, const int* in_sizes, int n_in,
                              void* d_out, int out_size, void* d_ws,
                              size_t ws_size, hipStream_t stream) {
  const float* x      = (const float*)d_in[0];
  const float* conv_w = (const float*)d_in[1];
  const float* conv_b = (const float*)d_in[2];
  const float* nxca_w = (const float*)d_in[3];
  const float* nxca_b = (const float*)d_in[4];
  const float* temp   = (const float*)d_in[5];
  const float* qkv_w  = (const float*)d_in[6];
  const float* qkv_b  = (const float*)d_in[7];
  const float* proj_w = (const float*)d_in[8];
  const float* proj_b = (const float*)d_in[9];
  const float* norm_w = (const float*)d_in[10];
  const float* norm_b = (const float*)d_in[11];
  const float* fc1_w  = (const float*)d_in[12];
  const float* fc1_b  = (const float*)d_in[13];
  const float* fc2_w  = (const float*)d_in[14];
  const float* fc2_b  = (const float*)d_in[15];
  const float* g_xca  = (const float*)d_in[16];
  const float* g_mlp  = (const float*)d_in[17];
  (void)in_sizes; (void)n_in; (void)out_size; (void)ws_size;

  char* ws = (char*)d_ws;
  float* xc  = (float*)(ws);                    // 50,331,648 B (f32 NCHW, shortcut)
  u16* Y     = (u16*)(ws + 50331648);           // 25,165,824 B (also Obuf)
  u16* Qn    = (u16*)(ws + 75497472);           // 25,165,824 B  [bh][1024][96]
  u16* Kn    = (u16*)(ws + 100663296);          // 33,554,432 B  [bh][1024][128]
  u16* Vt    = (u16*)(ws + 134217728);          // 25,165,824 B  [bh][96][1024]
  u16* Obuf  = Y;                               // attn O overlays Y (dead then)
  u16* H1    = Qn;                              // overlays Qn..: 100,663,296 B
  u16* wq    = (u16*)(ws + 176160768);
  u16* wp    = (u16*)(ws + 177045504);
  u16* w1    = (u16*)(ws + 177340416);
  u16* w2    = (u16*)(ws + 178520064);          // end: 179,699,712 B

  cvt_k<<<1728, 256, 0, stream>>>(qkv_w, wq, 442368);
  cvt_k<<<576, 256, 0, stream>>>(proj_w, wp, 147456);
  cvt_k<<<2304, 256, 0, stream>>>(fc1_w, w1, 589824);
  cvt_k<<<2304, 256, 0, stream>>>(fc2_w, w2, 589824);

  conv_k<<<49152, 256, 0, stream>>>(x, conv_w, conv_b, xc);
  ln_t_k<<<dim3(32, 32), 256, 0, stream>>>(xc, nxca_w, nxca_b, Y);
  gemm_k<3, true><<<2304, 256, 0, stream>>>(Y, wq, 32768, 1152, 384, qkv_b,
                                            nullptr, nullptr, Qn, 9);
  normqk_k<<<8192, 256, 0, stream>>>(Qn, Kn, temp);
  attn_k<<<1024, 256, 0, stream>>>(Qn, Kn, Vt, Obuf, temp);
  gemm_k<2, false><<<dim3(256, 3), 256, 0, stream>>>(wp, Obuf, 384, 32768, 384,
                                                     proj_b, g_xca, xc, xc, 0);
  ln_t_k<<<dim3(32, 32), 256, 0, stream>>>(xc, norm_w, norm_b, Y);
  gemm_k<1, true><<<3072, 256, 0, stream>>>(Y, w1, 32768, 1536, 384, fc1_b,
                                            nullptr, nullptr, H1, 12);
  gemm_k<2, false><<<dim3(256, 3), 256, 0, stream>>>(w2, H1, 384, 32768, 1536,
                                                     fc2_b, g_mlp, xc,
                                                     (float*)d_out, 0);
}

// Round 5
// 453.907 us; speedup vs baseline: 1.4873x; 1.0709x over previous
//
#include <hip/hip_runtime.h>
#include <cstdint>

typedef unsigned short u16;
typedef unsigned int u32;
typedef unsigned long long u64;
typedef __attribute__((ext_vector_type(4))) float f32x4;
typedef __attribute__((ext_vector_type(8))) __bf16 bf16x8;
typedef __attribute__((ext_vector_type(8))) u16 u16x8;

#define DEV __device__ __forceinline__

DEV u16 cvt16(float f) {
  __bf16 h = (__bf16)f;
  return __builtin_bit_cast(u16, h);
}
DEV u16 f2bf(float f) {  // round-to-nearest-even (for host-data convert)
  u32 u = __builtin_bit_cast(u32, f);
  u += 0x7fffu + ((u >> 16) & 1u);
  return (u16)(u >> 16);
}
DEV float bflo2f(u32 packed) { return __builtin_bit_cast(float, packed << 16); }
DEV float bfhi2f(u32 packed) { return __builtin_bit_cast(float, packed & 0xffff0000u); }

// async global->LDS, 16B per lane. lds pointer must be the WAVE-UNIFORM base;
// HW adds lane*16. Global pointer is per-lane.
DEV void g2l16(void* lds_wave_base, const void* gsrc) {
  __builtin_amdgcn_global_load_lds(
      (const __attribute__((address_space(1))) u32*)gsrc,
      (__attribute__((address_space(3))) u32*)lds_wave_base, 16, 0, 0);
}

DEV float gelu_tanh(float v) {
  // 0.5v(1+tanh(0.79788456(v+0.044715v^3))); max dev vs exact ~1e-3 << bf16 step
  float z = v * (0.7978845608f + 0.0356774081f * v * v);
  float e = __expf(2.0f * z);           // v_exp_f32 path
  float th = 1.0f - 2.0f / (e + 1.0f);
  return 0.5f * v * (1.0f + th);
}

// ---------------- depthwise conv 3x3 (first 192 ch) + passthrough ----------
__global__ __launch_bounds__(256) void conv_k(const float* __restrict__ x,
                                              const float* __restrict__ cw,
                                              const float* __restrict__ cb,
                                              float* __restrict__ xc) {
  int id = blockIdx.x * 256 + threadIdx.x;       // 32*384*1024 total
  int p = id & 1023;
  int bc = id >> 10;
  int c = bc % 384;
  float v;
  if (c < 192) {
    int hh = p >> 5, ww = p & 31;
    float a = cb[c];
    const float* xp = x + ((size_t)bc << 10);
    const float* wp = cw + c * 9;
#pragma unroll
    for (int dy = 0; dy < 3; ++dy) {
      int y = hh + dy - 1;
      if ((unsigned)y < 32u) {
#pragma unroll
        for (int dx = 0; dx < 3; ++dx) {
          int xw = ww + dx - 1;
          if ((unsigned)xw < 32u) a += xp[y * 32 + xw] * wp[dy * 3 + dx];
        }
      }
    }
    v = a;
  } else {
    v = x[id];
  }
  xc[id] = v;
}

// ---------------- f32 -> bf16 convert ----------------
__global__ __launch_bounds__(256) void cvt_k(const float* __restrict__ in,
                                             u16* __restrict__ out, int n) {
  int id = blockIdx.x * 256 + threadIdx.x;
  if (id < n) out[id] = f2bf(in[id]);
}

// ---------------- channel-LN (NCHW) + transpose to [token][C] bf16 ---------
__global__ __launch_bounds__(256) void ln_t_k(const float* __restrict__ X,
                                              const float* __restrict__ w,
                                              const float* __restrict__ bsh,
                                              u16* __restrict__ Y) {
  __shared__ float tile[384][33];
  __shared__ float ps[8][32], ps2[8][32];
  __shared__ float mean_s[32], rstd_s[32];
  const int b = blockIdx.y;
  const int p0 = blockIdx.x * 32;
  const int t = threadIdx.x;
  const int pl = t & 31, cg = t >> 5;
  const float* xb = X + (((size_t)b * 384) << 10) + p0 + pl;
  float s = 0.f, s2 = 0.f;
  for (int c = cg; c < 384; c += 8) {
    float v = xb[(size_t)c << 10];
    tile[c][pl] = v;
    s += v;
    s2 += v * v;
  }
  ps[cg][pl] = s;
  ps2[cg][pl] = s2;
  __syncthreads();
  if (t < 32) {
    float a = 0.f, a2 = 0.f;
#pragma unroll
    for (int g = 0; g < 8; ++g) { a += ps[g][t]; a2 += ps2[g][t]; }
    float mu = a * (1.f / 384.f);
    float var = a2 * (1.f / 384.f) - mu * mu;
    mean_s[t] = mu;
    rstd_s[t] = rsqrtf(var + 1e-6f);
  }
  __syncthreads();
  const int cl = t & 63, pg = t >> 6;
  for (int p = pg; p < 32; p += 4) {
    float mu = mean_s[p], rs = rstd_s[p];
    size_t orow = (((size_t)b << 10) + p0 + p) * 384;
#pragma unroll
    for (int cc = 0; cc < 6; ++cc) {
      int c = cc * 64 + cl;
      float v = (tile[c][p] - mu) * rs * w[c] + bsh[c];
      Y[orow + c] = f2bf(v);
    }
  }
}

// ---------------- L2-normalize rows of Qn (×temp, stride 96) and Kn (128) --
__global__ __launch_bounds__(256) void normqk_k(u16* __restrict__ Qn,
                                                u16* __restrict__ Kn,
                                                const float* __restrict__ temp) {
  const int t = threadIdx.x;
  const int w = t >> 6, l = t & 63;
  const int rg = l >> 4, li = l & 15;
  const int row = blockIdx.x * 16 + w * 4 + rg;   // bh*1024 + n
  const float tmp = temp[(row >> 10) & 3];
#pragma unroll
  for (int arr = 0; arr < 2; ++arr) {
    u16* p = arr ? (Kn + (size_t)row * 128 + li * 6)
                 : (Qn + (size_t)row * 96 + li * 6);
    u32 a = *(const u32*)p;
    u32 b2 = *(const u32*)(p + 2);
    u32 c = *(const u32*)(p + 4);
    float v[6] = {bflo2f(a), bfhi2f(a), bflo2f(b2), bfhi2f(b2), bflo2f(c), bfhi2f(c)};
    float ss = 0.f;
#pragma unroll
    for (int i = 0; i < 6; ++i) ss += v[i] * v[i];
#pragma unroll
    for (int mk = 1; mk < 16; mk <<= 1) ss += __shfl_xor(ss, mk, 64);
    float sc = 1.0f / fmaxf(sqrtf(ss), 1e-12f);
    if (arr == 0) sc *= tmp;     // fold temp into q̂
    u32 o0 = (u32)f2bf(v[0] * sc) | ((u32)f2bf(v[1] * sc) << 16);
    u32 o1 = (u32)f2bf(v[2] * sc) | ((u32)f2bf(v[3] * sc) << 16);
    u32 o2 = (u32)f2bf(v[4] * sc) | ((u32)f2bf(v[5] * sc) << 16);
    *(u32*)p = o0;
    *(u32*)(p + 2) = o1;
    *(u32*)(p + 4) = o2;
  }
}

// ---------------- flash attention v4: LDS dbuf pipeline --------------------
__global__ __launch_bounds__(256) void attn_k(const u16* __restrict__ Qn,
                                              const u16* __restrict__ Kg,
                                              const u16* __restrict__ Vg,
                                              u16* __restrict__ O,
                                              const float* __restrict__ temp) {
  __shared__ u16 Kt[2][8192];    // [64 rows][128 u16] swizzled
  __shared__ u16 Vt[2][6144];    // [96 rows][64 u16] swizzled
  __shared__ u16 Pt[4][2304];    // per-wave P [32][72]
  const int t = threadIdx.x;
  const int w = t >> 6, l = t & 63;
  const int l15 = l & 15, kg = l >> 4;
  const int id = blockIdx.x;
  const int xcd = id & 7, jj = id >> 3;          // jj in [0,128)
  const int bh = xcd * 16 + (jj >> 3);
  const int qb = jj & 7;
  const int b = bh >> 2, h = bh & 3;
  const int q0 = qb * 128 + w * 32;
  const u16* Qb = Qn + (size_t)bh * 98304;       // stride 96
  const u16* Kbg = Kg + (size_t)bh * 131072;     // stride 128
  const u16* Vbg = Vg + (size_t)bh * 98304;      // [96][1024]
  const float T = fabsf(temp[h]);

  u32 sK[4], sV[3];
#pragma unroll
  for (int j = 0; j < 4; ++j) {
    u32 s = w * 4096 + j * 1024 + l * 16;
    sK[j] = s ^ (((s >> 8) & 7) << 4);
  }
#pragma unroll
  for (int j = 0; j < 3; ++j) {
    u32 s = w * 3072 + j * 1024 + l * 16;
    u32 u = s ^ (((s >> 7) & 7) << 4);
    sV[j] = (u >> 7) * 2048 + (u & 127);
  }
  u32 cs[3];
#pragma unroll
  for (int kk = 0; kk < 3; ++kk)
    cs[kk] = (u32)((kk * 64 + kg * 16) ^ ((l15 & 7) << 4));

  bf16x8 qf[2][3];
#pragma unroll
  for (int f = 0; f < 2; ++f) {
    const u16* qp = Qb + (size_t)(q0 + f * 16 + l15) * 96 + kg * 8;
#pragma unroll
    for (int kk = 0; kk < 3; ++kk) qf[f][kk] = *(const bf16x8*)(qp + kk * 32);
  }
  f32x4 oa[2][6];
#pragma unroll
  for (int f = 0; f < 2; ++f)
#pragma unroll
    for (int d = 0; d < 6; ++d) oa[f][d] = {0.f, 0.f, 0.f, 0.f};
  float l_r[2][4] = {{0.f, 0.f, 0.f, 0.f}, {0.f, 0.f, 0.f, 0.f}};
  __bf16* Pw = (__bf16*)&Pt[w][0];

#define STAGE(buf, kv0)                                                        \
  {                                                                            \
    const char* kb = (const char*)Kbg + (size_t)(kv0) * 256;                   \
    const char* vb = (const char*)Vbg + (size_t)(kv0) * 2;                     \
    char* kd = (char*)&Kt[buf][0] + w * 4096;                                  \
    char* vd = (char*)&Vt[buf][0] + w * 3072;                                  \
    g2l16(kd, kb + sK[0]);                                                     \
    g2l16(kd + 1024, kb + sK[1]);                                              \
    g2l16(kd + 2048, kb + sK[2]);                                              \
    g2l16(kd + 3072, kb + sK[3]);                                              \
    g2l16(vd, vb + sV[0]);                                                     \
    g2l16(vd + 1024, vb + sV[1]);                                              \
    g2l16(vd + 2048, vb + sV[2]);                                              \
  }

  STAGE(0, 0);
  for (int tt = 0; tt < 16; ++tt) {
    const int cur = tt & 1;
    if (tt < 15) {
      STAGE(cur ^ 1, (tt + 1) * 64);
      asm volatile("s_waitcnt vmcnt(7)" ::: "memory");
    } else {
      asm volatile("s_waitcnt vmcnt(0)" ::: "memory");
    }
    __builtin_amdgcn_s_barrier();
    const char* Kc = (const char*)&Kt[cur][0];
    const char* Vc = (const char*)&Vt[cur][0];
    f32x4 s0[4], s1[4];
#pragma unroll
    for (int n = 0; n < 4; ++n) { s0[n] = {0.f, 0.f, 0.f, 0.f}; s1[n] = {0.f, 0.f, 0.f, 0.f}; }
#pragma unroll
    for (int n = 0; n < 4; ++n) {
      const char* krow = Kc + ((n * 16 + l15) << 8);
#pragma unroll
      for (int kk = 0; kk < 3; ++kk) {
        bf16x8 kf = *(const bf16x8*)(krow + cs[kk]);
        s0[n] = __builtin_amdgcn_mfma_f32_16x16x32_bf16(qf[0][kk], kf, s0[n], 0, 0, 0);
        s1[n] = __builtin_amdgcn_mfma_f32_16x16x32_bf16(qf[1][kk], kf, s1[n], 0, 0, 0);
      }
    }
#pragma unroll
    for (int n = 0; n < 4; ++n) {
#pragma unroll
      for (int j = 0; j < 4; ++j) {
        float p0 = __expf(s0[n][j] - T);
        float p1 = __expf(s1[n][j] - T);
        l_r[0][j] += p0;
        l_r[1][j] += p1;
        Pw[(kg * 4 + j) * 72 + n * 16 + l15] = (__bf16)p0;
        Pw[(16 + kg * 4 + j) * 72 + n * 16 + l15] = (__bf16)p1;
      }
    }
#pragma unroll
    for (int kk = 0; kk < 2; ++kk) {
      bf16x8 pf0 = *(const bf16x8*)(Pw + (size_t)l15 * 72 + kk * 32 + kg * 8);
      bf16x8 pf1 = *(const bf16x8*)(Pw + (size_t)(16 + l15) * 72 + kk * 32 + kg * 8);
#pragma unroll
      for (int d = 0; d < 6; ++d) {
        bf16x8 vf = *(const bf16x8*)(Vc + ((d * 16 + l15) << 7) + cs[kk]);
        oa[0][d] = __builtin_amdgcn_mfma_f32_16x16x32_bf16(pf0, vf, oa[0][d], 0, 0, 0);
        oa[1][d] = __builtin_amdgcn_mfma_f32_16x16x32_bf16(pf1, vf, oa[1][d], 0, 0, 0);
      }
    }
    __builtin_amdgcn_s_barrier();
  }
#undef STAGE
  float inv[2][4];
#pragma unroll
  for (int f = 0; f < 2; ++f)
#pragma unroll
    for (int j = 0; j < 4; ++j) {
      float sum = l_r[f][j];
#pragma unroll
      for (int mk = 1; mk < 16; mk <<= 1) sum += __shfl_xor(sum, mk, 64);
      inv[f][j] = 1.0f / sum;
    }
#pragma unroll
  for (int f = 0; f < 2; ++f)
#pragma unroll
    for (int d = 0; d < 6; ++d)
#pragma unroll
      for (int j = 0; j < 4; ++j) {
        int tok = q0 + f * 16 + kg * 4 + j;
        O[((size_t)b * 1024 + tok) * 384 + h * 96 + d * 16 + l15] =
            f2bf(oa[f][d][j] * inv[f][j]);
      }
}

// ---------------- 128x128 bf16 GEMM, double-buffered K-loop ----------------
// A [M][K] rm bf16, B [N][K] rm bf16, D = A @ B^T.
// SWZ 1: 1D grid, y-tiles pinned per-XCD (gy==256). SWZ 2: 768-block EPI2
//        mapping co-locating the 3 by-blocks of one bx on one XCD.
// EPI 1: gelu(D+bias) -> bf16 rm [M][N] via LDS-bounce epilogue
// EPI 2: rows=channels, cols=tokens; out[b,c,p]=res[b,c,p]+gamma[c]*(D+bias)
// EPI 3: QKV split: q -> [bh][n][96]; k -> [bh][n][128]; v -> [bh][96][n]
template <int EPI, int SWZ>
__global__ __launch_bounds__(256) void gemm_k(const u16* __restrict__ A,
                                              const u16* __restrict__ B, int M,
                                              int N, int K,
                                              const float* __restrict__ bias,
                                              const float* gamma,
                                              const float* res, void* outp,
                                              int nbx) {
  __shared__ u16 SM[16384];      // 32KB: At0|At1|Bt0|Bt1 (8KB each); Ct after
  const int t = threadIdx.x;
  const int w = t >> 6, l = t & 63;
  const int l15 = l & 15, kg = l >> 4;
  int bx, by;
  if (SWZ == 1) {
    int id = blockIdx.x;
    int xcd = id & 7, jj = id >> 3;
    int q = jj / nbx;
    bx = jj - q * nbx;
    by = xcd * 32 + q;
  } else if (SWZ == 2) {
    int id = blockIdx.x;           // 768 blocks
    int xcd = id & 7, jj = id >> 3;
    by = jj % 3;
    bx = (jj / 3) * 8 + xcd;
  } else {
    bx = blockIdx.x; by = blockIdx.y;
  }
  const int m0 = by * 128, n0 = bx * 128;
  const int wr = w >> 1, wc = w & 1;

  const int off1 = w * 1024 + l * 16;
  const int off2 = 4096 + w * 1024 + l * 16;
  const int r1 = off1 >> 6, c1 = off1 & 63;
  const int r2 = off2 >> 6, c2 = off2 & 63;
  const size_t ldab = (size_t)K * 2;
  const char* pa1 = (const char*)A + (size_t)(m0 + r1) * ldab + c1;
  const char* pa2 = (const char*)A + (size_t)(m0 + r2) * ldab + c2;
  const char* pb1 = (const char*)B + (size_t)(n0 + r1) * ldab + c1;
  const char* pb2 = (const char*)B + (size_t)(n0 + r2) * ldab + c2;
  char* SMc = (char*)SM;

  f32x4 acc[4][4];
#pragma unroll
  for (int m = 0; m < 4; ++m)
#pragma unroll
    for (int n = 0; n < 4; ++n) acc[m][n] = {0.f, 0.f, 0.f, 0.f};

  const int nkt = K >> 5;
  {
    char* ad = SMc + w * 1024;
    char* bd = SMc + 16384 + w * 1024;
    g2l16(ad, pa1); g2l16(ad + 4096, pa2);
    g2l16(bd, pb1); g2l16(bd + 4096, pb2);
  }
  __syncthreads();
  for (int kt = 0; kt < nkt; ++kt) {
    const int buf = kt & 1;
    if (kt + 1 < nkt) {            // stage NEXT tile into other buffer
      const size_t o = (size_t)(kt + 1) * 64;
      char* ad = SMc + (buf ^ 1) * 8192 + w * 1024;
      char* bd = SMc + 16384 + (buf ^ 1) * 8192 + w * 1024;
      g2l16(ad, pa1 + o); g2l16(ad + 4096, pa2 + o);
      g2l16(bd, pb1 + o); g2l16(bd + 4096, pb2 + o);
    }
    const u16* Ab = SM + buf * 4096;
    const u16* Bb = SM + 8192 + buf * 4096;
    bf16x8 af[4], bfr[4];
#pragma unroll
    for (int m = 0; m < 4; ++m)
      af[m] = *(const bf16x8*)(Ab + (wr * 64 + m * 16 + l15) * 32 + kg * 8);
#pragma unroll
    for (int n = 0; n < 4; ++n)
      bfr[n] = *(const bf16x8*)(Bb + (wc * 64 + n * 16 + l15) * 32 + kg * 8);
#pragma unroll
    for (int m = 0; m < 4; ++m)
#pragma unroll
      for (int n = 0; n < 4; ++n)
        acc[m][n] = __builtin_amdgcn_mfma_f32_16x16x32_bf16(af[m], bfr[n], acc[m][n], 0, 0, 0);
    __syncthreads();               // drains this iter's stage; guards reuse
  }

  if (EPI == 2) {
    float* out = (float*)outp;
#pragma unroll
    for (int m = 0; m < 4; ++m) {
#pragma unroll
      for (int n = 0; n < 4; ++n) {
        int tok = n0 + wc * 64 + n * 16 + l15;
        int bb = tok >> 10, p = tok & 1023;
#pragma unroll
        for (int j = 0; j < 4; ++j) {
          int c = m0 + wr * 64 + m * 16 + kg * 4 + j;
          size_t addr = (((size_t)(bb * 384 + c)) << 10) + p;
          out[addr] = res[addr] + gamma[c] * (acc[m][n][j] + bias[c]);
        }
      }
    }
    return;
  }

  const int sec = (EPI == 3) ? (n0 / 384) : 0;
  if (EPI == 3 && sec == 2) {      // V: transposed, packed u64 (efficient)
    u16* Vp = (u16*)outp + 12582912 + 16777216;
#pragma unroll
    for (int m = 0; m < 4; ++m) {
      const int tokbase = m0 + wr * 64 + m * 16 + kg * 4;
      const int bb = tokbase >> 10, nb = tokbase & 1023;
#pragma unroll
      for (int n = 0; n < 4; ++n) {
        int within = n0 - 768 + wc * 64 + n * 16 + l15;
        int hh = within / 96;
        int dd = within - hh * 96;
        float bs = bias[768 + within];
        int bh = bb * 4 + hh;
        u64 pk = 0;
#pragma unroll
        for (int j = 0; j < 4; ++j)
          pk |= (u64)cvt16(acc[m][n][j] + bs) << (16 * j);
        *(u64*)(Vp + ((size_t)bh * 96 + dd) * 1024 + nb) = pk;
      }
    }
    return;
  }

  // ---- LDS-bounce epilogue (EPI 1, and EPI 3 sec<2) ----
  {
    u16* Ct = SM;                  // 128x128 u16, overlays tiles (post-barrier)
    float bs[4];
#pragma unroll
    for (int n = 0; n < 4; ++n) bs[n] = bias[n0 + wc * 64 + n * 16 + l15];
    u16* cw_ = Ct + (wr * 64 + kg * 4) * 128 + wc * 64 + l15;
#pragma unroll
    for (int m = 0; m < 4; ++m)
#pragma unroll
      for (int n = 0; n < 4; ++n)
#pragma unroll
        for (int j = 0; j < 4; ++j) {
          float v = acc[m][n][j] + bs[n];
          if (EPI == 1) v = gelu_tanh(v);
          cw_[(m * 16 + j) * 128 + n * 16] = cvt16(v);
        }
    __syncthreads();
    const int row_l = w * 4 + (l >> 4);       // 0..15
    const int colc = (l & 15) * 8;            // 0..120
    const u16* src = Ct + row_l * 128 + colc;
    if (EPI == 1) {
      u16* dst = (u16*)outp + (size_t)(m0 + row_l) * N + n0 + colc;
#pragma unroll
      for (int rr = 0; rr < 8; ++rr)
        *(u16x8*)(dst + (size_t)rr * 16 * N) =
            *(const u16x8*)(src + rr * 16 * 128);
    } else {                                   // EPI3 q/k sections
      int within = n0 - sec * 384 + colc;      // [0,384)
      int hh = within / 96;
      int dd = within - hh * 96;
      int tokb = m0 + row_l;
      int bb = tokb >> 10, nb = tokb & 1023;   // bb,nb valid for all rr (+16k)
      int bh = bb * 4 + hh;
      u16* dp;
      int stride;
      if (sec == 0) {
        dp = (u16*)outp + ((size_t)bh * 1024 + nb) * 96 + dd;
        stride = 16 * 96;
      } else {
        dp = (u16*)outp + 12582912 + (((size_t)bh * 1024 + nb) << 7) + dd;
        stride = 16 * 128;
      }
#pragma unroll
      for (int rr = 0; rr < 8; ++rr) {
        *(u16x8*)dp = *(const u16x8*)(src + rr * 16 * 128);
        dp += stride;
      }
    }
  }
}

// ---------------------------------------------------------------------------
extern "C" void kernel_launch(void* const* d_in, const int* in_sizes, int n_in,
                              void* d_out, int out_size, void* d_ws,
                              size_t ws_size, hipStream_t stream) {
  const float* x      = (const float*)d_in[0];
  const float* conv_w = (const float*)d_in[1];
  const float* conv_b = (const float*)d_in[2];
  const float* nxca_w = (const float*)d_in[3];
  const float* nxca_b = (const float*)d_in[4];
  const float* temp   = (const float*)d_in[5];
  const float* qkv_w  = (const float*)d_in[6];
  const float* qkv_b  = (const float*)d_in[7];
  const float* proj_w = (const float*)d_in[8];
  const float* proj_b = (const float*)d_in[9];
  const float* norm_w = (const float*)d_in[10];
  const float* norm_b = (const float*)d_in[11];
  const float* fc1_w  = (const float*)d_in[12];
  const float* fc1_b  = (const float*)d_in[13];
  const float* fc2_w  = (const float*)d_in[14];
  const float* fc2_b  = (const float*)d_in[15];
  const float* g_xca  = (const float*)d_in[16];
  const float* g_mlp  = (const float*)d_in[17];
  (void)in_sizes; (void)n_in; (void)out_size; (void)ws_size;

  char* ws = (char*)d_ws;
  float* xc  = (float*)(ws);                    // 50,331,648 B (f32 NCHW, shortcut)
  u16* Y     = (u16*)(ws + 50331648);           // 25,165,824 B (also Obuf)
  u16* Qn    = (u16*)(ws + 75497472);           // 25,165,824 B  [bh][1024][96]
  u16* Kn    = (u16*)(ws + 100663296);          // 33,554,432 B  [bh][1024][128]
  u16* Vt    = (u16*)(ws + 134217728);          // 25,165,824 B  [bh][96][1024]
  u16* Obuf  = Y;                               // attn O overlays Y (dead then)
  u16* H1    = Qn;                              // overlays Qn..: 100,663,296 B
  u16* wq    = (u16*)(ws + 176160768);
  u16* wp    = (u16*)(ws + 177045504);
  u16* w1    = (u16*)(ws + 177340416);
  u16* w2    = (u16*)(ws + 178520064);          // end: 179,699,712 B

  cvt_k<<<1728, 256, 0, stream>>>(qkv_w, wq, 442368);
  cvt_k<<<576, 256, 0, stream>>>(proj_w, wp, 147456);
  cvt_k<<<2304, 256, 0, stream>>>(fc1_w, w1, 589824);
  cvt_k<<<2304, 256, 0, stream>>>(fc2_w, w2, 589824);

  conv_k<<<49152, 256, 0, stream>>>(x, conv_w, conv_b, xc);
  ln_t_k<<<dim3(32, 32), 256, 0, stream>>>(xc, nxca_w, nxca_b, Y);
  gemm_k<3, 1><<<2304, 256, 0, stream>>>(Y, wq, 32768, 1152, 384, qkv_b,
                                         nullptr, nullptr, Qn, 9);
  normqk_k<<<8192, 256, 0, stream>>>(Qn, Kn, temp);
  attn_k<<<1024, 256, 0, stream>>>(Qn, Kn, Vt, Obuf, temp);
  gemm_k<2, 2><<<768, 256, 0, stream>>>(wp, Obuf, 384, 32768, 384,
                                        proj_b, g_xca, xc, xc, 0);
  ln_t_k<<<dim3(32, 32), 256, 0, stream>>>(xc, norm_w, norm_b, Y);
  gemm_k<1, 1><<<3072, 256, 0, stream>>>(Y, w1, 32768, 1536, 384, fc1_b,
                                         nullptr, nullptr, H1, 12);
  gemm_k<2, 2><<<768, 256, 0, stream>>>(w2, H1, 384, 32768, 1536,
                                        fc2_b, g_mlp, xc, (float*)d_out, 0);
}

// Round 6
// 452.528 us; speedup vs baseline: 1.4918x; 1.0030x over previous
//
#include <hip/hip_runtime.h>
#include <cstdint>

typedef unsigned short u16;
typedef unsigned int u32;
typedef unsigned long long u64;
typedef __attribute__((ext_vector_type(4))) float f32x4;
typedef __attribute__((ext_vector_type(8))) __bf16 bf16x8;
typedef __attribute__((ext_vector_type(8))) u16 u16x8;

#define DEV __device__ __forceinline__

DEV u16 cvt16(float f) {
  __bf16 h = (__bf16)f;
  return __builtin_bit_cast(u16, h);
}
DEV u16 f2bf(float f) {  // round-to-nearest-even (for host-data convert)
  u32 u = __builtin_bit_cast(u32, f);
  u += 0x7fffu + ((u >> 16) & 1u);
  return (u16)(u >> 16);
}
DEV float bflo2f(u32 packed) { return __builtin_bit_cast(float, packed << 16); }
DEV float bfhi2f(u32 packed) { return __builtin_bit_cast(float, packed & 0xffff0000u); }

// async global->LDS, 16B per lane. lds pointer must be the WAVE-UNIFORM base;
// HW adds lane*16. Global pointer is per-lane.
DEV void g2l16(void* lds_wave_base, const void* gsrc) {
  __builtin_amdgcn_global_load_lds(
      (const __attribute__((address_space(1))) u32*)gsrc,
      (__attribute__((address_space(3))) u32*)lds_wave_base, 16, 0, 0);
}

DEV float gelu_tanh(float v) {
  float z = v * (0.7978845608f + 0.0356774081f * v * v);
  float e = __expf(2.0f * z);
  float th = 1.0f - 2.0f / (e + 1.0f);
  return 0.5f * v * (1.0f + th);
}

// ---------------- depthwise conv 3x3 (first 192 ch) + passthrough ----------
__global__ __launch_bounds__(256) void conv_k(const float* __restrict__ x,
                                              const float* __restrict__ cw,
                                              const float* __restrict__ cb,
                                              float* __restrict__ xc) {
  int id = blockIdx.x * 256 + threadIdx.x;       // 32*384*1024 total
  int p = id & 1023;
  int bc = id >> 10;
  int c = bc % 384;
  float v;
  if (c < 192) {
    int hh = p >> 5, ww = p & 31;
    float a = cb[c];
    const float* xp = x + ((size_t)bc << 10);
    const float* wp = cw + c * 9;
#pragma unroll
    for (int dy = 0; dy < 3; ++dy) {
      int y = hh + dy - 1;
      if ((unsigned)y < 32u) {
#pragma unroll
        for (int dx = 0; dx < 3; ++dx) {
          int xw = ww + dx - 1;
          if ((unsigned)xw < 32u) a += xp[y * 32 + xw] * wp[dy * 3 + dx];
        }
      }
    }
    v = a;
  } else {
    v = x[id];
  }
  xc[id] = v;
}

// ---------------- fused f32 -> bf16 convert of the 4 weight mats -----------
__global__ __launch_bounds__(256) void cvt4_k(const float* __restrict__ s0,
                                              const float* __restrict__ s1,
                                              const float* __restrict__ s2,
                                              const float* __restrict__ s3,
                                              u16* __restrict__ d0,
                                              u16* __restrict__ d1,
                                              u16* __restrict__ d2,
                                              u16* __restrict__ d3) {
  int id = blockIdx.x * 256 + threadIdx.x;
  if (id < 442368) d0[id] = f2bf(s0[id]);
  else if (id < 589824) d1[id - 442368] = f2bf(s1[id - 442368]);
  else if (id < 1179648) d2[id - 589824] = f2bf(s2[id - 589824]);
  else if (id < 1769472) d3[id - 1179648] = f2bf(s3[id - 1179648]);
}

// ---------------- channel-LN (NCHW) + transpose to [token][C] bf16 ---------
__global__ __launch_bounds__(256) void ln_t_k(const float* __restrict__ X,
                                              const float* __restrict__ w,
                                              const float* __restrict__ bsh,
                                              u16* __restrict__ Y) {
  __shared__ float tile[384][33];
  __shared__ float ps[8][32], ps2[8][32];
  __shared__ float mean_s[32], rstd_s[32];
  const int b = blockIdx.y;
  const int p0 = blockIdx.x * 32;
  const int t = threadIdx.x;
  const int pl = t & 31, cg = t >> 5;
  const float* xb = X + (((size_t)b * 384) << 10) + p0 + pl;
  float s = 0.f, s2 = 0.f;
  for (int c = cg; c < 384; c += 8) {
    float v = xb[(size_t)c << 10];
    tile[c][pl] = v;
    s += v;
    s2 += v * v;
  }
  ps[cg][pl] = s;
  ps2[cg][pl] = s2;
  __syncthreads();
  if (t < 32) {
    float a = 0.f, a2 = 0.f;
#pragma unroll
    for (int g = 0; g < 8; ++g) { a += ps[g][t]; a2 += ps2[g][t]; }
    float mu = a * (1.f / 384.f);
    float var = a2 * (1.f / 384.f) - mu * mu;
    mean_s[t] = mu;
    rstd_s[t] = rsqrtf(var + 1e-6f);
  }
  __syncthreads();
  const int cl = t & 63, pg = t >> 6;
  for (int p = pg; p < 32; p += 4) {
    float mu = mean_s[p], rs = rstd_s[p];
    size_t orow = (((size_t)b << 10) + p0 + p) * 384;
#pragma unroll
    for (int cc = 0; cc < 6; ++cc) {
      int c = cc * 64 + cl;
      float v = (tile[c][p] - mu) * rs * w[c] + bsh[c];
      Y[orow + c] = f2bf(v);
    }
  }
}

// ---------------- L2-normalize rows of Qn (×temp, stride 96) and Kn (128) --
__global__ __launch_bounds__(256) void normqk_k(u16* __restrict__ Qn,
                                                u16* __restrict__ Kn,
                                                const float* __restrict__ temp) {
  const int t = threadIdx.x;
  const int w = t >> 6, l = t & 63;
  const int rg = l >> 4, li = l & 15;
  const int row = blockIdx.x * 16 + w * 4 + rg;   // bh*1024 + n
  const float tmp = temp[(row >> 10) & 3];
#pragma unroll
  for (int arr = 0; arr < 2; ++arr) {
    u16* p = arr ? (Kn + (size_t)row * 128 + li * 6)
                 : (Qn + (size_t)row * 96 + li * 6);
    u32 a = *(const u32*)p;
    u32 b2 = *(const u32*)(p + 2);
    u32 c = *(const u32*)(p + 4);
    float v[6] = {bflo2f(a), bfhi2f(a), bflo2f(b2), bfhi2f(b2), bflo2f(c), bfhi2f(c)};
    float ss = 0.f;
#pragma unroll
    for (int i = 0; i < 6; ++i) ss += v[i] * v[i];
#pragma unroll
    for (int mk = 1; mk < 16; mk <<= 1) ss += __shfl_xor(ss, mk, 64);
    float sc = 1.0f / fmaxf(sqrtf(ss), 1e-12f);
    if (arr == 0) sc *= tmp;     // fold temp into q̂
    u32 o0 = (u32)f2bf(v[0] * sc) | ((u32)f2bf(v[1] * sc) << 16);
    u32 o1 = (u32)f2bf(v[2] * sc) | ((u32)f2bf(v[3] * sc) << 16);
    u32 o2 = (u32)f2bf(v[4] * sc) | ((u32)f2bf(v[5] * sc) << 16);
    *(u32*)p = o0;
    *(u32*)(p + 2) = o1;
    *(u32*)(p + 4) = o2;
  }
}

// ---------------- flash attention v5: KVBLK=32, 4 blocks/CU ----------------
// 1024 blocks (XCD-pinned), 4 waves × 32 q-rows. LDS 38.9KB -> 4 blocks/CU.
// K LDS [32][128u16] XOR-swizzled (pre-swizzled source, linear g2l dest);
// V LDS [96][32u16] linear (64B rows spread banks naturally).
__global__ __launch_bounds__(256) void attn_k(const u16* __restrict__ Qn,
                                              const u16* __restrict__ Kg,
                                              const u16* __restrict__ Vg,
                                              u16* __restrict__ O,
                                              const float* __restrict__ temp) {
  __shared__ u16 Kt[2][4096];    // [32 rows][128 u16] swizzled, 8KB each
  __shared__ u16 Vt[2][3072];    // [96 rows][32 u16] linear, 6KB each
  __shared__ u16 Pt[4][1280];    // per-wave P [32][40]
  const int t = threadIdx.x;
  const int w = t >> 6, l = t & 63;
  const int l15 = l & 15, kg = l >> 4;
  const int id = blockIdx.x;
  const int xcd = id & 7, jj = id >> 3;          // jj in [0,128)
  const int bh = xcd * 16 + (jj >> 3);
  const int qb = jj & 7;
  const int b = bh >> 2, h = bh & 3;
  const int q0 = qb * 128 + w * 32;
  const u16* Qb = Qn + (size_t)bh * 98304;       // stride 96
  const u16* Kbg = Kg + (size_t)bh * 131072;     // stride 128
  const u16* Vbg = Vg + (size_t)bh * 98304;      // [96][1024]
  const float T = fabsf(temp[h]);

  // staging source offsets. K: inverse-XOR-swizzled linear; V: linear remap.
  u32 sK[2], sV[2];
#pragma unroll
  for (int j = 0; j < 2; ++j) {
    u32 s = w * 2048 + j * 1024 + l * 16;        // 0..8191
    sK[j] = s ^ (((s >> 8) & 7) << 4);
  }
  const int wv = (w < 2) ? w : 2;                // wave3 duplicates wave2's V
#pragma unroll
  for (int j = 0; j < 2; ++j) {
    u32 s = wv * 2048 + j * 1024 + l * 16;       // 0..6127
    sV[j] = (s >> 6) * 2048 + (s & 63);          // d*rowstride + colbytes
  }
  u32 cs[3];
#pragma unroll
  for (int kk = 0; kk < 3; ++kk)
    cs[kk] = (u32)((kk * 64 + kg * 16) ^ ((l15 & 7) << 4));

  bf16x8 qf[2][3];
#pragma unroll
  for (int f = 0; f < 2; ++f) {
    const u16* qp = Qb + (size_t)(q0 + f * 16 + l15) * 96 + kg * 8;
#pragma unroll
    for (int kk = 0; kk < 3; ++kk) qf[f][kk] = *(const bf16x8*)(qp + kk * 32);
  }
  f32x4 oa[2][6];
#pragma unroll
  for (int f = 0; f < 2; ++f)
#pragma unroll
    for (int d = 0; d < 6; ++d) oa[f][d] = {0.f, 0.f, 0.f, 0.f};
  float l_r[2][4] = {{0.f, 0.f, 0.f, 0.f}, {0.f, 0.f, 0.f, 0.f}};
  __bf16* Pw = (__bf16*)&Pt[w][0];

#define STAGE(buf, kv0)                                                        \
  {                                                                            \
    const char* kb = (const char*)Kbg + (size_t)(kv0) * 256;                   \
    const char* vb = (const char*)Vbg + (size_t)(kv0) * 2;                     \
    char* kd = (char*)&Kt[buf][0] + w * 2048;                                  \
    char* vd = (char*)&Vt[buf][0] + wv * 2048;                                 \
    g2l16(kd, kb + sK[0]);                                                     \
    g2l16(kd + 1024, kb + sK[1]);                                              \
    g2l16(vd, vb + sV[0]);                                                     \
    g2l16(vd + 1024, vb + sV[1]);                                              \
  }

  STAGE(0, 0);
  for (int tt = 0; tt < 32; ++tt) {
    const int cur = tt & 1;
    if (tt < 31) {
      STAGE(cur ^ 1, (tt + 1) * 32);
      asm volatile("s_waitcnt vmcnt(4)" ::: "memory");
    } else {
      asm volatile("s_waitcnt vmcnt(0)" ::: "memory");
    }
    __builtin_amdgcn_s_barrier();
    __builtin_amdgcn_sched_barrier(0);
    const char* Kc = (const char*)&Kt[cur][0];
    const char* Vc = (const char*)&Vt[cur][0];
    // S = Qn @ Kn^T   (32 kv rows -> 2 col-frags)
    f32x4 s0[2], s1[2];
#pragma unroll
    for (int n = 0; n < 2; ++n) { s0[n] = {0.f, 0.f, 0.f, 0.f}; s1[n] = {0.f, 0.f, 0.f, 0.f}; }
#pragma unroll
    for (int n = 0; n < 2; ++n) {
      const char* krow = Kc + ((n * 16 + l15) << 8);
#pragma unroll
      for (int kk = 0; kk < 3; ++kk) {
        bf16x8 kf = *(const bf16x8*)(krow + cs[kk]);
        s0[n] = __builtin_amdgcn_mfma_f32_16x16x32_bf16(qf[0][kk], kf, s0[n], 0, 0, 0);
        s1[n] = __builtin_amdgcn_mfma_f32_16x16x32_bf16(qf[1][kk], kf, s1[n], 0, 0, 0);
      }
    }
#pragma unroll
    for (int n = 0; n < 2; ++n) {
#pragma unroll
      for (int j = 0; j < 4; ++j) {
        float p0 = __expf(s0[n][j] - T);
        float p1 = __expf(s1[n][j] - T);
        l_r[0][j] += p0;
        l_r[1][j] += p1;
        Pw[(kg * 4 + j) * 40 + n * 16 + l15] = (__bf16)p0;
        Pw[(16 + kg * 4 + j) * 40 + n * 16 + l15] = (__bf16)p1;
      }
    }
    // O += P @ V  (one k-chunk of 32)
    {
      bf16x8 pf0 = *(const bf16x8*)(Pw + (size_t)l15 * 40 + kg * 8);
      bf16x8 pf1 = *(const bf16x8*)(Pw + (size_t)(16 + l15) * 40 + kg * 8);
#pragma unroll
      for (int d = 0; d < 6; ++d) {
        bf16x8 vf = *(const bf16x8*)(Vc + ((d * 16 + l15) << 6) + kg * 16);
        oa[0][d] = __builtin_amdgcn_mfma_f32_16x16x32_bf16(pf0, vf, oa[0][d], 0, 0, 0);
        oa[1][d] = __builtin_amdgcn_mfma_f32_16x16x32_bf16(pf1, vf, oa[1][d], 0, 0, 0);
      }
    }
    __builtin_amdgcn_sched_barrier(0);
    __builtin_amdgcn_s_barrier();
  }
#undef STAGE
  float inv[2][4];
#pragma unroll
  for (int f = 0; f < 2; ++f)
#pragma unroll
    for (int j = 0; j < 4; ++j) {
      float sum = l_r[f][j];
#pragma unroll
      for (int mk = 1; mk < 16; mk <<= 1) sum += __shfl_xor(sum, mk, 64);
      inv[f][j] = 1.0f / sum;
    }
#pragma unroll
  for (int f = 0; f < 2; ++f)
#pragma unroll
    for (int d = 0; d < 6; ++d)
#pragma unroll
      for (int j = 0; j < 4; ++j) {
        int tok = q0 + f * 16 + kg * 4 + j;
        O[((size_t)b * 1024 + tok) * 384 + h * 96 + d * 16 + l15] =
            f2bf(oa[f][d][j] * inv[f][j]);
      }
}

// ---------------- 128x128 bf16 GEMM, dbuf + counted vmcnt ------------------
// A [M][K] rm bf16, B [N][K] rm bf16, D = A @ B^T.
// SWZ 1: 1D grid, y-tiles pinned per-XCD (gy==256). SWZ 2: 768-block EPI2
//        mapping co-locating the 3 by-blocks of one bx on one XCD.
// EPI 1: gelu(D+bias) -> bf16 rm [M][N] via LDS-bounce epilogue
// EPI 2: rows=channels, cols=tokens; out[b,c,p]=res[b,c,p]+gamma[c]*(D+bias)
// EPI 3: QKV split: q -> [bh][n][96]; k -> [bh][n][128]; v -> [bh][96][n]
template <int EPI, int SWZ>
__global__ __launch_bounds__(256) void gemm_k(const u16* __restrict__ A,
                                              const u16* __restrict__ B, int M,
                                              int N, int K,
                                              const float* __restrict__ bias,
                                              const float* gamma,
                                              const float* res, void* outp,
                                              int nbx) {
  __shared__ u16 SM[16384];      // 32KB: At0|At1|Bt0|Bt1 (8KB each); Ct after
  const int t = threadIdx.x;
  const int w = t >> 6, l = t & 63;
  const int l15 = l & 15, kg = l >> 4;
  int bx, by;
  if (SWZ == 1) {
    int id = blockIdx.x;
    int xcd = id & 7, jj = id >> 3;
    int q = jj / nbx;
    bx = jj - q * nbx;
    by = xcd * 32 + q;
  } else if (SWZ == 2) {
    int id = blockIdx.x;           // 768 blocks
    int xcd = id & 7, jj = id >> 3;
    by = jj % 3;
    bx = (jj / 3) * 8 + xcd;
  } else {
    bx = blockIdx.x; by = blockIdx.y;
  }
  const int m0 = by * 128, n0 = bx * 128;
  const int wr = w >> 1, wc = w & 1;

  const int off1 = w * 1024 + l * 16;
  const int off2 = 4096 + w * 1024 + l * 16;
  const int r1 = off1 >> 6, c1 = off1 & 63;
  const int r2 = off2 >> 6, c2 = off2 & 63;
  const size_t ldab = (size_t)K * 2;
  const char* pa1 = (const char*)A + (size_t)(m0 + r1) * ldab + c1;
  const char* pa2 = (const char*)A + (size_t)(m0 + r2) * ldab + c2;
  const char* pb1 = (const char*)B + (size_t)(n0 + r1) * ldab + c1;
  const char* pb2 = (const char*)B + (size_t)(n0 + r2) * ldab + c2;
  char* SMc = (char*)SM;

  f32x4 acc[4][4];
#pragma unroll
  for (int m = 0; m < 4; ++m)
#pragma unroll
    for (int n = 0; n < 4; ++n) acc[m][n] = {0.f, 0.f, 0.f, 0.f};

  const int nkt = K >> 5;
  {
    char* ad = SMc + w * 1024;
    char* bd = SMc + 16384 + w * 1024;
    g2l16(ad, pa1); g2l16(ad + 4096, pa2);
    g2l16(bd, pb1); g2l16(bd + 4096, pb2);
  }
  for (int kt = 0; kt < nkt; ++kt) {
    const int buf = kt & 1;
    if (kt + 1 < nkt) {            // stage NEXT tile into other buffer
      const size_t o = (size_t)(kt + 1) * 64;
      char* ad = SMc + (buf ^ 1) * 8192 + w * 1024;
      char* bd = SMc + 16384 + (buf ^ 1) * 8192 + w * 1024;
      g2l16(ad, pa1 + o); g2l16(ad + 4096, pa2 + o);
      g2l16(bd, pb1 + o); g2l16(bd + 4096, pb2 + o);
      asm volatile("s_waitcnt vmcnt(4)" ::: "memory");   // cur tile landed
    } else {
      asm volatile("s_waitcnt vmcnt(0)" ::: "memory");
    }
    __builtin_amdgcn_s_barrier();
    __builtin_amdgcn_sched_barrier(0);
    const u16* Ab = SM + buf * 4096;
    const u16* Bb = SM + 8192 + buf * 4096;
    bf16x8 af[4], bfr[4];
#pragma unroll
    for (int m = 0; m < 4; ++m)
      af[m] = *(const bf16x8*)(Ab + (wr * 64 + m * 16 + l15) * 32 + kg * 8);
#pragma unroll
    for (int n = 0; n < 4; ++n)
      bfr[n] = *(const bf16x8*)(Bb + (wc * 64 + n * 16 + l15) * 32 + kg * 8);
#pragma unroll
    for (int m = 0; m < 4; ++m)
#pragma unroll
      for (int n = 0; n < 4; ++n)
        acc[m][n] = __builtin_amdgcn_mfma_f32_16x16x32_bf16(af[m], bfr[n], acc[m][n], 0, 0, 0);
    __builtin_amdgcn_sched_barrier(0);
    __builtin_amdgcn_s_barrier();  // all waves done reading buf
  }

  if (EPI == 2) {
    float* out = (float*)outp;
#pragma unroll
    for (int m = 0; m < 4; ++m) {
#pragma unroll
      for (int n = 0; n < 4; ++n) {
        int tok = n0 + wc * 64 + n * 16 + l15;
        int bb = tok >> 10, p = tok & 1023;
#pragma unroll
        for (int j = 0; j < 4; ++j) {
          int c = m0 + wr * 64 + m * 16 + kg * 4 + j;
          size_t addr = (((size_t)(bb * 384 + c)) << 10) + p;
          out[addr] = res[addr] + gamma[c] * (acc[m][n][j] + bias[c]);
        }
      }
    }
    return;
  }

  const int sec = (EPI == 3) ? (n0 / 384) : 0;
  if (EPI == 3 && sec == 2) {      // V: transposed, packed u64
    u16* Vp = (u16*)outp + 12582912 + 16777216;
#pragma unroll
    for (int m = 0; m < 4; ++m) {
      const int tokbase = m0 + wr * 64 + m * 16 + kg * 4;
      const int bb = tokbase >> 10, nb = tokbase & 1023;
#pragma unroll
      for (int n = 0; n < 4; ++n) {
        int within = n0 - 768 + wc * 64 + n * 16 + l15;
        int hh = within / 96;
        int dd = within - hh * 96;
        float bs = bias[768 + within];
        int bh = bb * 4 + hh;
        u64 pk = 0;
#pragma unroll
        for (int j = 0; j < 4; ++j)
          pk |= (u64)cvt16(acc[m][n][j] + bs) << (16 * j);
        *(u64*)(Vp + ((size_t)bh * 96 + dd) * 1024 + nb) = pk;
      }
    }
    return;
  }

  // ---- LDS-bounce epilogue (EPI 1, and EPI 3 sec<2) ----
  {
    u16* Ct = SM;                  // 128x128 u16, overlays tiles (post-barrier)
    float bs[4];
#pragma unroll
    for (int n = 0; n < 4; ++n) bs[n] = bias[n0 + wc * 64 + n * 16 + l15];
    u16* cw_ = Ct + (wr * 64 + kg * 4) * 128 + wc * 64 + l15;
#pragma unroll
    for (int m = 0; m < 4; ++m)
#pragma unroll
      for (int n = 0; n < 4; ++n)
#pragma unroll
        for (int j = 0; j < 4; ++j) {
          float v = acc[m][n][j] + bs[n];
          if (EPI == 1) v = gelu_tanh(v);
          cw_[(m * 16 + j) * 128 + n * 16] = cvt16(v);
        }
    __syncthreads();
    const int row_l = w * 4 + (l >> 4);       // 0..15
    const int colc = (l & 15) * 8;            // 0..120
    const u16* src = Ct + row_l * 128 + colc;
    if (EPI == 1) {
      u16* dst = (u16*)outp + (size_t)(m0 + row_l) * N + n0 + colc;
#pragma unroll
      for (int rr = 0; rr < 8; ++rr)
        *(u16x8*)(dst + (size_t)rr * 16 * N) =
            *(const u16x8*)(src + rr * 16 * 128);
    } else {                                   // EPI3 q/k sections
      int within = n0 - sec * 384 + colc;      // [0,384)
      int hh = within / 96;
      int dd = within - hh * 96;
      int tokb = m0 + row_l;
      int bb = tokb >> 10, nb = tokb & 1023;
      int bh = bb * 4 + hh;
      u16* dp;
      int stride;
      if (sec == 0) {
        dp = (u16*)outp + ((size_t)bh * 1024 + nb) * 96 + dd;
        stride = 16 * 96;
      } else {
        dp = (u16*)outp + 12582912 + (((size_t)bh * 1024 + nb) << 7) + dd;
        stride = 16 * 128;
      }
#pragma unroll
      for (int rr = 0; rr < 8; ++rr) {
        *(u16x8*)dp = *(const u16x8*)(src + rr * 16 * 128);
        dp += stride;
      }
    }
  }
}

// ---------------------------------------------------------------------------
extern "C" void kernel_launch(void* const* d_in, const int* in_sizes, int n_in,
                              void* d_out, int out_size, void* d_ws,
                              size_t ws_size, hipStream_t stream) {
  const float* x      = (const float*)d_in[0];
  const float* conv_w = (const float*)d_in[1];
  const float* conv_b = (const float*)d_in[2];
  const float* nxca_w = (const float*)d_in[3];
  const float* nxca_b = (const float*)d_in[4];
  const float* temp   = (const float*)d_in[5];
  const float* qkv_w  = (const float*)d_in[6];
  const float* qkv_b  = (const float*)d_in[7];
  const float* proj_w = (const float*)d_in[8];
  const float* proj_b = (const float*)d_in[9];
  const float* norm_w = (const float*)d_in[10];
  const float* norm_b = (const float*)d_in[11];
  const float* fc1_w  = (const float*)d_in[12];
  const float* fc1_b  = (const float*)d_in[13];
  const float* fc2_w  = (const float*)d_in[14];
  const float* fc2_b  = (const float*)d_in[15];
  const float* g_xca  = (const float*)d_in[16];
  const float* g_mlp  = (const float*)d_in[17];
  (void)in_sizes; (void)n_in; (void)out_size; (void)ws_size;

  char* ws = (char*)d_ws;
  float* xc  = (float*)(ws);                    // 50,331,648 B (f32 NCHW, shortcut)
  u16* Y     = (u16*)(ws + 50331648);           // 25,165,824 B (also Obuf)
  u16* Qn    = (u16*)(ws + 75497472);           // 25,165,824 B  [bh][1024][96]
  u16* Kn    = (u16*)(ws + 100663296);          // 33,554,432 B  [bh][1024][128]
  u16* Vt    = (u16*)(ws + 134217728);          // 25,165,824 B  [bh][96][1024]
  u16* Obuf  = Y;                               // attn O overlays Y (dead then)
  u16* H1    = Qn;                              // overlays Qn..: 100,663,296 B
  u16* wq    = (u16*)(ws + 176160768);
  u16* wp    = (u16*)(ws + 177045504);
  u16* w1    = (u16*)(ws + 177340416);
  u16* w2    = (u16*)(ws + 178520064);          // end: 179,699,712 B

  cvt4_k<<<6912, 256, 0, stream>>>(qkv_w, proj_w, fc1_w, fc2_w, wq, wp, w1, w2);

  conv_k<<<49152, 256, 0, stream>>>(x, conv_w, conv_b, xc);
  ln_t_k<<<dim3(32, 32), 256, 0, stream>>>(xc, nxca_w, nxca_b, Y);
  gemm_k<3, 1><<<2304, 256, 0, stream>>>(Y, wq, 32768, 1152, 384, qkv_b,
                                         nullptr, nullptr, Qn, 9);
  normqk_k<<<8192, 256, 0, stream>>>(Qn, Kn, temp);
  attn_k<<<1024, 256, 0, stream>>>(Qn, Kn, Vt, Obuf, temp);
  gemm_k<2, 2><<<768, 256, 0, stream>>>(wp, Obuf, 384, 32768, 384,
                                        proj_b, g_xca, xc, xc, 0);
  ln_t_k<<<dim3(32, 32), 256, 0, stream>>>(xc, norm_w, norm_b, Y);
  gemm_k<1, 1><<<3072, 256, 0, stream>>>(Y, w1, 32768, 1536, 384, fc1_b,
                                         nullptr, nullptr, H1, 12);
  gemm_k<2, 2><<<768, 256, 0, stream>>>(w2, H1, 384, 32768, 1536,
                                        fc2_b, g_mlp, xc, (float*)d_out, 0);
}

// Round 7
// 413.184 us; speedup vs baseline: 1.6339x; 1.0952x over previous
//
#include <hip/hip_runtime.h>
#include <cstdint>

typedef unsigned short u16;
typedef unsigned int u32;
typedef unsigned long long u64;
typedef __attribute__((ext_vector_type(4))) float f32x4;
typedef __attribute__((ext_vector_type(8))) __bf16 bf16x8;
typedef __attribute__((ext_vector_type(8))) u16 u16x8;

#define DEV __device__ __forceinline__

DEV u16 cvt16(float f) {
  __bf16 h = (__bf16)f;
  return __builtin_bit_cast(u16, h);
}
DEV u16 f2bf(float f) {  // round-to-nearest-even (for host-data convert)
  u32 u = __builtin_bit_cast(u32, f);
  u += 0x7fffu + ((u >> 16) & 1u);
  return (u16)(u >> 16);
}
DEV float bflo2f(u32 packed) { return __builtin_bit_cast(float, packed << 16); }
DEV float bfhi2f(u32 packed) { return __builtin_bit_cast(float, packed & 0xffff0000u); }

// async global->LDS, 16B per lane. lds pointer must be the WAVE-UNIFORM base;
// HW adds lane*16. Global pointer is per-lane.
DEV void g2l16(void* lds_wave_base, const void* gsrc) {
  __builtin_amdgcn_global_load_lds(
      (const __attribute__((address_space(1))) u32*)gsrc,
      (__attribute__((address_space(3))) u32*)lds_wave_base, 16, 0, 0);
}

DEV float gelu_tanh(float v) {
  float z = v * (0.7978845608f + 0.0356774081f * v * v);
  float e = __expf(2.0f * z);
  float th = 1.0f - 2.0f / (e + 1.0f);
  return 0.5f * v * (1.0f + th);
}

// ---------------- depthwise conv 3x3 (first 192 ch) + passthrough ----------
// One block per (b,c) image; thread handles 4 consecutive pixels (float4).
__global__ __launch_bounds__(256) void conv_k(const float* __restrict__ x,
                                              const float* __restrict__ cw,
                                              const float* __restrict__ cb,
                                              float* __restrict__ xc) {
  const int bc = blockIdx.x;             // b*384 + c
  const int c = bc % 384;
  const int p4 = threadIdx.x * 4;
  const float* xp = x + ((size_t)bc << 10);
  float* op = xc + ((size_t)bc << 10) + p4;
  if (c >= 192) {
    *(f32x4*)op = *(const f32x4*)(xp + p4);
    return;
  }
  const int hh = p4 >> 5, ww0 = p4 & 31;
  const float* wb = cw + c * 9;
  float b0 = cb[c];
  float a0 = b0, a1 = b0, a2 = b0, a3 = b0;
#pragma unroll
  for (int dy = 0; dy < 3; ++dy) {
    int y = hh + dy - 1;
    if ((unsigned)y < 32u) {
      const float* rp = xp + y * 32 + ww0;
      f32x4 m = *(const f32x4*)rp;
      float lft = (ww0 > 0) ? rp[-1] : 0.f;
      float rgt = (ww0 < 28) ? rp[4] : 0.f;
      float w0 = wb[dy * 3], w1 = wb[dy * 3 + 1], w2 = wb[dy * 3 + 2];
      a0 += lft * w0 + m[0] * w1 + m[1] * w2;
      a1 += m[0] * w0 + m[1] * w1 + m[2] * w2;
      a2 += m[1] * w0 + m[2] * w1 + m[3] * w2;
      a3 += m[2] * w0 + m[3] * w1 + rgt * w2;
    }
  }
  f32x4 r = {a0, a1, a2, a3};
  *(f32x4*)op = r;
}

// ---------------- fused f32 -> bf16 convert of the 4 weight mats -----------
__global__ __launch_bounds__(256) void cvt4_k(const float* __restrict__ s0,
                                              const float* __restrict__ s1,
                                              const float* __restrict__ s2,
                                              const float* __restrict__ s3,
                                              u16* __restrict__ d0,
                                              u16* __restrict__ d1,
                                              u16* __restrict__ d2,
                                              u16* __restrict__ d3) {
  int id = blockIdx.x * 256 + threadIdx.x;
  if (id < 442368) d0[id] = f2bf(s0[id]);
  else if (id < 589824) d1[id - 442368] = f2bf(s1[id - 442368]);
  else if (id < 1179648) d2[id - 589824] = f2bf(s2[id - 589824]);
  else if (id < 1769472) d3[id - 1179648] = f2bf(s3[id - 1179648]);
}

// ---------------- channel-LN (NCHW) + transpose to [token][C] bf16 ---------
__global__ __launch_bounds__(256) void ln_t_k(const float* __restrict__ X,
                                              const float* __restrict__ w,
                                              const float* __restrict__ bsh,
                                              u16* __restrict__ Y) {
  __shared__ float tile[384][33];
  __shared__ float ps[8][32], ps2[8][32];
  __shared__ float mean_s[32], rstd_s[32];
  const int b = blockIdx.y;
  const int p0 = blockIdx.x * 32;
  const int t = threadIdx.x;
  const int pl = t & 31, cg = t >> 5;
  const float* xb = X + (((size_t)b * 384) << 10) + p0 + pl;
  float s = 0.f, s2 = 0.f;
  for (int c = cg; c < 384; c += 8) {
    float v = xb[(size_t)c << 10];
    tile[c][pl] = v;
    s += v;
    s2 += v * v;
  }
  ps[cg][pl] = s;
  ps2[cg][pl] = s2;
  __syncthreads();
  if (t < 32) {
    float a = 0.f, a2 = 0.f;
#pragma unroll
    for (int g = 0; g < 8; ++g) { a += ps[g][t]; a2 += ps2[g][t]; }
    float mu = a * (1.f / 384.f);
    float var = a2 * (1.f / 384.f) - mu * mu;
    mean_s[t] = mu;
    rstd_s[t] = rsqrtf(var + 1e-6f);
  }
  __syncthreads();
  const int cl = t & 63, pg = t >> 6;
  for (int p = pg; p < 32; p += 4) {
    float mu = mean_s[p], rs = rstd_s[p];
    size_t orow = (((size_t)b << 10) + p0 + p) * 384;
#pragma unroll
    for (int cc = 0; cc < 6; ++cc) {
      int c = cc * 64 + cl;
      float v = (tile[c][p] - mu) * rs * w[c] + bsh[c];
      Y[orow + c] = f2bf(v);
    }
  }
}

// ---------------- L2-normalize q(×temp) and k heads in QKV rows ------------
// QKV rows [32768][1152]; per token: 8 segments ({q,k}×4 heads) of 96.
__global__ __launch_bounds__(256) void normqk_k(u16* __restrict__ QKV,
                                                const float* __restrict__ temp) {
  const int t = threadIdx.x;
  const int w = t >> 6, l = t & 63;
  const int rg = l >> 4, li = l & 15;
  const int tok = blockIdx.x * 16 + w * 4 + rg;
  u16* rowp = QKV + (size_t)tok * 1152;
#pragma unroll
  for (int seg = 0; seg < 8; ++seg) {
    const int h = seg & 3, isK = seg >> 2;
    u16* p = rowp + isK * 384 + h * 96 + li * 6;
    u32 a = *(const u32*)p;
    u32 b2 = *(const u32*)(p + 2);
    u32 c = *(const u32*)(p + 4);
    float v[6] = {bflo2f(a), bfhi2f(a), bflo2f(b2), bfhi2f(b2), bflo2f(c), bfhi2f(c)};
    float ss = 0.f;
#pragma unroll
    for (int i = 0; i < 6; ++i) ss += v[i] * v[i];
#pragma unroll
    for (int mk = 1; mk < 16; mk <<= 1) ss += __shfl_xor(ss, mk, 64);
    float sc = 1.0f / fmaxf(sqrtf(ss), 1e-12f);
    if (!isK) sc *= temp[h];     // fold temp into q̂
    u32 o0 = (u32)f2bf(v[0] * sc) | ((u32)f2bf(v[1] * sc) << 16);
    u32 o1 = (u32)f2bf(v[2] * sc) | ((u32)f2bf(v[3] * sc) << 16);
    u32 o2 = (u32)f2bf(v[4] * sc) | ((u32)f2bf(v[5] * sc) << 16);
    *(u32*)p = o0;
    *(u32*)(p + 2) = o1;
    *(u32*)(p + 4) = o2;
  }
}

// ---------------- flash attention v6: round-5 structure, QKV-row source ----
// 1024 blocks (XCD-pinned), 4 waves × 32 q-rows, KVBLK=64.
// K LDS [64][128u16] XOR-swizzled; source gathered per-lane from the
// consolidated QKV rows (192B data + 64B hole per LDS row).
// V LDS [96][64u16] XOR-swizzled from pre-transposed Vt. vmcnt(7), 2 barriers.
__global__ __launch_bounds__(256) void attn_k(const u16* __restrict__ QKV,
                                              const u16* __restrict__ Vg,
                                              u16* __restrict__ O,
                                              const float* __restrict__ temp) {
  __shared__ u16 Kt[2][8192];    // [64 rows][128 u16] swizzled, 16KB each
  __shared__ u16 Vt[2][6144];    // [96 rows][64 u16] swizzled, 12KB each
  __shared__ u16 Pt[4][2304];    // per-wave P [32][72]
  const int t = threadIdx.x;
  const int w = t >> 6, l = t & 63;
  const int l15 = l & 15, kg = l >> 4;
  const int id = blockIdx.x;
  const int xcd = id & 7, jj = id >> 3;          // jj in [0,128)
  const int bh = xcd * 16 + (jj >> 3);
  const int qb = jj & 7;
  const int b = bh >> 2, h = bh & 3;
  const int q0 = qb * 128 + w * 32;
  const u16* Qb = QKV + (size_t)b * 1024 * 1152;
  const char* Kbg = (const char*)QKV + (size_t)b * 1024 * 2304 + 768 + 192 * h;
  const u16* Vbg = Vg + (size_t)bh * 98304;      // [96][1024]
  const float T = fabsf(temp[h]);

  // staging source offsets (per-lane). K: LDS linear (row,rem) holds global
  // col rem^((row&7)<<4); cols >=192 are holes (dummy src 0).
  u32 sK[4], sV[3];
#pragma unroll
  for (int j = 0; j < 4; ++j) {
    u32 s = w * 4096 + j * 1024 + l * 16;
    u32 row = s >> 8, rem = s & 255;
    u32 X = rem ^ ((row & 7) << 4);
    sK[j] = (X < 192) ? (row * 2304 + X) : 0u;
  }
#pragma unroll
  for (int j = 0; j < 3; ++j) {
    u32 s = w * 3072 + j * 1024 + l * 16;
    u32 u = s ^ (((s >> 7) & 7) << 4);
    sV[j] = (u >> 7) * 2048 + (u & 127);
  }
  u32 cs[3];
#pragma unroll
  for (int kk = 0; kk < 3; ++kk)
    cs[kk] = (u32)((kk * 64 + kg * 16) ^ ((l15 & 7) << 4));

  bf16x8 qf[2][3];
#pragma unroll
  for (int f = 0; f < 2; ++f) {
    const u16* qp = Qb + (size_t)(q0 + f * 16 + l15) * 1152 + h * 96 + kg * 8;
#pragma unroll
    for (int kk = 0; kk < 3; ++kk) qf[f][kk] = *(const bf16x8*)(qp + kk * 32);
  }
  f32x4 oa[2][6];
#pragma unroll
  for (int f = 0; f < 2; ++f)
#pragma unroll
    for (int d = 0; d < 6; ++d) oa[f][d] = {0.f, 0.f, 0.f, 0.f};
  float l_r[2][4] = {{0.f, 0.f, 0.f, 0.f}, {0.f, 0.f, 0.f, 0.f}};
  __bf16* Pw = (__bf16*)&Pt[w][0];

#define STAGE(buf, kv0)                                                        \
  {                                                                            \
    const char* kb = Kbg + (size_t)(kv0) * 2304;                               \
    const char* vb = (const char*)Vbg + (size_t)(kv0) * 2;                     \
    char* kd = (char*)&Kt[buf][0] + w * 4096;                                  \
    char* vd = (char*)&Vt[buf][0] + w * 3072;                                  \
    g2l16(kd, kb + sK[0]);                                                     \
    g2l16(kd + 1024, kb + sK[1]);                                              \
    g2l16(kd + 2048, kb + sK[2]);                                              \
    g2l16(kd + 3072, kb + sK[3]);                                              \
    g2l16(vd, vb + sV[0]);                                                     \
    g2l16(vd + 1024, vb + sV[1]);                                              \
    g2l16(vd + 2048, vb + sV[2]);                                              \
  }

  STAGE(0, 0);
  for (int tt = 0; tt < 16; ++tt) {
    const int cur = tt & 1;
    if (tt < 15) {
      STAGE(cur ^ 1, (tt + 1) * 64);
      asm volatile("s_waitcnt vmcnt(7)" ::: "memory");
    } else {
      asm volatile("s_waitcnt vmcnt(0)" ::: "memory");
    }
    __builtin_amdgcn_s_barrier();
    const char* Kc = (const char*)&Kt[cur][0];
    const char* Vc = (const char*)&Vt[cur][0];
    f32x4 s0[4], s1[4];
#pragma unroll
    for (int n = 0; n < 4; ++n) { s0[n] = {0.f, 0.f, 0.f, 0.f}; s1[n] = {0.f, 0.f, 0.f, 0.f}; }
#pragma unroll
    for (int n = 0; n < 4; ++n) {
      const char* krow = Kc + ((n * 16 + l15) << 8);
#pragma unroll
      for (int kk = 0; kk < 3; ++kk) {
        bf16x8 kf = *(const bf16x8*)(krow + cs[kk]);
        s0[n] = __builtin_amdgcn_mfma_f32_16x16x32_bf16(qf[0][kk], kf, s0[n], 0, 0, 0);
        s1[n] = __builtin_amdgcn_mfma_f32_16x16x32_bf16(qf[1][kk], kf, s1[n], 0, 0, 0);
      }
    }
#pragma unroll
    for (int n = 0; n < 4; ++n) {
#pragma unroll
      for (int j = 0; j < 4; ++j) {
        float p0 = __expf(s0[n][j] - T);
        float p1 = __expf(s1[n][j] - T);
        l_r[0][j] += p0;
        l_r[1][j] += p1;
        Pw[(kg * 4 + j) * 72 + n * 16 + l15] = (__bf16)p0;
        Pw[(16 + kg * 4 + j) * 72 + n * 16 + l15] = (__bf16)p1;
      }
    }
#pragma unroll
    for (int kk = 0; kk < 2; ++kk) {
      bf16x8 pf0 = *(const bf16x8*)(Pw + (size_t)l15 * 72 + kk * 32 + kg * 8);
      bf16x8 pf1 = *(const bf16x8*)(Pw + (size_t)(16 + l15) * 72 + kk * 32 + kg * 8);
#pragma unroll
      for (int d = 0; d < 6; ++d) {
        bf16x8 vf = *(const bf16x8*)(Vc + ((d * 16 + l15) << 7) + cs[kk]);
        oa[0][d] = __builtin_amdgcn_mfma_f32_16x16x32_bf16(pf0, vf, oa[0][d], 0, 0, 0);
        oa[1][d] = __builtin_amdgcn_mfma_f32_16x16x32_bf16(pf1, vf, oa[1][d], 0, 0, 0);
      }
    }
    __builtin_amdgcn_s_barrier();
  }
#undef STAGE
  float inv[2][4];
#pragma unroll
  for (int f = 0; f < 2; ++f)
#pragma unroll
    for (int j = 0; j < 4; ++j) {
      float sum = l_r[f][j];
#pragma unroll
      for (int mk = 1; mk < 16; mk <<= 1) sum += __shfl_xor(sum, mk, 64);
      inv[f][j] = 1.0f / sum;
    }
#pragma unroll
  for (int f = 0; f < 2; ++f)
#pragma unroll
    for (int d = 0; d < 6; ++d)
#pragma unroll
      for (int j = 0; j < 4; ++j) {
        int tok = q0 + f * 16 + kg * 4 + j;
        O[((size_t)b * 1024 + tok) * 384 + h * 96 + d * 16 + l15] =
            f2bf(oa[f][d][j] * inv[f][j]);
      }
}

// ---------------- 128x128 bf16 GEMM, dbuf + counted vmcnt ------------------
// A [M][K] rm bf16, B [N][K] rm bf16, D = A @ B^T.
// SWZ 1: 1D grid, y-tiles pinned per-XCD (gy==256). SWZ 2: 768-block EPI2
//        mapping co-locating the 3 by-blocks of one bx on one XCD.
// EPI 1: gelu(D+bias) -> bf16 rm [M][N] via LDS-bounce epilogue
// EPI 2: rows=channels, cols=tokens; out[b,c,p]=res[b,c,p]+gamma[c]*(D+bias)
// EPI 4: QKV: cols<768 (q,k) -> plain rm [tok][1152]; v -> Vt [bh][96][n]
//        (Vt pointer passed via gamma)
template <int EPI, int SWZ>
__global__ __launch_bounds__(256) void gemm_k(const u16* __restrict__ A,
                                              const u16* __restrict__ B, int M,
                                              int N, int K,
                                              const float* __restrict__ bias,
                                              const float* gamma,
                                              const float* res, void* outp,
                                              int nbx) {
  __shared__ u16 SM[16384];      // 32KB: At0|At1|Bt0|Bt1 (8KB each); Ct after
  const int t = threadIdx.x;
  const int w = t >> 6, l = t & 63;
  const int l15 = l & 15, kg = l >> 4;
  int bx, by;
  if (SWZ == 1) {
    int id = blockIdx.x;
    int xcd = id & 7, jj = id >> 3;
    int q = jj / nbx;
    bx = jj - q * nbx;
    by = xcd * 32 + q;
  } else if (SWZ == 2) {
    int id = blockIdx.x;           // 768 blocks
    int xcd = id & 7, jj = id >> 3;
    by = jj % 3;
    bx = (jj / 3) * 8 + xcd;
  } else {
    bx = blockIdx.x; by = blockIdx.y;
  }
  const int m0 = by * 128, n0 = bx * 128;
  const int wr = w >> 1, wc = w & 1;

  const int off1 = w * 1024 + l * 16;
  const int off2 = 4096 + w * 1024 + l * 16;
  const int r1 = off1 >> 6, c1 = off1 & 63;
  const int r2 = off2 >> 6, c2 = off2 & 63;
  const size_t ldab = (size_t)K * 2;
  const char* pa1 = (const char*)A + (size_t)(m0 + r1) * ldab + c1;
  const char* pa2 = (const char*)A + (size_t)(m0 + r2) * ldab + c2;
  const char* pb1 = (const char*)B + (size_t)(n0 + r1) * ldab + c1;
  const char* pb2 = (const char*)B + (size_t)(n0 + r2) * ldab + c2;
  char* SMc = (char*)SM;

  f32x4 acc[4][4];
#pragma unroll
  for (int m = 0; m < 4; ++m)
#pragma unroll
    for (int n = 0; n < 4; ++n) acc[m][n] = {0.f, 0.f, 0.f, 0.f};

  const int nkt = K >> 5;
  {
    char* ad = SMc + w * 1024;
    char* bd = SMc + 16384 + w * 1024;
    g2l16(ad, pa1); g2l16(ad + 4096, pa2);
    g2l16(bd, pb1); g2l16(bd + 4096, pb2);
  }
  for (int kt = 0; kt < nkt; ++kt) {
    const int buf = kt & 1;
    if (kt + 1 < nkt) {            // stage NEXT tile into other buffer
      const size_t o = (size_t)(kt + 1) * 64;
      char* ad = SMc + (buf ^ 1) * 8192 + w * 1024;
      char* bd = SMc + 16384 + (buf ^ 1) * 8192 + w * 1024;
      g2l16(ad, pa1 + o); g2l16(ad + 4096, pa2 + o);
      g2l16(bd, pb1 + o); g2l16(bd + 4096, pb2 + o);
      asm volatile("s_waitcnt vmcnt(4)" ::: "memory");   // cur tile landed
    } else {
      asm volatile("s_waitcnt vmcnt(0)" ::: "memory");
    }
    __builtin_amdgcn_s_barrier();
    __builtin_amdgcn_sched_barrier(0);
    const u16* Ab = SM + buf * 4096;
    const u16* Bb = SM + 8192 + buf * 4096;
    bf16x8 af[4], bfr[4];
#pragma unroll
    for (int m = 0; m < 4; ++m)
      af[m] = *(const bf16x8*)(Ab + (wr * 64 + m * 16 + l15) * 32 + kg * 8);
#pragma unroll
    for (int n = 0; n < 4; ++n)
      bfr[n] = *(const bf16x8*)(Bb + (wc * 64 + n * 16 + l15) * 32 + kg * 8);
#pragma unroll
    for (int m = 0; m < 4; ++m)
#pragma unroll
      for (int n = 0; n < 4; ++n)
        acc[m][n] = __builtin_amdgcn_mfma_f32_16x16x32_bf16(af[m], bfr[n], acc[m][n], 0, 0, 0);
    __builtin_amdgcn_sched_barrier(0);
    __builtin_amdgcn_s_barrier();  // all waves done reading buf
  }

  if (EPI == 2) {
    float* out = (float*)outp;
#pragma unroll
    for (int m = 0; m < 4; ++m) {
#pragma unroll
      for (int n = 0; n < 4; ++n) {
        int tok = n0 + wc * 64 + n * 16 + l15;
        int bb = tok >> 10, p = tok & 1023;
#pragma unroll
        for (int j = 0; j < 4; ++j) {
          int c = m0 + wr * 64 + m * 16 + kg * 4 + j;
          size_t addr = (((size_t)(bb * 384 + c)) << 10) + p;
          out[addr] = res[addr] + gamma[c] * (acc[m][n][j] + bias[c]);
        }
      }
    }
    return;
  }

  const int sec = (EPI == 4) ? (n0 / 384) : 0;
  if (EPI == 4 && sec == 2) {      // V: transposed into Vt (via gamma ptr)
    u16* Vp = (u16*)(uintptr_t)gamma;
#pragma unroll
    for (int m = 0; m < 4; ++m) {
      const int tokbase = m0 + wr * 64 + m * 16 + kg * 4;
      const int bb = tokbase >> 10, nb = tokbase & 1023;
#pragma unroll
      for (int n = 0; n < 4; ++n) {
        int within = n0 - 768 + wc * 64 + n * 16 + l15;
        int hh = within / 96;
        int dd = within - hh * 96;
        float bs = bias[768 + within];
        int bh = bb * 4 + hh;
        u64 pk = 0;
#pragma unroll
        for (int j = 0; j < 4; ++j)
          pk |= (u64)cvt16(acc[m][n][j] + bs) << (16 * j);
        *(u64*)(Vp + ((size_t)bh * 96 + dd) * 1024 + nb) = pk;
      }
    }
    return;
  }

  // ---- LDS-bounce epilogue (EPI 1, and EPI 4 q/k sections) ----
  {
    u16* Ct = SM;                  // 128x128 u16, overlays tiles (post-barrier)
    float bs[4];
#pragma unroll
    for (int n = 0; n < 4; ++n) bs[n] = bias[n0 + wc * 64 + n * 16 + l15];
    u16* cw_ = Ct + (wr * 64 + kg * 4) * 128 + wc * 64 + l15;
#pragma unroll
    for (int m = 0; m < 4; ++m)
#pragma unroll
      for (int n = 0; n < 4; ++n)
#pragma unroll
        for (int j = 0; j < 4; ++j) {
          float v = acc[m][n][j] + bs[n];
          if (EPI == 1) v = gelu_tanh(v);
          cw_[(m * 16 + j) * 128 + n * 16] = cvt16(v);
        }
    __syncthreads();
    const int row_l = w * 4 + (l >> 4);       // 0..15
    const int colc = (l & 15) * 8;            // 0..120
    const u16* src = Ct + row_l * 128 + colc;
    if (EPI == 1) {
      u16* dst = (u16*)outp + (size_t)(m0 + row_l) * N + n0 + colc;
#pragma unroll
      for (int rr = 0; rr < 8; ++rr)
        *(u16x8*)(dst + (size_t)rr * 16 * N) =
            *(const u16x8*)(src + rr * 16 * 128);
    } else {                                   // EPI4 q/k: plain [tok][1152]
      u16* dst = (u16*)outp + (size_t)(m0 + row_l) * 1152 + n0 + colc;
#pragma unroll
      for (int rr = 0; rr < 8; ++rr)
        *(u16x8*)(dst + (size_t)rr * 16 * 1152) =
            *(const u16x8*)(src + rr * 16 * 128);
    }
  }
}

// ---------------------------------------------------------------------------
extern "C" void kernel_launch(void* const* d_in, const int* in_sizes, int n_in,
                              void* d_out, int out_size, void* d_ws,
                              size_t ws_size, hipStream_t stream) {
  const float* x      = (const float*)d_in[0];
  const float* conv_w = (const float*)d_in[1];
  const float* conv_b = (const float*)d_in[2];
  const float* nxca_w = (const float*)d_in[3];
  const float* nxca_b = (const float*)d_in[4];
  const float* temp   = (const float*)d_in[5];
  const float* qkv_w  = (const float*)d_in[6];
  const float* qkv_b  = (const float*)d_in[7];
  const float* proj_w = (const float*)d_in[8];
  const float* proj_b = (const float*)d_in[9];
  const float* norm_w = (const float*)d_in[10];
  const float* norm_b = (const float*)d_in[11];
  const float* fc1_w  = (const float*)d_in[12];
  const float* fc1_b  = (const float*)d_in[13];
  const float* fc2_w  = (const float*)d_in[14];
  const float* fc2_b  = (const float*)d_in[15];
  const float* g_xca  = (const float*)d_in[16];
  const float* g_mlp  = (const float*)d_in[17];
  (void)in_sizes; (void)n_in; (void)out_size; (void)ws_size;

  char* ws = (char*)d_ws;
  float* xc  = (float*)(ws);                    // 50,331,648 B (f32 NCHW, shortcut)
  u16* Y     = (u16*)(ws + 50331648);           // 25,165,824 B (also Obuf)
  u16* QKVr  = (u16*)(ws + 75497472);           // 75,497,472 B  [32768][1152]
  u16* Vt    = (u16*)(ws + 150994944);          // 25,165,824 B  [bh][96][1024]
  u16* Obuf  = Y;                               // attn O overlays Y (dead then)
  u16* H1    = QKVr;                            // fc1 out overlays QKVr+Vt
  u16* wq    = (u16*)(ws + 176160768);
  u16* wp    = (u16*)(ws + 177045504);
  u16* w1    = (u16*)(ws + 177340416);
  u16* w2    = (u16*)(ws + 178520064);          // end: 179,699,712 B

  cvt4_k<<<6912, 256, 0, stream>>>(qkv_w, proj_w, fc1_w, fc2_w, wq, wp, w1, w2);

  conv_k<<<12288, 256, 0, stream>>>(x, conv_w, conv_b, xc);
  ln_t_k<<<dim3(32, 32), 256, 0, stream>>>(xc, nxca_w, nxca_b, Y);
  gemm_k<4, 1><<<2304, 256, 0, stream>>>(Y, wq, 32768, 1152, 384, qkv_b,
                                         (const float*)Vt, nullptr, QKVr, 9);
  normqk_k<<<2048, 256, 0, stream>>>(QKVr, temp);
  attn_k<<<1024, 256, 0, stream>>>(QKVr, Vt, Obuf, temp);
  gemm_k<2, 2><<<768, 256, 0, stream>>>(wp, Obuf, 384, 32768, 384,
                                        proj_b, g_xca, xc, xc, 0);
  ln_t_k<<<dim3(32, 32), 256, 0, stream>>>(xc, norm_w, norm_b, Y);
  gemm_k<1, 1><<<3072, 256, 0, stream>>>(Y, w1, 32768, 1536, 384, fc1_b,
                                         nullptr, nullptr, H1, 12);
  gemm_k<2, 2><<<768, 256, 0, stream>>>(w2, H1, 384, 32768, 1536,
                                        fc2_b, g_mlp, xc, (float*)d_out, 0);
}

// Round 8
// 411.575 us; speedup vs baseline: 1.6403x; 1.0039x over previous
//
#include <hip/hip_runtime.h>
#include <cstdint>

typedef unsigned short u16;
typedef unsigned int u32;
typedef unsigned long long u64;
typedef __attribute__((ext_vector_type(4))) float f32x4;
typedef __attribute__((ext_vector_type(8))) __bf16 bf16x8;
typedef __attribute__((ext_vector_type(8))) u16 u16x8;

#define DEV __device__ __forceinline__

DEV u16 cvt16(float f) {
  __bf16 h = (__bf16)f;
  return __builtin_bit_cast(u16, h);
}
DEV u16 f2bf(float f) {  // round-to-nearest-even (for host-data convert)
  u32 u = __builtin_bit_cast(u32, f);
  u += 0x7fffu + ((u >> 16) & 1u);
  return (u16)(u >> 16);
}
DEV float bflo2f(u32 packed) { return __builtin_bit_cast(float, packed << 16); }
DEV float bfhi2f(u32 packed) { return __builtin_bit_cast(float, packed & 0xffff0000u); }

// async global->LDS, 16B per lane. lds pointer must be the WAVE-UNIFORM base;
// HW adds lane*16. Global pointer is per-lane.
DEV void g2l16(void* lds_wave_base, const void* gsrc) {
  __builtin_amdgcn_global_load_lds(
      (const __attribute__((address_space(1))) u32*)gsrc,
      (__attribute__((address_space(3))) u32*)lds_wave_base, 16, 0, 0);
}

DEV float gelu_tanh(float v) {
  float z = v * (0.7978845608f + 0.0356774081f * v * v);
  float e = __expf(2.0f * z);
  float th = 1.0f - 2.0f / (e + 1.0f);
  return 0.5f * v * (1.0f + th);
}

// ---------------- depthwise conv 3x3 (first 192 ch) + passthrough ----------
__global__ __launch_bounds__(256) void conv_k(const float* __restrict__ x,
                                              const float* __restrict__ cw,
                                              const float* __restrict__ cb,
                                              float* __restrict__ xc) {
  const int bc = blockIdx.x;             // b*384 + c
  const int c = bc % 384;
  const int p4 = threadIdx.x * 4;
  const float* xp = x + ((size_t)bc << 10);
  float* op = xc + ((size_t)bc << 10) + p4;
  if (c >= 192) {
    *(f32x4*)op = *(const f32x4*)(xp + p4);
    return;
  }
  const int hh = p4 >> 5, ww0 = p4 & 31;
  const float* wb = cw + c * 9;
  float b0 = cb[c];
  float a0 = b0, a1 = b0, a2 = b0, a3 = b0;
#pragma unroll
  for (int dy = 0; dy < 3; ++dy) {
    int y = hh + dy - 1;
    if ((unsigned)y < 32u) {
      const float* rp = xp + y * 32 + ww0;
      f32x4 m = *(const f32x4*)rp;
      float lft = (ww0 > 0) ? rp[-1] : 0.f;
      float rgt = (ww0 < 28) ? rp[4] : 0.f;
      float w0 = wb[dy * 3], w1 = wb[dy * 3 + 1], w2 = wb[dy * 3 + 2];
      a0 += lft * w0 + m[0] * w1 + m[1] * w2;
      a1 += m[0] * w0 + m[1] * w1 + m[2] * w2;
      a2 += m[1] * w0 + m[2] * w1 + m[3] * w2;
      a3 += m[2] * w0 + m[3] * w1 + rgt * w2;
    }
  }
  f32x4 r = {a0, a1, a2, a3};
  *(f32x4*)op = r;
}

// ---------------- fused f32 -> bf16 convert of the 4 weight mats -----------
__global__ __launch_bounds__(256) void cvt4_k(const float* __restrict__ s0,
                                              const float* __restrict__ s1,
                                              const float* __restrict__ s2,
                                              const float* __restrict__ s3,
                                              u16* __restrict__ d0,
                                              u16* __restrict__ d1,
                                              u16* __restrict__ d2,
                                              u16* __restrict__ d3) {
  int id = blockIdx.x * 256 + threadIdx.x;
  if (id < 442368) d0[id] = f2bf(s0[id]);
  else if (id < 589824) d1[id - 442368] = f2bf(s1[id - 442368]);
  else if (id < 1179648) d2[id - 589824] = f2bf(s2[id - 589824]);
  else if (id < 1769472) d3[id - 1179648] = f2bf(s3[id - 1179648]);
}

// ---------------- channel-LN (NCHW) + transpose to [token][C] bf16 ---------
__global__ __launch_bounds__(256) void ln_t_k(const float* __restrict__ X,
                                              const float* __restrict__ w,
                                              const float* __restrict__ bsh,
                                              u16* __restrict__ Y) {
  __shared__ float tile[384][33];
  __shared__ float ps[8][32], ps2[8][32];
  __shared__ float mean_s[32], rstd_s[32];
  const int b = blockIdx.y;
  const int p0 = blockIdx.x * 32;
  const int t = threadIdx.x;
  const int pl = t & 31, cg = t >> 5;
  const float* xb = X + (((size_t)b * 384) << 10) + p0 + pl;
  float s = 0.f, s2 = 0.f;
  for (int c = cg; c < 384; c += 8) {
    float v = xb[(size_t)c << 10];
    tile[c][pl] = v;
    s += v;
    s2 += v * v;
  }
  ps[cg][pl] = s;
  ps2[cg][pl] = s2;
  __syncthreads();
  if (t < 32) {
    float a = 0.f, a2 = 0.f;
#pragma unroll
    for (int g = 0; g < 8; ++g) { a += ps[g][t]; a2 += ps2[g][t]; }
    float mu = a * (1.f / 384.f);
    float var = a2 * (1.f / 384.f) - mu * mu;
    mean_s[t] = mu;
    rstd_s[t] = rsqrtf(var + 1e-6f);
  }
  __syncthreads();
  const int cl = t & 63, pg = t >> 6;
  for (int p = pg; p < 32; p += 4) {
    float mu = mean_s[p], rs = rstd_s[p];
    size_t orow = (((size_t)b << 10) + p0 + p) * 384;
#pragma unroll
    for (int cc = 0; cc < 6; ++cc) {
      int c = cc * 64 + cl;
      float v = (tile[c][p] - mu) * rs * w[c] + bsh[c];
      Y[orow + c] = f2bf(v);
    }
  }
}

// ---------------- L2-normalize k heads in QKV rows (q folded into attn) ----
__global__ __launch_bounds__(256) void normk_k(u16* __restrict__ QKV) {
  const int t = threadIdx.x;
  const int w = t >> 6, l = t & 63;
  const int rg = l >> 4, li = l & 15;
  const int tok = blockIdx.x * 16 + w * 4 + rg;
  u16* rowp = QKV + (size_t)tok * 1152 + 384;
#pragma unroll
  for (int h = 0; h < 4; ++h) {
    u16* p = rowp + h * 96 + li * 6;
    u32 a = *(const u32*)p;
    u32 b2 = *(const u32*)(p + 2);
    u32 c = *(const u32*)(p + 4);
    float v[6] = {bflo2f(a), bfhi2f(a), bflo2f(b2), bfhi2f(b2), bflo2f(c), bfhi2f(c)};
    float ss = 0.f;
#pragma unroll
    for (int i = 0; i < 6; ++i) ss += v[i] * v[i];
#pragma unroll
    for (int mk = 1; mk < 16; mk <<= 1) ss += __shfl_xor(ss, mk, 64);
    float sc = 1.0f / fmaxf(sqrtf(ss), 1e-12f);
    u32 o0 = (u32)f2bf(v[0] * sc) | ((u32)f2bf(v[1] * sc) << 16);
    u32 o1 = (u32)f2bf(v[2] * sc) | ((u32)f2bf(v[3] * sc) << 16);
    u32 o2 = (u32)f2bf(v[4] * sc) | ((u32)f2bf(v[5] * sc) << 16);
    *(u32*)p = o0;
    *(u32*)(p + 2) = o1;
    *(u32*)(p + 4) = o2;
  }
}

// ---------------- flash attention v7: q-norm folded, exp2, setprio ---------
// 1024 blocks (XCD-pinned), 4 waves × 32 q-rows, KVBLK=64. K from QKV rows
// (gathered, swizzled); V from pre-transposed Vt (swizzled). Q loaded RAW;
// alpha = t*log2e/|q| folded into the exp2 fma. vmcnt(7), 2 barriers/tile.
__global__ __launch_bounds__(256) void attn_k(const u16* __restrict__ QKV,
                                              const u16* __restrict__ Vg,
                                              u16* __restrict__ O,
                                              const float* __restrict__ temp) {
  __shared__ u16 Kt[2][8192];    // [64 rows][128 u16] swizzled, 16KB each
  __shared__ u16 Vt[2][6144];    // [96 rows][64 u16] swizzled, 12KB each
  __shared__ u16 Pt[4][2304];    // per-wave P [32][72]
  const int t = threadIdx.x;
  const int w = t >> 6, l = t & 63;
  const int l15 = l & 15, kg = l >> 4;
  const int id = blockIdx.x;
  const int xcd = id & 7, jj = id >> 3;          // jj in [0,128)
  const int bh = xcd * 16 + (jj >> 3);
  const int qb = jj & 7;
  const int b = bh >> 2, h = bh & 3;
  const int q0 = qb * 128 + w * 32;
  const u16* Qb = QKV + (size_t)b * 1024 * 1152;
  const char* Kbg = (const char*)QKV + (size_t)b * 1024 * 2304 + 768 + 192 * h;
  const u16* Vbg = Vg + (size_t)bh * 98304;      // [96][1024]
  const float tl2e = temp[h] * 1.44269504f;
  const float mT2 = -fabsf(temp[h]) * 1.44269504f;

  u32 sK[4], sV[3];
#pragma unroll
  for (int j = 0; j < 4; ++j) {
    u32 s = w * 4096 + j * 1024 + l * 16;
    u32 row = s >> 8, rem = s & 255;
    u32 X = rem ^ ((row & 7) << 4);
    sK[j] = (X < 192) ? (row * 2304 + X) : 0u;
  }
#pragma unroll
  for (int j = 0; j < 3; ++j) {
    u32 s = w * 3072 + j * 1024 + l * 16;
    u32 u = s ^ (((s >> 7) & 7) << 4);
    sV[j] = (u >> 7) * 2048 + (u & 127);
  }
  u32 cs[3];
#pragma unroll
  for (int kk = 0; kk < 3; ++kk)
    cs[kk] = (u32)((kk * 64 + kg * 16) ^ ((l15 & 7) << 4));

  bf16x8 qf[2][3];
#pragma unroll
  for (int f = 0; f < 2; ++f) {
    const u16* qp = Qb + (size_t)(q0 + f * 16 + l15) * 1152 + h * 96 + kg * 8;
#pragma unroll
    for (int kk = 0; kk < 3; ++kk) qf[f][kk] = *(const bf16x8*)(qp + kk * 32);
  }
  // alpha = t*log2e / max(|q|,1e-12); row f*16+l15's sumsq via kg-group shfl
  float a0[4], a1[4];
  {
    float alpha[2];
#pragma unroll
    for (int f = 0; f < 2; ++f) {
      float ss = 0.f;
#pragma unroll
      for (int kk = 0; kk < 3; ++kk)
#pragma unroll
        for (int e = 0; e < 8; ++e) {
          float v = (float)qf[f][kk][e];
          ss += v * v;
        }
      ss += __shfl_xor(ss, 16, 64);
      ss += __shfl_xor(ss, 32, 64);
      alpha[f] = tl2e * rsqrtf(fmaxf(ss, 1e-24f));
    }
#pragma unroll
    for (int j = 0; j < 4; ++j) {
      a0[j] = __shfl(alpha[0], kg * 4 + j, 64);
      a1[j] = __shfl(alpha[1], kg * 4 + j, 64);
    }
  }
  f32x4 oa[2][6];
#pragma unroll
  for (int f = 0; f < 2; ++f)
#pragma unroll
    for (int d = 0; d < 6; ++d) oa[f][d] = {0.f, 0.f, 0.f, 0.f};
  float l_r[2][4] = {{0.f, 0.f, 0.f, 0.f}, {0.f, 0.f, 0.f, 0.f}};
  __bf16* Pw = (__bf16*)&Pt[w][0];

#define STAGE(buf, kv0)                                                        \
  {                                                                            \
    const char* kb = Kbg + (size_t)(kv0) * 2304;                               \
    const char* vb = (const char*)Vbg + (size_t)(kv0) * 2;                     \
    char* kd = (char*)&Kt[buf][0] + w * 4096;                                  \
    char* vd = (char*)&Vt[buf][0] + w * 3072;                                  \
    g2l16(kd, kb + sK[0]);                                                     \
    g2l16(kd + 1024, kb + sK[1]);                                              \
    g2l16(kd + 2048, kb + sK[2]);                                              \
    g2l16(kd + 3072, kb + sK[3]);                                              \
    g2l16(vd, vb + sV[0]);                                                     \
    g2l16(vd + 1024, vb + sV[1]);                                              \
    g2l16(vd + 2048, vb + sV[2]);                                              \
  }

  STAGE(0, 0);
  for (int tt = 0; tt < 16; ++tt) {
    const int cur = tt & 1;
    if (tt < 15) {
      STAGE(cur ^ 1, (tt + 1) * 64);
      asm volatile("s_waitcnt vmcnt(7)" ::: "memory");
    } else {
      asm volatile("s_waitcnt vmcnt(0)" ::: "memory");
    }
    __builtin_amdgcn_s_barrier();
    const char* Kc = (const char*)&Kt[cur][0];
    const char* Vc = (const char*)&Vt[cur][0];
    f32x4 s0[4], s1[4];
#pragma unroll
    for (int n = 0; n < 4; ++n) { s0[n] = {0.f, 0.f, 0.f, 0.f}; s1[n] = {0.f, 0.f, 0.f, 0.f}; }
    __builtin_amdgcn_s_setprio(1);
#pragma unroll
    for (int n = 0; n < 4; ++n) {
      const char* krow = Kc + ((n * 16 + l15) << 8);
#pragma unroll
      for (int kk = 0; kk < 3; ++kk) {
        bf16x8 kf = *(const bf16x8*)(krow + cs[kk]);
        s0[n] = __builtin_amdgcn_mfma_f32_16x16x32_bf16(qf[0][kk], kf, s0[n], 0, 0, 0);
        s1[n] = __builtin_amdgcn_mfma_f32_16x16x32_bf16(qf[1][kk], kf, s1[n], 0, 0, 0);
      }
    }
    __builtin_amdgcn_s_setprio(0);
#pragma unroll
    for (int n = 0; n < 4; ++n) {
#pragma unroll
      for (int j = 0; j < 4; ++j) {
        float p0 = exp2f(fmaf(s0[n][j], a0[j], mT2));
        float p1 = exp2f(fmaf(s1[n][j], a1[j], mT2));
        l_r[0][j] += p0;
        l_r[1][j] += p1;
        Pw[(kg * 4 + j) * 72 + n * 16 + l15] = (__bf16)p0;
        Pw[(16 + kg * 4 + j) * 72 + n * 16 + l15] = (__bf16)p1;
      }
    }
    __builtin_amdgcn_s_setprio(1);
#pragma unroll
    for (int kk = 0; kk < 2; ++kk) {
      bf16x8 pf0 = *(const bf16x8*)(Pw + (size_t)l15 * 72 + kk * 32 + kg * 8);
      bf16x8 pf1 = *(const bf16x8*)(Pw + (size_t)(16 + l15) * 72 + kk * 32 + kg * 8);
#pragma unroll
      for (int d = 0; d < 6; ++d) {
        bf16x8 vf = *(const bf16x8*)(Vc + ((d * 16 + l15) << 7) + cs[kk]);
        oa[0][d] = __builtin_amdgcn_mfma_f32_16x16x32_bf16(pf0, vf, oa[0][d], 0, 0, 0);
        oa[1][d] = __builtin_amdgcn_mfma_f32_16x16x32_bf16(pf1, vf, oa[1][d], 0, 0, 0);
      }
    }
    __builtin_amdgcn_s_setprio(0);
    __builtin_amdgcn_s_barrier();
  }
#undef STAGE
  float inv[2][4];
#pragma unroll
  for (int f = 0; f < 2; ++f)
#pragma unroll
    for (int j = 0; j < 4; ++j) {
      float sum = l_r[f][j];
#pragma unroll
      for (int mk = 1; mk < 16; mk <<= 1) sum += __shfl_xor(sum, mk, 64);
      inv[f][j] = 1.0f / sum;
    }
#pragma unroll
  for (int f = 0; f < 2; ++f)
#pragma unroll
    for (int d = 0; d < 6; ++d)
#pragma unroll
      for (int j = 0; j < 4; ++j) {
        int tok = q0 + f * 16 + kg * 4 + j;
        O[((size_t)b * 1024 + tok) * 384 + h * 96 + d * 16 + l15] =
            f2bf(oa[f][d][j] * inv[f][j]);
      }
}

// ---------------- 256x128 bf16 GEMM, 512 thr, dbuf + counted vmcnt ---------
// A [M][K] rm bf16 (M=32768), B [N][K] rm bf16, D = A @ B^T.
// 1D grid XCD-pinned: by = xcd*16 + jj/nbx, bx = jj%nbx (M-tiles = 128).
// EPI 1: gelu(D+bias) -> bf16 rm [M][N] (LDS-bounce, 2 passes)
// EPI 4: QKV: cols<768 -> rm [tok][1152]; cols>=768 -> Vt [bh][96][n] (vtp)
template <int EPI>
__global__ __launch_bounds__(512) void gemm256_k(const u16* __restrict__ A,
                                                 const u16* __restrict__ B,
                                                 int N, int K,
                                                 const float* __restrict__ bias,
                                                 u16* __restrict__ vtp,
                                                 u16* __restrict__ outp,
                                                 int nbx) {
  __shared__ u16 SM[24576];      // 48KB: At[2]16KB | Bt[2]8KB ; Ct 32KB after
  const int t = threadIdx.x;
  const int w = t >> 6, l = t & 63;
  const int l15 = l & 15, kg = l >> 4;
  const int id = blockIdx.x;
  const int xcd = id & 7, jj = id >> 3;
  const int qq = jj / nbx;
  const int bx = jj - qq * nbx;
  const int by = xcd * 16 + qq;
  const int m0 = by * 256, n0 = bx * 128;
  const int wr = w >> 1, wc = w & 1;
  const size_t ldab = (size_t)K * 2;
  const char* pa1 = (const char*)A + (size_t)(m0 + (t >> 2)) * ldab + (t & 3) * 16;
  const char* pa2 = pa1 + (size_t)128 * ldab;
  const char* pb1 = (const char*)B + (size_t)(n0 + (t >> 2)) * ldab + (t & 3) * 16;
  char* SMc = (char*)SM;

  f32x4 acc[4][4];
#pragma unroll
  for (int m = 0; m < 4; ++m)
#pragma unroll
    for (int n = 0; n < 4; ++n) acc[m][n] = {0.f, 0.f, 0.f, 0.f};

  const int nkt = K >> 5;
  g2l16(SMc + w * 1024, pa1);
  g2l16(SMc + 8192 + w * 1024, pa2);
  g2l16(SMc + 32768 + w * 1024, pb1);
  for (int kt = 0; kt < nkt; ++kt) {
    const int buf = kt & 1;
    if (kt + 1 < nkt) {
      const size_t o = (size_t)(kt + 1) * 64;
      g2l16(SMc + (buf ^ 1) * 16384 + w * 1024, pa1 + o);
      g2l16(SMc + (buf ^ 1) * 16384 + 8192 + w * 1024, pa2 + o);
      g2l16(SMc + 32768 + (buf ^ 1) * 8192 + w * 1024, pb1 + o);
      asm volatile("s_waitcnt vmcnt(3)" ::: "memory");
    } else {
      asm volatile("s_waitcnt vmcnt(0)" ::: "memory");
    }
    __builtin_amdgcn_s_barrier();
    __builtin_amdgcn_sched_barrier(0);
    const u16* Ab = SM + buf * 8192;
    const u16* Bb = SM + 16384 + buf * 4096;
    bf16x8 af[4], bfr[4];
#pragma unroll
    for (int m = 0; m < 4; ++m)
      af[m] = *(const bf16x8*)(Ab + (wr * 64 + m * 16 + l15) * 32 + kg * 8);
#pragma unroll
    for (int n = 0; n < 4; ++n)
      bfr[n] = *(const bf16x8*)(Bb + (wc * 64 + n * 16 + l15) * 32 + kg * 8);
    __builtin_amdgcn_s_setprio(1);
#pragma unroll
    for (int m = 0; m < 4; ++m)
#pragma unroll
      for (int n = 0; n < 4; ++n)
        acc[m][n] = __builtin_amdgcn_mfma_f32_16x16x32_bf16(af[m], bfr[n], acc[m][n], 0, 0, 0);
    __builtin_amdgcn_s_setprio(0);
    __builtin_amdgcn_sched_barrier(0);
    __builtin_amdgcn_s_barrier();
  }

  if (EPI == 4 && n0 >= 768) {   // V section: transposed u64 into vtp
#pragma unroll
    for (int m = 0; m < 4; ++m) {
      const int tokbase = m0 + wr * 64 + m * 16 + kg * 4;
      const int bb = tokbase >> 10, nb = tokbase & 1023;
#pragma unroll
      for (int n = 0; n < 4; ++n) {
        int within = n0 - 768 + wc * 64 + n * 16 + l15;
        int hh = within / 96;
        int dd = within - hh * 96;
        float bs = bias[768 + within];
        int bh = bb * 4 + hh;
        u64 pk = 0;
#pragma unroll
        for (int j = 0; j < 4; ++j)
          pk |= (u64)cvt16(acc[m][n][j] + bs) << (16 * j);
        *(u64*)(vtp + ((size_t)bh * 96 + dd) * 1024 + nb) = pk;
      }
    }
    return;
  }

  // ---- LDS-bounce epilogue, two 128-row passes ----
  u16* Ct = SM;                  // 128x128 u16 (32KB), overlays staged tiles
  float bs[4];
#pragma unroll
  for (int n = 0; n < 4; ++n) bs[n] = bias[n0 + wc * 64 + n * 16 + l15];
  const size_t ostride = (EPI == 4) ? 1152 : (size_t)N;
#pragma unroll
  for (int p = 0; p < 2; ++p) {
    if ((wr >> 1) == p) {
      u16* cw_ = Ct + ((wr & 1) * 64 + kg * 4) * 128 + wc * 64 + l15;
#pragma unroll
      for (int m = 0; m < 4; ++m)
#pragma unroll
        for (int n = 0; n < 4; ++n)
#pragma unroll
          for (int j = 0; j < 4; ++j) {
            float v = acc[m][n][j] + bs[n];
            if (EPI == 1) v = gelu_tanh(v);
            cw_[(m * 16 + j) * 128 + n * 16] = cvt16(v);
          }
    }
    __syncthreads();
    const int row_l = t >> 2;
    const int colc = (t & 3) * 32;
    const u16* src = Ct + row_l * 128 + colc;
    u16* dst = outp + (size_t)(m0 + p * 128 + row_l) * ostride + n0 + colc;
#pragma unroll
    for (int c4 = 0; c4 < 4; ++c4)
      *(u16x8*)(dst + c4 * 8) = *(const u16x8*)(src + c4 * 8);
    __syncthreads();
  }
}

// ---------------- 128x128 bf16 GEMM (EPI2: M=384 fused-residual) -----------
// SWZ 2: 768 blocks; 3 by-blocks of one bx co-located per XCD.
__global__ __launch_bounds__(256) void gemm_k(const u16* __restrict__ A,
                                              const u16* __restrict__ B,
                                              int K,
                                              const float* __restrict__ bias,
                                              const float* __restrict__ gamma,
                                              const float* __restrict__ res,
                                              float* __restrict__ outp) {
  __shared__ u16 SM[16384];
  const int t = threadIdx.x;
  const int w = t >> 6, l = t & 63;
  const int l15 = l & 15, kg = l >> 4;
  int id = blockIdx.x;
  int xcd = id & 7, jj = id >> 3;
  int by = jj % 3;
  int bx = (jj / 3) * 8 + xcd;
  const int m0 = by * 128, n0 = bx * 128;
  const int wr = w >> 1, wc = w & 1;

  const size_t ldab = (size_t)K * 2;
  const char* pa1 = (const char*)A + (size_t)(m0 + (t >> 2)) * ldab + (t & 3) * 16;
  const char* pa2 = pa1 + (size_t)64 * ldab;
  const char* pb1 = (const char*)B + (size_t)(n0 + (t >> 2)) * ldab + (t & 3) * 16;
  const char* pb2 = pb1 + (size_t)64 * ldab;
  char* SMc = (char*)SM;

  f32x4 acc[4][4];
#pragma unroll
  for (int m = 0; m < 4; ++m)
#pragma unroll
    for (int n = 0; n < 4; ++n) acc[m][n] = {0.f, 0.f, 0.f, 0.f};

  const int nkt = K >> 5;
  {
    char* ad = SMc + w * 1024;
    char* bd = SMc + 16384 + w * 1024;
    g2l16(ad, pa1); g2l16(ad + 4096, pa2);
    g2l16(bd, pb1); g2l16(bd + 4096, pb2);
  }
  for (int kt = 0; kt < nkt; ++kt) {
    const int buf = kt & 1;
    if (kt + 1 < nkt) {
      const size_t o = (size_t)(kt + 1) * 64;
      char* ad = SMc + (buf ^ 1) * 8192 + w * 1024;
      char* bd = SMc + 16384 + (buf ^ 1) * 8192 + w * 1024;
      g2l16(ad, pa1 + o); g2l16(ad + 4096, pa2 + o);
      g2l16(bd, pb1 + o); g2l16(bd + 4096, pb2 + o);
      asm volatile("s_waitcnt vmcnt(4)" ::: "memory");
    } else {
      asm volatile("s_waitcnt vmcnt(0)" ::: "memory");
    }
    __builtin_amdgcn_s_barrier();
    __builtin_amdgcn_sched_barrier(0);
    const u16* Ab = SM + buf * 4096;
    const u16* Bb = SM + 8192 + buf * 4096;
    bf16x8 af[4], bfr[4];
#pragma unroll
    for (int m = 0; m < 4; ++m)
      af[m] = *(const bf16x8*)(Ab + (wr * 64 + m * 16 + l15) * 32 + kg * 8);
#pragma unroll
    for (int n = 0; n < 4; ++n)
      bfr[n] = *(const bf16x8*)(Bb + (wc * 64 + n * 16 + l15) * 32 + kg * 8);
    __builtin_amdgcn_s_setprio(1);
#pragma unroll
    for (int m = 0; m < 4; ++m)
#pragma unroll
      for (int n = 0; n < 4; ++n)
        acc[m][n] = __builtin_amdgcn_mfma_f32_16x16x32_bf16(af[m], bfr[n], acc[m][n], 0, 0, 0);
    __builtin_amdgcn_s_setprio(0);
    __builtin_amdgcn_sched_barrier(0);
    __builtin_amdgcn_s_barrier();
  }

  // EPI2: rows=channels, cols=tokens; out[b,c,p] = res + gamma[c]*(D+bias[c])
#pragma unroll
  for (int m = 0; m < 4; ++m) {
#pragma unroll
    for (int n = 0; n < 4; ++n) {
      int tok = n0 + wc * 64 + n * 16 + l15;
      int bb = tok >> 10, p = tok & 1023;
#pragma unroll
      for (int j = 0; j < 4; ++j) {
        int c = m0 + wr * 64 + m * 16 + kg * 4 + j;
        size_t addr = (((size_t)(bb * 384 + c)) << 10) + p;
        outp[addr] = res[addr] + gamma[c] * (acc[m][n][j] + bias[c]);
      }
    }
  }
}

// ---------------------------------------------------------------------------
extern "C" void kernel_launch(void* const* d_in, const int* in_sizes, int n_in,
                              void* d_out, int out_size, void* d_ws,
                              size_t ws_size, hipStream_t stream) {
  const float* x      = (const float*)d_in[0];
  const float* conv_w = (const float*)d_in[1];
  const float* conv_b = (const float*)d_in[2];
  const float* nxca_w = (const float*)d_in[3];
  const float* nxca_b = (const float*)d_in[4];
  const float* temp   = (const float*)d_in[5];
  const float* qkv_w  = (const float*)d_in[6];
  const float* qkv_b  = (const float*)d_in[7];
  const float* proj_w = (const float*)d_in[8];
  const float* proj_b = (const float*)d_in[9];
  const float* norm_w = (const float*)d_in[10];
  const float* norm_b = (const float*)d_in[11];
  const float* fc1_w  = (const float*)d_in[12];
  const float* fc1_b  = (const float*)d_in[13];
  const float* fc2_w  = (const float*)d_in[14];
  const float* fc2_b  = (const float*)d_in[15];
  const float* g_xca  = (const float*)d_in[16];
  const float* g_mlp  = (const float*)d_in[17];
  (void)in_sizes; (void)n_in; (void)out_size; (void)ws_size;

  char* ws = (char*)d_ws;
  float* xc  = (float*)(ws);                    // 50,331,648 B (f32 NCHW, shortcut)
  u16* Y     = (u16*)(ws + 50331648);           // 25,165,824 B (also Obuf)
  u16* QKVr  = (u16*)(ws + 75497472);           // 75,497,472 B  [32768][1152]
  u16* Vt    = (u16*)(ws + 150994944);          // 25,165,824 B  [bh][96][1024]
  u16* Obuf  = Y;                               // attn O overlays Y (dead then)
  u16* H1    = QKVr;                            // fc1 out overlays QKVr+Vt
  u16* wq    = (u16*)(ws + 176160768);
  u16* wp    = (u16*)(ws + 177045504);
  u16* w1    = (u16*)(ws + 177340416);
  u16* w2    = (u16*)(ws + 178520064);          // end: 179,699,712 B

  cvt4_k<<<6912, 256, 0, stream>>>(qkv_w, proj_w, fc1_w, fc2_w, wq, wp, w1, w2);

  conv_k<<<12288, 256, 0, stream>>>(x, conv_w, conv_b, xc);
  ln_t_k<<<dim3(32, 32), 256, 0, stream>>>(xc, nxca_w, nxca_b, Y);
  gemm256_k<4><<<1152, 512, 0, stream>>>(Y, wq, 1152, 384, qkv_b, Vt, QKVr, 9);
  normk_k<<<2048, 256, 0, stream>>>(QKVr);
  attn_k<<<1024, 256, 0, stream>>>(QKVr, Vt, Obuf, temp);
  gemm_k<<<768, 256, 0, stream>>>(wp, Obuf, 384, proj_b, g_xca, xc, xc);
  ln_t_k<<<dim3(32, 32), 256, 0, stream>>>(xc, norm_w, norm_b, Y);
  gemm256_k<1><<<1536, 512, 0, stream>>>(Y, w1, 1536, 384, fc1_b, nullptr, H1, 12);
  gemm_k<<<768, 256, 0, stream>>>(w2, H1, 1536, fc2_b, g_mlp, xc, (float*)d_out);
}

// Round 9
// 396.059 us; speedup vs baseline: 1.7045x; 1.0392x over previous
//
#include <hip/hip_runtime.h>
#include <cstdint>

typedef unsigned short u16;
typedef unsigned int u32;
typedef unsigned long long u64;
typedef __attribute__((ext_vector_type(4))) float f32x4;
typedef __attribute__((ext_vector_type(16))) float f32x16;
typedef __attribute__((ext_vector_type(8))) __bf16 bf16x8;
typedef __attribute__((ext_vector_type(8))) u16 u16x8;
typedef __attribute__((ext_vector_type(4))) u32 u32x4;
typedef __attribute__((ext_vector_type(2))) int i32x2;

#define DEV __device__ __forceinline__

DEV u16 cvt16(float f) {
  __bf16 h = (__bf16)f;
  return __builtin_bit_cast(u16, h);
}
DEV u16 f2bf(float f) {  // round-to-nearest-even (for host-data convert)
  u32 u = __builtin_bit_cast(u32, f);
  u += 0x7fffu + ((u >> 16) & 1u);
  return (u16)(u >> 16);
}
DEV float bflo2f(u32 packed) { return __builtin_bit_cast(float, packed << 16); }
DEV float bfhi2f(u32 packed) { return __builtin_bit_cast(float, packed & 0xffff0000u); }

// async global->LDS, 16B per lane. lds pointer must be the WAVE-UNIFORM base;
// HW adds lane*16. Global pointer is per-lane.
DEV void g2l16(void* lds_wave_base, const void* gsrc) {
  __builtin_amdgcn_global_load_lds(
      (const __attribute__((address_space(1))) u32*)gsrc,
      (__attribute__((address_space(3))) u32*)lds_wave_base, 16, 0, 0);
}

DEV float gelu_tanh(float v) {
  float z = v * (0.7978845608f + 0.0356774081f * v * v);
  float e = __expf(2.0f * z);
  float th = 1.0f - 2.0f / (e + 1.0f);
  return 0.5f * v * (1.0f + th);
}

// ---------------- depthwise conv 3x3 (first 192 ch) + passthrough ----------
__global__ __launch_bounds__(256) void conv_k(const float* __restrict__ x,
                                              const float* __restrict__ cw,
                                              const float* __restrict__ cb,
                                              float* __restrict__ xc) {
  const int bc = blockIdx.x;             // b*384 + c
  const int c = bc % 384;
  const int p4 = threadIdx.x * 4;
  const float* xp = x + ((size_t)bc << 10);
  float* op = xc + ((size_t)bc << 10) + p4;
  if (c >= 192) {
    *(f32x4*)op = *(const f32x4*)(xp + p4);
    return;
  }
  const int hh = p4 >> 5, ww0 = p4 & 31;
  const float* wb = cw + c * 9;
  float b0 = cb[c];
  float a0 = b0, a1 = b0, a2 = b0, a3 = b0;
#pragma unroll
  for (int dy = 0; dy < 3; ++dy) {
    int y = hh + dy - 1;
    if ((unsigned)y < 32u) {
      const float* rp = xp + y * 32 + ww0;
      f32x4 m = *(const f32x4*)rp;
      float lft = (ww0 > 0) ? rp[-1] : 0.f;
      float rgt = (ww0 < 28) ? rp[4] : 0.f;
      float w0 = wb[dy * 3], w1 = wb[dy * 3 + 1], w2 = wb[dy * 3 + 2];
      a0 += lft * w0 + m[0] * w1 + m[1] * w2;
      a1 += m[0] * w0 + m[1] * w1 + m[2] * w2;
      a2 += m[1] * w0 + m[2] * w1 + m[3] * w2;
      a3 += m[2] * w0 + m[3] * w1 + rgt * w2;
    }
  }
  f32x4 r = {a0, a1, a2, a3};
  *(f32x4*)op = r;
}

// ---------------- fused f32 -> bf16 convert of the 4 weight mats -----------
__global__ __launch_bounds__(256) void cvt4_k(const float* __restrict__ s0,
                                              const float* __restrict__ s1,
                                              const float* __restrict__ s2,
                                              const float* __restrict__ s3,
                                              u16* __restrict__ d0,
                                              u16* __restrict__ d1,
                                              u16* __restrict__ d2,
                                              u16* __restrict__ d3) {
  int id = blockIdx.x * 256 + threadIdx.x;
  if (id < 442368) d0[id] = f2bf(s0[id]);
  else if (id < 589824) d1[id - 442368] = f2bf(s1[id - 442368]);
  else if (id < 1179648) d2[id - 589824] = f2bf(s2[id - 589824]);
  else if (id < 1769472) d3[id - 1179648] = f2bf(s3[id - 1179648]);
}

// ---------------- channel-LN (NCHW) + transpose to [token][C] bf16 ---------
__global__ __launch_bounds__(256) void ln_t_k(const float* __restrict__ X,
                                              const float* __restrict__ w,
                                              const float* __restrict__ bsh,
                                              u16* __restrict__ Y) {
  __shared__ float tile[384][33];
  __shared__ float ps[8][32], ps2[8][32];
  __shared__ float mean_s[32], rstd_s[32];
  const int b = blockIdx.y;
  const int p0 = blockIdx.x * 32;
  const int t = threadIdx.x;
  const int pl = t & 31, cg = t >> 5;
  const float* xb = X + (((size_t)b * 384) << 10) + p0 + pl;
  float s = 0.f, s2 = 0.f;
  for (int c = cg; c < 384; c += 8) {
    float v = xb[(size_t)c << 10];
    tile[c][pl] = v;
    s += v;
    s2 += v * v;
  }
  ps[cg][pl] = s;
  ps2[cg][pl] = s2;
  __syncthreads();
  if (t < 32) {
    float a = 0.f, a2 = 0.f;
#pragma unroll
    for (int g = 0; g < 8; ++g) { a += ps[g][t]; a2 += ps2[g][t]; }
    float mu = a * (1.f / 384.f);
    float var = a2 * (1.f / 384.f) - mu * mu;
    mean_s[t] = mu;
    rstd_s[t] = rsqrtf(var + 1e-6f);
  }
  __syncthreads();
  const int cl = t & 63, pg = t >> 6;
  for (int p = pg; p < 32; p += 4) {
    float mu = mean_s[p], rs = rstd_s[p];
    size_t orow = (((size_t)b << 10) + p0 + p) * 384;
#pragma unroll
    for (int cc = 0; cc < 6; ++cc) {
      int c = cc * 64 + cl;
      float v = (tile[c][p] - mu) * rs * w[c] + bsh[c];
      Y[orow + c] = f2bf(v);
    }
  }
}

// ---------------- L2-normalize k heads in QKV rows (q folded into attn) ----
__global__ __launch_bounds__(256) void normk_k(u16* __restrict__ QKV) {
  const int t = threadIdx.x;
  const int w = t >> 6, l = t & 63;
  const int rg = l >> 4, li = l & 15;
  const int tok = blockIdx.x * 16 + w * 4 + rg;
  u16* rowp = QKV + (size_t)tok * 1152 + 384;
#pragma unroll
  for (int h = 0; h < 4; ++h) {
    u16* p = rowp + h * 96 + li * 6;
    u32 a = *(const u32*)p;
    u32 b2 = *(const u32*)(p + 2);
    u32 c = *(const u32*)(p + 4);
    float v[6] = {bflo2f(a), bfhi2f(a), bflo2f(b2), bfhi2f(b2), bflo2f(c), bfhi2f(c)};
    float ss = 0.f;
#pragma unroll
    for (int i = 0; i < 6; ++i) ss += v[i] * v[i];
#pragma unroll
    for (int mk = 1; mk < 16; mk <<= 1) ss += __shfl_xor(ss, mk, 64);
    float sc = 1.0f / fmaxf(sqrtf(ss), 1e-12f);
    u32 o0 = (u32)f2bf(v[0] * sc) | ((u32)f2bf(v[1] * sc) << 16);
    u32 o1 = (u32)f2bf(v[2] * sc) | ((u32)f2bf(v[3] * sc) << 16);
    u32 o2 = (u32)f2bf(v[4] * sc) | ((u32)f2bf(v[5] * sc) << 16);
    *(u32*)p = o0;
    *(u32*)(p + 2) = o1;
    *(u32*)(p + 4) = o2;
  }
}

// ---------------- flash attention v9: 32x32 MFMA, in-register P ------------
// 1024 blocks (XCD-pinned), 4 waves × 32 q-rows, KVBLK=64. Swapped QK^T
// (st = mfma(K,Q)) -> lane owns q-col l31; alpha lane-local; P repacked to
// the PV A-operand via cvt_pk pairs + permlane32_swap (no P LDS). K LDS
// [64][104]u16 (208B stride, bank-uniform, no swizzle); V [96][64] XOR-swz.
// LDS 50KB -> 3 blocks/CU. vmcnt(7) counted, 2 barriers/tile.
__global__ __launch_bounds__(256, 3) void attn_k(const u16* __restrict__ QKV,
                                                 const u16* __restrict__ Vg,
                                                 u16* __restrict__ O,
                                                 const float* __restrict__ temp) {
  __shared__ u16 Kt[2][6656];    // 64 rows × 104 u16, 13312B each
  __shared__ u16 Vt[2][6144];    // 96 rows × 64 u16 XOR-swz, 12288B each
  const int t = threadIdx.x;
  const int w = t >> 6, l = t & 63;
  const int l31 = l & 31, hi = l >> 5;
  const int id = blockIdx.x;
  const int xcd = id & 7, jj = id >> 3;          // jj in [0,128)
  const int bh = xcd * 16 + (jj >> 3);
  const int qb = jj & 7;
  const int b = bh >> 2, h = bh & 3;
  const int q0 = qb * 128 + w * 32;
  const u16* Qb = QKV + (size_t)b * 1024 * 1152;
  const char* Kbg = (const char*)QKV + (size_t)b * 1024 * 2304 + 768 + 192 * h;
  const char* Vbg = (const char*)(Vg + (size_t)bh * 98304);  // [96][1024]
  const float tl2e = temp[h] * 1.44269504f;
  const float mT2 = -fabsf(temp[h]) * 1.44269504f;

  // staging source offsets. K tile: LDS slot s (16B) -> row=s/13, col c=s%13
  // (c==12 is pad; dummy src). V tile: XOR-swizzled source (linear g2l dest).
  u32 kOff[4], vOff[3];
#pragma unroll
  for (int i = 0; i < 4; ++i) {
    int s = (i < 3) ? (i * 256 + t) : (768 + w * 16 + (l & 15));
    int row = s / 13, c = s - row * 13;
    kOff[i] = row * 2304 + ((c < 12) ? c * 16 : 0);
  }
#pragma unroll
  for (int i = 0; i < 3; ++i) {
    int s = i * 256 + t;
    int row = s >> 3, cb = (s & 7) * 16;
    vOff[i] = row * 2048 + (cb ^ ((row & 7) << 4));
  }

  // Q fragments (B-operand rows = q = l31): qf[kc] holds Q[q][kc*16+hi*8+e]
  bf16x8 qf[6];
  {
    const u16* qp = Qb + (size_t)(q0 + l31) * 1152 + h * 96 + hi * 8;
#pragma unroll
    for (int kc = 0; kc < 6; ++kc) qf[kc] = *(const bf16x8*)(qp + kc * 16);
  }
  // alpha = temp*log2e / |q| for row l31 (own half + partner half via xor32)
  float alpha;
  {
    float ss = 0.f;
#pragma unroll
    for (int kc = 0; kc < 6; ++kc)
#pragma unroll
      for (int e = 0; e < 8; ++e) {
        float v = (float)qf[kc][e];
        ss += v * v;
      }
    ss += __shfl_xor(ss, 32, 64);
    alpha = tl2e * rsqrtf(fmaxf(ss, 1e-24f));
  }

  f32x16 oa[3];
#pragma unroll
  for (int dt = 0; dt < 3; ++dt)
#pragma unroll
    for (int r = 0; r < 16; ++r) oa[dt][r] = 0.f;
  float l_r = 0.f;

#define STAGE(buf, kv0)                                                        \
  {                                                                            \
    const char* kb = Kbg + (size_t)(kv0) * 2304;                               \
    const char* vb = Vbg + (size_t)(kv0) * 2;                                  \
    char* kd = (char*)&Kt[buf][0];                                             \
    char* vd = (char*)&Vt[buf][0];                                             \
    g2l16(kd + w * 1024, kb + kOff[0]);                                        \
    g2l16(kd + 4096 + w * 1024, kb + kOff[1]);                                 \
    g2l16(kd + 8192 + w * 1024, kb + kOff[2]);                                 \
    if (l < 16) g2l16(kd + 12288 + w * 256, kb + kOff[3]);                     \
    g2l16(vd + w * 1024, vb + vOff[0]);                                        \
    g2l16(vd + 4096 + w * 1024, vb + vOff[1]);                                 \
    g2l16(vd + 8192 + w * 1024, vb + vOff[2]);                                 \
  }

  STAGE(0, 0);
  for (int tt = 0; tt < 16; ++tt) {
    const int cur = tt & 1;
    if (tt < 15) {
      STAGE(cur ^ 1, (tt + 1) * 64);
      asm volatile("s_waitcnt vmcnt(7)" ::: "memory");
    } else {
      asm volatile("s_waitcnt vmcnt(0)" ::: "memory");
    }
    __builtin_amdgcn_s_barrier();
    const char* Kc = (const char*)&Kt[cur][0];
    const char* Vc = (const char*)&Vt[cur][0];
    // S^T = K @ Q^T : st[n] reg r holds s[q=l31][kv = n*32+(r&3)+8(r>>2)+4hi]
    f32x16 st[2];
#pragma unroll
    for (int n = 0; n < 2; ++n)
#pragma unroll
      for (int r = 0; r < 16; ++r) st[n][r] = 0.f;
#pragma unroll
    for (int n = 0; n < 2; ++n) {
      const char* krow = Kc + (n * 32 + l31) * 208 + hi * 16;
#pragma unroll
      for (int kc = 0; kc < 6; ++kc) {
        bf16x8 kf = *(const bf16x8*)(krow + kc * 32);
        st[n] = __builtin_amdgcn_mfma_f32_32x32x16_bf16(kf, qf[kc], st[n], 0, 0, 0);
      }
    }
    // P = exp2(s*alpha - T2) in-register; pack adjacent reg pairs to bf16
    u32 pk[2][8];
#pragma unroll
    for (int n = 0; n < 2; ++n) {
      float p[16];
#pragma unroll
      for (int r = 0; r < 16; ++r) {
        p[r] = exp2f(fmaf(st[n][r], alpha, mT2));
        l_r += p[r];
      }
#pragma unroll
      for (int m = 0; m < 8; ++m)
        pk[n][m] = (u32)cvt16(p[2 * m]) | ((u32)cvt16(p[2 * m + 1]) << 16);
    }
    // O += P @ V : build PV A-frag per 16-kv chunk via permlane32_swap
#pragma unroll
    for (int c = 0; c < 4; ++c) {
      const int n = c >> 1, cc = c & 1;
      i32x2 s1 = __builtin_amdgcn_permlane32_swap((int)pk[n][4 * cc],
                                                  (int)pk[n][4 * cc + 2], 0, 0);
      i32x2 s2 = __builtin_amdgcn_permlane32_swap((int)pk[n][4 * cc + 1],
                                                  (int)pk[n][4 * cc + 3], 0, 0);
      u32x4 wd;
      wd[0] = (u32)s1[0]; wd[1] = (u32)s2[0];
      wd[2] = (u32)s1[1]; wd[3] = (u32)s2[1];
      bf16x8 pa = __builtin_bit_cast(bf16x8, wd);
      const u32 vcol = (u32)((c * 32 + hi * 16) ^ ((l31 & 7) << 4));
#pragma unroll
      for (int dt = 0; dt < 3; ++dt) {
        bf16x8 vf = *(const bf16x8*)(Vc + (dt * 32 + l31) * 128 + vcol);
        oa[dt] = __builtin_amdgcn_mfma_f32_32x32x16_bf16(pa, vf, oa[dt], 0, 0, 0);
      }
    }
    __builtin_amdgcn_s_barrier();
  }
#undef STAGE
  // finalize: row sum (own half + partner), redistribute inv to O rows
  l_r += __shfl_xor(l_r, 32, 64);
  float inv = 1.0f / l_r;
#pragma unroll
  for (int r = 0; r < 16; ++r) {
    const int qr = (r & 3) + 8 * (r >> 2) + 4 * hi;
    float invr = __shfl(inv, qr, 64);
    const int tok = q0 + qr;
    u16* orow = O + ((size_t)b * 1024 + tok) * 384 + h * 96;
#pragma unroll
    for (int dt = 0; dt < 3; ++dt)
      orow[dt * 32 + l31] = f2bf(oa[dt][r] * invr);
  }
}

// ---------------- 256x128 bf16 GEMM, 512 thr, dbuf + counted vmcnt ---------
// A [M][K] rm bf16 (M=32768), B [N][K] rm bf16, D = A @ B^T.
// 1D grid XCD-pinned: by = xcd*16 + jj/nbx, bx = jj%nbx (M-tiles = 128).
// EPI 1: gelu(D+bias) -> bf16 rm [M][N] (LDS-bounce, 2 passes)
// EPI 4: QKV: cols<768 -> rm [tok][1152]; cols>=768 -> Vt [bh][96][n] (vtp)
template <int EPI>
__global__ __launch_bounds__(512) void gemm256_k(const u16* __restrict__ A,
                                                 const u16* __restrict__ B,
                                                 int N, int K,
                                                 const float* __restrict__ bias,
                                                 u16* __restrict__ vtp,
                                                 u16* __restrict__ outp,
                                                 int nbx) {
  __shared__ u16 SM[24576];      // 48KB: At[2]16KB | Bt[2]8KB ; Ct 32KB after
  const int t = threadIdx.x;
  const int w = t >> 6, l = t & 63;
  const int l15 = l & 15, kg = l >> 4;
  const int id = blockIdx.x;
  const int xcd = id & 7, jj = id >> 3;
  const int qq = jj / nbx;
  const int bx = jj - qq * nbx;
  const int by = xcd * 16 + qq;
  const int m0 = by * 256, n0 = bx * 128;
  const int wr = w >> 1, wc = w & 1;
  const size_t ldab = (size_t)K * 2;
  const char* pa1 = (const char*)A + (size_t)(m0 + (t >> 2)) * ldab + (t & 3) * 16;
  const char* pa2 = pa1 + (size_t)128 * ldab;
  const char* pb1 = (const char*)B + (size_t)(n0 + (t >> 2)) * ldab + (t & 3) * 16;
  char* SMc = (char*)SM;

  f32x4 acc[4][4];
#pragma unroll
  for (int m = 0; m < 4; ++m)
#pragma unroll
    for (int n = 0; n < 4; ++n) acc[m][n] = {0.f, 0.f, 0.f, 0.f};

  const int nkt = K >> 5;
  g2l16(SMc + w * 1024, pa1);
  g2l16(SMc + 8192 + w * 1024, pa2);
  g2l16(SMc + 32768 + w * 1024, pb1);
  for (int kt = 0; kt < nkt; ++kt) {
    const int buf = kt & 1;
    if (kt + 1 < nkt) {
      const size_t o = (size_t)(kt + 1) * 64;
      g2l16(SMc + (buf ^ 1) * 16384 + w * 1024, pa1 + o);
      g2l16(SMc + (buf ^ 1) * 16384 + 8192 + w * 1024, pa2 + o);
      g2l16(SMc + 32768 + (buf ^ 1) * 8192 + w * 1024, pb1 + o);
      asm volatile("s_waitcnt vmcnt(3)" ::: "memory");
    } else {
      asm volatile("s_waitcnt vmcnt(0)" ::: "memory");
    }
    __builtin_amdgcn_s_barrier();
    __builtin_amdgcn_sched_barrier(0);
    const u16* Ab = SM + buf * 8192;
    const u16* Bb = SM + 16384 + buf * 4096;
    bf16x8 af[4], bfr[4];
#pragma unroll
    for (int m = 0; m < 4; ++m)
      af[m] = *(const bf16x8*)(Ab + (wr * 64 + m * 16 + l15) * 32 + kg * 8);
#pragma unroll
    for (int n = 0; n < 4; ++n)
      bfr[n] = *(const bf16x8*)(Bb + (wc * 64 + n * 16 + l15) * 32 + kg * 8);
    __builtin_amdgcn_s_setprio(1);
#pragma unroll
    for (int m = 0; m < 4; ++m)
#pragma unroll
      for (int n = 0; n < 4; ++n)
        acc[m][n] = __builtin_amdgcn_mfma_f32_16x16x32_bf16(af[m], bfr[n], acc[m][n], 0, 0, 0);
    __builtin_amdgcn_s_setprio(0);
    __builtin_amdgcn_sched_barrier(0);
    __builtin_amdgcn_s_barrier();
  }

  if (EPI == 4 && n0 >= 768) {   // V section: transposed u64 into vtp
#pragma unroll
    for (int m = 0; m < 4; ++m) {
      const int tokbase = m0 + wr * 64 + m * 16 + kg * 4;
      const int bb = tokbase >> 10, nb = tokbase & 1023;
#pragma unroll
      for (int n = 0; n < 4; ++n) {
        int within = n0 - 768 + wc * 64 + n * 16 + l15;
        int hh = within / 96;
        int dd = within - hh * 96;
        float bs = bias[768 + within];
        int bh = bb * 4 + hh;
        u64 pk = 0;
#pragma unroll
        for (int j = 0; j < 4; ++j)
          pk |= (u64)cvt16(acc[m][n][j] + bs) << (16 * j);
        *(u64*)(vtp + ((size_t)bh * 96 + dd) * 1024 + nb) = pk;
      }
    }
    return;
  }

  // ---- LDS-bounce epilogue, two 128-row passes ----
  u16* Ct = SM;                  // 128x128 u16 (32KB), overlays staged tiles
  float bs[4];
#pragma unroll
  for (int n = 0; n < 4; ++n) bs[n] = bias[n0 + wc * 64 + n * 16 + l15];
  const size_t ostride = (EPI == 4) ? 1152 : (size_t)N;
#pragma unroll
  for (int p = 0; p < 2; ++p) {
    if ((wr >> 1) == p) {
      u16* cw_ = Ct + ((wr & 1) * 64 + kg * 4) * 128 + wc * 64 + l15;
#pragma unroll
      for (int m = 0; m < 4; ++m)
#pragma unroll
        for (int n = 0; n < 4; ++n)
#pragma unroll
          for (int j = 0; j < 4; ++j) {
            float v = acc[m][n][j] + bs[n];
            if (EPI == 1) v = gelu_tanh(v);
            cw_[(m * 16 + j) * 128 + n * 16] = cvt16(v);
          }
    }
    __syncthreads();
    const int row_l = t >> 2;
    const int colc = (t & 3) * 32;
    const u16* src = Ct + row_l * 128 + colc;
    u16* dst = outp + (size_t)(m0 + p * 128 + row_l) * ostride + n0 + colc;
#pragma unroll
    for (int c4 = 0; c4 < 4; ++c4)
      *(u16x8*)(dst + c4 * 8) = *(const u16x8*)(src + c4 * 8);
    __syncthreads();
  }
}

// ---------------- 128x128 bf16 GEMM (EPI2: M=384 fused-residual) -----------
// SWZ 2: 768 blocks; 3 by-blocks of one bx co-located per XCD.
__global__ __launch_bounds__(256) void gemm_k(const u16* __restrict__ A,
                                              const u16* __restrict__ B,
                                              int K,
                                              const float* __restrict__ bias,
                                              const float* __restrict__ gamma,
                                              const float* __restrict__ res,
                                              float* __restrict__ outp) {
  __shared__ u16 SM[16384];
  const int t = threadIdx.x;
  const int w = t >> 6, l = t & 63;
  const int l15 = l & 15, kg = l >> 4;
  int id = blockIdx.x;
  int xcd = id & 7, jj = id >> 3;
  int by = jj % 3;
  int bx = (jj / 3) * 8 + xcd;
  const int m0 = by * 128, n0 = bx * 128;
  const int wr = w >> 1, wc = w & 1;

  const size_t ldab = (size_t)K * 2;
  const char* pa1 = (const char*)A + (size_t)(m0 + (t >> 2)) * ldab + (t & 3) * 16;
  const char* pa2 = pa1 + (size_t)64 * ldab;
  const char* pb1 = (const char*)B + (size_t)(n0 + (t >> 2)) * ldab + (t & 3) * 16;
  const char* pb2 = pb1 + (size_t)64 * ldab;
  char* SMc = (char*)SM;

  f32x4 acc[4][4];
#pragma unroll
  for (int m = 0; m < 4; ++m)
#pragma unroll
    for (int n = 0; n < 4; ++n) acc[m][n] = {0.f, 0.f, 0.f, 0.f};

  const int nkt = K >> 5;
  {
    char* ad = SMc + w * 1024;
    char* bd = SMc + 16384 + w * 1024;
    g2l16(ad, pa1); g2l16(ad + 4096, pa2);
    g2l16(bd, pb1); g2l16(bd + 4096, pb2);
  }
  for (int kt = 0; kt < nkt; ++kt) {
    const int buf = kt & 1;
    if (kt + 1 < nkt) {
      const size_t o = (size_t)(kt + 1) * 64;
      char* ad = SMc + (buf ^ 1) * 8192 + w * 1024;
      char* bd = SMc + 16384 + (buf ^ 1) * 8192 + w * 1024;
      g2l16(ad, pa1 + o); g2l16(ad + 4096, pa2 + o);
      g2l16(bd, pb1 + o); g2l16(bd + 4096, pb2 + o);
      asm volatile("s_waitcnt vmcnt(4)" ::: "memory");
    } else {
      asm volatile("s_waitcnt vmcnt(0)" ::: "memory");
    }
    __builtin_amdgcn_s_barrier();
    __builtin_amdgcn_sched_barrier(0);
    const u16* Ab = SM + buf * 4096;
    const u16* Bb = SM + 8192 + buf * 4096;
    bf16x8 af[4], bfr[4];
#pragma unroll
    for (int m = 0; m < 4; ++m)
      af[m] = *(const bf16x8*)(Ab + (wr * 64 + m * 16 + l15) * 32 + kg * 8);
#pragma unroll
    for (int n = 0; n < 4; ++n)
      bfr[n] = *(const bf16x8*)(Bb + (wc * 64 + n * 16 + l15) * 32 + kg * 8);
    __builtin_amdgcn_s_setprio(1);
#pragma unroll
    for (int m = 0; m < 4; ++m)
#pragma unroll
      for (int n = 0; n < 4; ++n)
        acc[m][n] = __builtin_amdgcn_mfma_f32_16x16x32_bf16(af[m], bfr[n], acc[m][n], 0, 0, 0);
    __builtin_amdgcn_s_setprio(0);
    __builtin_amdgcn_sched_barrier(0);
    __builtin_amdgcn_s_barrier();
  }

  // EPI2: rows=channels, cols=tokens; out[b,c,p] = res + gamma[c]*(D+bias[c])
#pragma unroll
  for (int m = 0; m < 4; ++m) {
#pragma unroll
    for (int n = 0; n < 4; ++n) {
      int tok = n0 + wc * 64 + n * 16 + l15;
      int bb = tok >> 10, p = tok & 1023;
#pragma unroll
      for (int j = 0; j < 4; ++j) {
        int c = m0 + wr * 64 + m * 16 + kg * 4 + j;
        size_t addr = (((size_t)(bb * 384 + c)) << 10) + p;
        outp[addr] = res[addr] + gamma[c] * (acc[m][n][j] + bias[c]);
      }
    }
  }
}

// ---------------------------------------------------------------------------
extern "C" void kernel_launch(void* const* d_in, const int* in_sizes, int n_in,
                              void* d_out, int out_size, void* d_ws,
                              size_t ws_size, hipStream_t stream) {
  const float* x      = (const float*)d_in[0];
  const float* conv_w = (const float*)d_in[1];
  const float* conv_b = (const float*)d_in[2];
  const float* nxca_w = (const float*)d_in[3];
  const float* nxca_b = (const float*)d_in[4];
  const float* temp   = (const float*)d_in[5];
  const float* qkv_w  = (const float*)d_in[6];
  const float* qkv_b  = (const float*)d_in[7];
  const float* proj_w = (const float*)d_in[8];
  const float* proj_b = (const float*)d_in[9];
  const float* norm_w = (const float*)d_in[10];
  const float* norm_b = (const float*)d_in[11];
  const float* fc1_w  = (const float*)d_in[12];
  const float* fc1_b  = (const float*)d_in[13];
  const float* fc2_w  = (const float*)d_in[14];
  const float* fc2_b  = (const float*)d_in[15];
  const float* g_xca  = (const float*)d_in[16];
  const float* g_mlp  = (const float*)d_in[17];
  (void)in_sizes; (void)n_in; (void)out_size; (void)ws_size;

  char* ws = (char*)d_ws;
  float* xc  = (float*)(ws);                    // 50,331,648 B (f32 NCHW, shortcut)
  u16* Y     = (u16*)(ws + 50331648);           // 25,165,824 B (also Obuf)
  u16* QKVr  = (u16*)(ws + 75497472);           // 75,497,472 B  [32768][1152]
  u16* Vt    = (u16*)(ws + 150994944);          // 25,165,824 B  [bh][96][1024]
  u16* Obuf  = Y;                               // attn O overlays Y (dead then)
  u16* H1    = QKVr;                            // fc1 out overlays QKVr+Vt
  u16* wq    = (u16*)(ws + 176160768);
  u16* wp    = (u16*)(ws + 177045504);
  u16* w1    = (u16*)(ws + 177340416);
  u16* w2    = (u16*)(ws + 178520064);          // end: 179,699,712 B

  cvt4_k<<<6912, 256, 0, stream>>>(qkv_w, proj_w, fc1_w, fc2_w, wq, wp, w1, w2);

  conv_k<<<12288, 256, 0, stream>>>(x, conv_w, conv_b, xc);
  ln_t_k<<<dim3(32, 32), 256, 0, stream>>>(xc, nxca_w, nxca_b, Y);
  gemm256_k<4><<<1152, 512, 0, stream>>>(Y, wq, 1152, 384, qkv_b, Vt, QKVr, 9);
  normk_k<<<2048, 256, 0, stream>>>(QKVr);
  attn_k<<<1024, 256, 0, stream>>>(QKVr, Vt, Obuf, temp);
  gemm_k<<<768, 256, 0, stream>>>(wp, Obuf, 384, proj_b, g_xca, xc, xc);
  ln_t_k<<<dim3(32, 32), 256, 0, stream>>>(xc, norm_w, norm_b, Y);
  gemm256_k<1><<<1536, 512, 0, stream>>>(Y, w1, 1536, 384, fc1_b, nullptr, H1, 12);
  gemm_k<<<768, 256, 0, stream>>>(w2, H1, 1536, fc2_b, g_mlp, xc, (float*)d_out);
}